// Round 11
// baseline (386.639 us; speedup 1.0000x reference)
//
#include <hip/hip_runtime.h>
#include <hip/hip_bf16.h>
#include <math.h>

typedef __hip_bfloat16 bf16;
using f32x4 = __attribute__((ext_vector_type(4))) float;
using s16x8 = __attribute__((ext_vector_type(8))) short;

#define DEV_INLINE __device__ __forceinline__

static constexpr int BB   = 256;
static constexpr int CIN  = 17;
static constexpr int WIN  = 84;
static constexpr int C1   = 64;
static constexpr int W1   = 20;
static constexpr int P1   = W1 * W1;     // 400
static constexpr int C2   = 510;
static constexpr int W2   = 9;
static constexpr int NE   = 81;
static constexpr int DM   = 512;
static constexpr int HID  = 1024;
static constexpr int NH   = 4;
static constexpr int DK   = 256;
static constexpr int MR   = BB * NE;     // 20736
static constexpr int ODIM = 256;
static constexpr int PLANE = WIN * WIN;  // 7056
static constexpr int QS   = 3 * HID;     // 3072

DEV_INLINE float lrelu_f(float v) { return v > 0.f ? v : 0.1f * v; }
DEV_INLINE float bf2f(ushort u) { return __uint_as_float((unsigned)u << 16); }
DEV_INLINE short f2bs(float f) { bf16 t = __float2bfloat16(f); return *reinterpret_cast<short*>(&t); }

DEV_INLINE void gll16(const void* g, const void* l) {
    __builtin_amdgcn_global_load_lds(
        (const __attribute__((address_space(1))) unsigned int*)g,
        (__attribute__((address_space(3))) unsigned int*)l, 16, 0, 0);
}
DEV_INLINE f32x4 mfma16(s16x8 a, s16x8 b, f32x4 c) {
    return __builtin_amdgcn_mfma_f32_16x16x32_bf16(a, b, c, 0, 0, 0);
}

// ---------------- fused weight prep (all casts/packs in ONE launch) ---------
__global__ void k_prep(const float* __restrict__ w1, const float* __restrict__ w2,
        const float* __restrict__ b2, const float* __restrict__ wq,
        const float* __restrict__ wk, const float* __restrict__ wv,
        const float* __restrict__ wo, bf16* __restrict__ w1b,
        bf16* __restrict__ w2b, float* __restrict__ b2p,
        bf16* __restrict__ wqkv, bf16* __restrict__ wob) {
    int i = blockIdx.x * 256 + threadIdx.x;
    if (i < 17408) {
        const size_t o = (size_t)i * 4;
        const float4 v = *(const float4*)(w1 + o);
        short r[4] = { f2bs(v.x), f2bs(v.y), f2bs(v.z), f2bs(v.w) };
        *(ushort4*)(w1b + o) = *(ushort4*)r;
        return;
    }
    i -= 17408;
    if (i < 524288) {   // w2 cast + K-permute to (kh,kw,ic), zero-pad rows 510/511
        const int n = i >> 10, rem = i & 1023;
        const int khkw = rem >> 6, ic = rem & 63;
        w2b[i] = (n < C2) ? __float2bfloat16(w2[n * 1024 + ic * 16 + khkw])
                          : __float2bfloat16(0.f);
        return;
    }
    i -= 524288;
    if (i < 512) { b2p[i] = (i < C2) ? b2[i] : 0.f; return; }
    i -= 512;
    if (i < 393216) {   // wq|wk|wv concat -> wqkv[3072][512]
        const size_t o = (size_t)i * 4;
        const int n = (int)(o >> 9), c = (int)(o & 511);
        const float* src = (n < 1024) ? wq : (n < 2048) ? wk : wv;
        const float4 v = *(const float4*)(src + (size_t)(n & 1023) * 512 + c);
        short r[4] = { f2bs(v.x), f2bs(v.y), f2bs(v.z), f2bs(v.w) };
        *(ushort4*)(wqkv + o) = *(ushort4*)r;
        return;
    }
    i -= 393216;
    if (i < 131072) {
        const size_t o = (size_t)i * 4;
        const float4 v = *(const float4*)(wo + o);
        short r[4] = { f2bs(v.x), f2bs(v.y), f2bs(v.z), f2bs(v.w) };
        *(ushort4*)(wob + o) = *(ushort4*)r;
    }
}

// ---------------- conv1 as implicit-GEMM MFMA -------------------------------
__global__ __launch_bounds__(512, 1) void k_conv1_mfma(const float* __restrict__ x,
        const bf16* __restrict__ w1b, const float* __restrict__ bias,
        bf16* __restrict__ y1t) {
    __shared__ __align__(16) char pl[2][28224];
    const int b = blockIdx.x;
    const int tid = threadIdx.x;
    const int w = tid >> 6, l = tid & 63;
    const int l15 = l & 15, l4 = l >> 4;
    const float* xb = x + (size_t)b * CIN * PLANE;

    int baseA[4], tval[4];
    #pragma unroll
    for (int j = 0; j < 4; ++j) {
        const int t = w + 8 * j; tval[j] = t;
        int p = t * 16 + l15; if (t >= 25) p = 0;
        const int oh = p / 20, ow = p % 20;
        baseA[j] = (oh * 4 + l4) * 336 + ow * 16;
    }
    float bias_r[4];
    #pragma unroll
    for (int nt = 0; nt < 4; ++nt) bias_r[nt] = bias[nt * 16 + l15];

    #pragma unroll
    for (int it = 0; it < 4; ++it) {
        const int g = it * 512 + tid;
        if (g < 1764) gll16(xb + (size_t)g * 4, pl[0] + (size_t)g * 16);
    }
    __syncthreads();

    f32x4 acc[4][4] = {};
    int cur = 0;
    for (int ic = 0; ic < CIN; ++ic) {
        if (ic + 1 < CIN) {
            const float* src = xb + (size_t)(ic + 1) * PLANE;
            #pragma unroll
            for (int it = 0; it < 4; ++it) {
                const int g = it * 512 + tid;
                if (g < 1764) gll16(src + (size_t)g * 4, pl[cur ^ 1] + (size_t)g * 16);
            }
        }
        s16x8 bq[4][2];
        #pragma unroll
        for (int nt = 0; nt < 4; ++nt)
            #pragma unroll
            for (int ks = 0; ks < 2; ++ks)
                bq[nt][ks] = *(const s16x8*)(w1b + (size_t)(nt * 16 + l15) * 1088
                                             + ic * 64 + (ks * 4 + l4) * 8);
        const char* P = pl[cur];
        #pragma unroll
        for (int j = 0; j < 4; ++j) {
            if (tval[j] < 25) {
                #pragma unroll
                for (int ks = 0; ks < 2; ++ks) {
                    const float* fp = (const float*)(P + baseA[j] + ks * 1344);
                    const f32x4 f0 = *(const f32x4*)fp;
                    const f32x4 f1 = *(const f32x4*)(fp + 4);
                    s16x8 af;
                    #pragma unroll
                    for (int jj = 0; jj < 4; ++jj) {
                        af[jj]     = f2bs(f0[jj]);
                        af[jj + 4] = f2bs(f1[jj]);
                    }
                    #pragma unroll
                    for (int nt = 0; nt < 4; ++nt)
                        acc[j][nt] = mfma16(af, bq[nt][ks], acc[j][nt]);
                }
            }
        }
        __syncthreads();
        cur ^= 1;
    }
    #pragma unroll
    for (int j = 0; j < 4; ++j) {
        if (tval[j] < 25) {
            #pragma unroll
            for (int nt = 0; nt < 4; ++nt) {
                #pragma unroll
                for (int q = 0; q < 4; ++q) {
                    const int pix = tval[j] * 16 + l4 * 4 + q;
                    const int oc  = nt * 16 + l15;
                    y1t[((size_t)b * P1 + pix) * 64 + oc] =
                        __float2bfloat16(lrelu_f(acc[j][nt][q] + bias_r[nt]));
                }
            }
        }
    }
}

// ---------------- conv2 GEMM (128x128, dbuf pipeline, implicit im2col) ------
__global__ __launch_bounds__(256) void k_gemm_conv2(const bf16* __restrict__ A,
        const bf16* __restrict__ B, const float* __restrict__ bias,
        bf16* __restrict__ Cb) {
    __shared__ __align__(16) char Asm[2][128 * 64];
    __shared__ __align__(16) char Bsm[2][128 * 64];
    const int tid = threadIdx.x;
    const int m0 = blockIdx.y * 128, n0 = blockIdx.x * 128;
    const int w = tid >> 6, l = tid & 63;
    const int wm = w >> 1, wn = w & 1;
    const int l15 = l & 15, l4 = l >> 4;
    const int r0 = tid >> 2, p0 = tid & 3;
    const int r1 = 64 + r0;
    const int sw0 = (p0 ^ ((r0 >> 1) & 3)) << 3;
    const int sw1 = (p0 ^ ((r1 >> 1) & 3)) << 3;
    int bimg[2], ohh[2], oww[2];
    #pragma unroll
    for (int it = 0; it < 2; ++it) {
        const int m = m0 + (it ? r1 : r0);
        bimg[it] = m / 81;
        const int n = m - bimg[it] * 81;
        ohh[it] = n / 9; oww[it] = n - ohh[it] * 9;
    }
    auto stage = [&](int buf, int k0) {
        const int khkw = k0 >> 6, icb = k0 & 63;
        const int kh = khkw >> 2, kwv = khkw & 3;
        const int pix0 = (ohh[0] * 2 + kh) * 20 + oww[0] * 2 + kwv;
        const int pix1 = (ohh[1] * 2 + kh) * 20 + oww[1] * 2 + kwv;
        gll16(A + ((size_t)bimg[0] * P1 + pix0) * 64 + icb + sw0, Asm[buf] + tid * 16);
        gll16(A + ((size_t)bimg[1] * P1 + pix1) * 64 + icb + sw1, Asm[buf] + (256 + tid) * 16);
        gll16(B + (size_t)(n0 + r0) * HID + k0 + sw0, Bsm[buf] + tid * 16);
        gll16(B + (size_t)(n0 + r1) * HID + k0 + sw1, Bsm[buf] + (256 + tid) * 16);
    };
    stage(0, 0);
    __syncthreads();
    f32x4 acc[4][4] = {};
    int cur = 0;
    for (int t = 0; t < 32; ++t) {
        if (t < 31) stage(cur ^ 1, (t + 1) * 32);
        s16x8 af[4], bfv[4];
        #pragma unroll
        for (int i = 0; i < 4; ++i) {
            const int ra = wm * 64 + i * 16 + l15;
            af[i]  = *(const s16x8*)(Asm[cur] + ra * 64 + ((l4 ^ ((ra >> 1) & 3)) << 4));
            const int rb = wn * 64 + i * 16 + l15;
            bfv[i] = *(const s16x8*)(Bsm[cur] + rb * 64 + ((l4 ^ ((rb >> 1) & 3)) << 4));
        }
        #pragma unroll
        for (int i = 0; i < 4; ++i)
            #pragma unroll
            for (int j = 0; j < 4; ++j)
                acc[i][j] = mfma16(af[i], bfv[j], acc[i][j]);
        __syncthreads();
        cur ^= 1;
    }
    #pragma unroll
    for (int i = 0; i < 4; ++i) {
        #pragma unroll
        for (int j = 0; j < 4; ++j) {
            const int col = n0 + wn * 64 + j * 16 + l15;
            #pragma unroll
            for (int q = 0; q < 4; ++q) {
                const int row = m0 + wm * 64 + i * 16 + l4 * 4 + q;
                float v = lrelu_f(acc[i][j][q] + bias[col]);
                if (col >= 510) {
                    const int n = row % 81;
                    v = (col == 510) ? (float)(n / 9) * (1.f / 9.f)
                                     : (float)(n % 9) * (1.f / 9.f);
                }
                Cb[(size_t)row * DM + col] = __float2bfloat16(v);
            }
        }
    }
}

// ---------------- GEMM 128x128, BK=32, single-buffer 16KB (round-4 struct) --
// Measured-best for this shape (113us). + row-partial stats epilogue.
// NO XCD swizzle (round-10 A/B: swizzle = +20% FETCH, +27% time).
template <int RESID>
__global__ __launch_bounds__(256) void k_gemm32(const bf16* __restrict__ A,
        const bf16* __restrict__ B, const bf16* __restrict__ resid,
        bf16* __restrict__ Cb, float2* __restrict__ part,
        int K, int ldc, int nPH) {
    __shared__ __align__(16) char Asm[128 * 64];
    __shared__ __align__(16) char Bsm[128 * 64];
    const int tid = threadIdx.x;
    const int m0 = blockIdx.y * 128, n0 = blockIdx.x * 128;
    const int w = tid >> 6, l = tid & 63;
    const int wm = w >> 1, wn = w & 1;
    const int l15 = l & 15, l4 = l >> 4;
    const int r0 = tid >> 2, p0 = tid & 3;
    const int r1 = 64 + r0;
    const int sw0 = (p0 ^ ((r0 >> 1) & 3)) << 3;
    const int sw1 = (p0 ^ ((r1 >> 1) & 3)) << 3;
    f32x4 acc[4][4] = {};
    for (int k0 = 0; k0 < K; k0 += 32) {
        gll16(A + (size_t)(m0 + r0) * K + k0 + sw0, Asm + tid * 16);
        gll16(A + (size_t)(m0 + r1) * K + k0 + sw1, Asm + (256 + tid) * 16);
        gll16(B + (size_t)(n0 + r0) * K + k0 + sw0, Bsm + tid * 16);
        gll16(B + (size_t)(n0 + r1) * K + k0 + sw1, Bsm + (256 + tid) * 16);
        __syncthreads();
        s16x8 af[4], bfv[4];
        #pragma unroll
        for (int i = 0; i < 4; ++i) {
            const int ra = wm * 64 + i * 16 + l15;
            af[i]  = *(const s16x8*)(Asm + ra * 64 + ((l4 ^ ((ra >> 1) & 3)) << 4));
            const int rb = wn * 64 + i * 16 + l15;
            bfv[i] = *(const s16x8*)(Bsm + rb * 64 + ((l4 ^ ((rb >> 1) & 3)) << 4));
        }
        #pragma unroll
        for (int i = 0; i < 4; ++i)
            #pragma unroll
            for (int j = 0; j < 4; ++j)
                acc[i][j] = mfma16(af[i], bfv[j], acc[i][j]);
        __syncthreads();
    }
    #pragma unroll
    for (int i = 0; i < 4; ++i) {
        #pragma unroll
        for (int q = 0; q < 4; ++q) {
            const int row = m0 + wm * 64 + i * 16 + l4 * 4 + q;
            if (RESID) {
                const bf16* rr = resid + (size_t)row * ldc;
                #pragma unroll
                for (int j = 0; j < 4; ++j)
                    acc[i][j][q] += bf2f(*(const ushort*)(rr + n0 + wn * 64 + j * 16 + l15));
            }
            float s = 0.f, s2 = 0.f;
            #pragma unroll
            for (int j = 0; j < 4; ++j) {
                const float v = acc[i][j][q];
                s += v; s2 += v * v;
            }
            #pragma unroll
            for (int o = 1; o < 16; o <<= 1) {
                s  += __shfl_xor(s, o, 64);
                s2 += __shfl_xor(s2, o, 64);
            }
            if (l15 == 0)
                part[(size_t)row * nPH + (n0 >> 6) + wn] = make_float2(s, s2);
            bf16* cr = Cb + (size_t)row * ldc + n0 + wn * 64;
            #pragma unroll
            for (int j = 0; j < 4; ++j)
                cr[j * 16 + l15] = __float2bfloat16(acc[i][j][q]);
        }
    }
}

// ---------------- partial stats -> per-row (mean, inv-sigma) ----------------
__global__ void k_red(const float2* __restrict__ part, float2* __restrict__ stats,
                      int total, int nPH, int groups, float invD) {
    const int gid = blockIdx.x * 256 + threadIdx.x;
    if (gid >= total) return;
    const int proj = gid / MR, row = gid - proj * MR;
    const float2* p = part + (size_t)row * (nPH * groups) + proj * nPH;
    float s = 0.f, s2 = 0.f;
    for (int h = 0; h < nPH; ++h) { s += p[h].x; s2 += p[h].y; }
    const float mean = s * invD;
    const float var  = s2 * invD - mean * mean;
    stats[gid] = make_float2(mean, rsqrtf(var + 1e-6f));
}

// ---------------- V transpose + LN: qkv3 v-slice -> vt[bh][256][96] ---------
__global__ __launch_bounds__(256) void k_vt(const bf16* __restrict__ qkv3,
        const float2* __restrict__ vstats, const float* __restrict__ g,
        const float* __restrict__ bprm, bf16* __restrict__ vt) {
    __shared__ bf16 T[81 * 264];
    const int tid = threadIdx.x;
    const int bh = blockIdx.x;
    const int b = bh >> 2, h = bh & 3;
    const int brow = b * NE;
    const int hoff = h * DK;
    for (int gidx = tid; gidx < 81 * 32; gidx += 256) {
        const int m = gidx >> 5, c8 = gidx & 31;
        const int row = brow + m;
        const s16x8 vv = *(const s16x8*)(qkv3 + (size_t)row * QS + 2048 + hoff + c8 * 8);
        const float2 st = vstats[row];
        const int col0 = hoff + c8 * 8;
        const float4 g0 = *(const float4*)(g + col0), g1 = *(const float4*)(g + col0 + 4);
        const float4 b0 = *(const float4*)(bprm + col0), b1 = *(const float4*)(bprm + col0 + 4);
        const float ga[8] = { g0.x, g0.y, g0.z, g0.w, g1.x, g1.y, g1.z, g1.w };
        const float ba[8] = { b0.x, b0.y, b0.z, b0.w, b1.x, b1.y, b1.z, b1.w };
        short o[8];
        #pragma unroll
        for (int jj = 0; jj < 8; ++jj) {
            const float a = st.y * ga[jj];
            o[jj] = f2bs(bf2f((ushort)vv[jj]) * a + (ba[jj] - st.x * a));
        }
        *(s16x8*)(T + m * 264 + c8 * 8) = *(s16x8*)o;
    }
    __syncthreads();
    const int d = tid;
    bf16 row[96];
    #pragma unroll
    for (int m = 0; m < 81; ++m) row[m] = T[m * 264 + d];
    #pragma unroll
    for (int m = 81; m < 96; ++m) row[m] = __float2bfloat16(0.f);
    bf16* out = vt + ((size_t)bh * DK + d) * 96;
    #pragma unroll
    for (int g8 = 0; g8 < 12; ++g8)
        *(s16x8*)(out + g8 * 8) = *(const s16x8*)(&row[g8 * 8]);
}

// ---------------- attention v3: LN-on-the-fly Q/K, K in LDS -----------------
__global__ __launch_bounds__(512) void k_attn3(const bf16* __restrict__ qkv3,
        const float2* __restrict__ stats, const float* __restrict__ g,
        const float* __restrict__ bprm, const bf16* __restrict__ vt,
        bf16* __restrict__ nv) {
    __shared__ __align__(16) char smem[49152 + 96 * 104 * 2];
    char* Ks = smem;
    bf16* Pb = (bf16*)(smem + 49152);
    const int tid = threadIdx.x;
    const int bh = blockIdx.x;
    const int b = bh >> 2, h = bh & 3;
    const int brow = b * NE;
    const int hoff = h * DK;
    const int w = tid >> 6, l = tid & 63;
    const int l15 = l & 15, l4 = l >> 4;

    for (int gidx = tid; gidx < 96 * 32; gidx += 512) {
        const int r = gidx >> 5, c8 = gidx & 31;
        int krow = brow + r; if (krow >= MR) krow = MR - 1;
        const s16x8 kv = *(const s16x8*)(qkv3 + (size_t)krow * QS + 1024 + hoff + c8 * 8);
        const float2 st = stats[MR + krow];
        const int col0 = hoff + c8 * 8;
        const float4 g0 = *(const float4*)(g + col0), g1 = *(const float4*)(g + col0 + 4);
        const float4 b0 = *(const float4*)(bprm + col0), b1 = *(const float4*)(bprm + col0 + 4);
        const float ga[8] = { g0.x, g0.y, g0.z, g0.w, g1.x, g1.y, g1.z, g1.w };
        const float ba[8] = { b0.x, b0.y, b0.z, b0.w, b1.x, b1.y, b1.z, b1.w };
        short o[8];
        #pragma unroll
        for (int jj = 0; jj < 8; ++jj) {
            const float a = st.y * ga[jj];
            o[jj] = f2bs(bf2f((ushort)kv[jj]) * a + (ba[jj] - st.x * a));
        }
        *(s16x8*)(Ks + r * 512 + ((c8 ^ (r & 7)) << 4)) = *(s16x8*)o;
    }
    __syncthreads();

    if (w < 6) {
        int qrow = brow + w * 16 + l15; if (qrow >= MR) qrow = MR - 1;
        const float2 stq = stats[qrow];
        s16x8 qa[8];
        #pragma unroll
        for (int kk = 0; kk < 8; ++kk) {
            const int col0 = hoff + kk * 32 + l4 * 8;
            const s16x8 qv = *(const s16x8*)(qkv3 + (size_t)qrow * QS + col0);
            const float4 g0 = *(const float4*)(g + col0), g1 = *(const float4*)(g + col0 + 4);
            const float4 b0 = *(const float4*)(bprm + col0), b1 = *(const float4*)(bprm + col0 + 4);
            const float ga[8] = { g0.x, g0.y, g0.z, g0.w, g1.x, g1.y, g1.z, g1.w };
            const float ba[8] = { b0.x, b0.y, b0.z, b0.w, b1.x, b1.y, b1.z, b1.w };
            short o[8];
            #pragma unroll
            for (int jj = 0; jj < 8; ++jj) {
                const float a = stq.y * ga[jj];
                o[jj] = f2bs(bf2f((ushort)qv[jj]) * a + (ba[jj] - stq.x * a));
            }
            qa[kk] = *(s16x8*)o;
        }
        f32x4 sacc[6];
        #pragma unroll
        for (int j = 0; j < 6; ++j) {
            f32x4 a = {};
            const int rb = j * 16 + l15;
            #pragma unroll
            for (int kk = 0; kk < 8; ++kk) {
                const s16x8 kf = *(const s16x8*)(Ks + rb * 512 + (((kk * 4 + l4) ^ (rb & 7)) << 4));
                a = mfma16(qa[kk], kf, a);
            }
            sacc[j] = a;
        }
        float px[6][4];
        #pragma unroll
        for (int q = 0; q < 4; ++q) {
            float m = -1e30f;
            #pragma unroll
            for (int j = 0; j < 6; ++j) {
                const int key = j * 16 + l15;
                const float v = (key < NE) ? sacc[j][q] : -1e30f;
                px[j][q] = v;
                m = fmaxf(m, v);
            }
            #pragma unroll
            for (int o = 1; o < 16; o <<= 1) m = fmaxf(m, __shfl_xor(m, o, 64));
            float s = 0.f;
            #pragma unroll
            for (int j = 0; j < 6; ++j) {
                const float e = __expf((px[j][q] - m) * 0.0625f);
                px[j][q] = e; s += e;
            }
            #pragma unroll
            for (int o = 1; o < 16; o <<= 1) s += __shfl_xor(s, o, 64);
            const float r = 1.f / s;
            #pragma unroll
            for (int j = 0; j < 6; ++j) px[j][q] *= r;
        }
        #pragma unroll
        for (int j = 0; j < 6; ++j)
            #pragma unroll
            for (int q = 0; q < 4; ++q)
                Pb[(w * 16 + l4 * 4 + q) * 104 + j * 16 + l15] =
                    __float2bfloat16(px[j][q]);
    }
    __syncthreads();

    const bf16* vtb = vt + (size_t)bh * DK * 96;
    s16x8 vf[2][3];
    #pragma unroll
    for (int dj = 0; dj < 2; ++dj) {
        const int d = (2 * w + dj) * 16 + l15;
        #pragma unroll
        for (int ks = 0; ks < 3; ++ks)
            vf[dj][ks] = *(const s16x8*)(vtb + (size_t)d * 96 + (ks * 4 + l4) * 8);
    }
    f32x4 oacc[6][2] = {};
    #pragma unroll
    for (int i = 0; i < 6; ++i) {
        s16x8 pa[3];
        #pragma unroll
        for (int ks = 0; ks < 3; ++ks)
            pa[ks] = *(const s16x8*)(Pb + (i * 16 + l15) * 104 + (ks * 4 + l4) * 8);
        #pragma unroll
        for (int dj = 0; dj < 2; ++dj)
            #pragma unroll
            for (int ks = 0; ks < 3; ++ks)
                oacc[i][dj] = mfma16(pa[ks], vf[dj][ks], oacc[i][dj]);
    }
    #pragma unroll
    for (int i = 0; i < 6; ++i) {
        #pragma unroll
        for (int q = 0; q < 4; ++q) {
            const int n = i * 16 + l4 * 4 + q;
            if (n < NE) {
                #pragma unroll
                for (int dj = 0; dj < 2; ++dj) {
                    const int d = (2 * w + dj) * 16 + l15;
                    nv[(size_t)(brow + n) * HID + hoff + d] =
                        __float2bfloat16(oacc[i][dj][q]);
                }
            }
        }
    }
}

// ---------------- maxpool with fused LN + relu ------------------------------
__global__ void k_maxpool_ln(const bf16* __restrict__ X, const float2* __restrict__ st,
        const float* __restrict__ g, const float* __restrict__ bprm,
        float* __restrict__ P) {
    const int i = blockIdx.x * 256 + threadIdx.x;
    const int bb = i >> 9, c = i & 511;
    const float gc = g[c], bc = bprm[c];
    const bf16* xp = X + (size_t)bb * NE * DM + c;
    const float2* sp = st + (size_t)bb * NE;
    float mx = -1e30f;
    for (int n = 0; n < NE; ++n) {
        const float2 s = sp[n];
        const float a = s.y * gc;
        const float v = __bfloat162float(xp[(size_t)n * DM]) * a + (bc - s.x * a);
        mx = fmaxf(mx, fmaxf(v, 0.f));
    }
    P[i] = mx;
}

// ---------------- final mapping ---------------------------------------------
__global__ __launch_bounds__(256) void k_final(const float* __restrict__ P,
        const float* __restrict__ W, const float* __restrict__ bias,
        float* __restrict__ out) {
    const int bb = blockIdx.x;
    __shared__ float pr[DM];
    for (int i = threadIdx.x; i < DM; i += 256) pr[i] = P[(size_t)bb * DM + i];
    __syncthreads();
    const int o = threadIdx.x;
    const float4* w4 = (const float4*)(W + (size_t)o * DM);
    float acc = 0.f;
    for (int c4 = 0; c4 < DM / 4; ++c4) {
        const float4 wv = w4[c4];
        acc += wv.x * pr[c4 * 4] + wv.y * pr[c4 * 4 + 1]
             + wv.z * pr[c4 * 4 + 2] + wv.w * pr[c4 * 4 + 3];
    }
    out[(size_t)bb * ODIM + o] = lrelu_f(acc + bias[o]);
}

extern "C" void kernel_launch(void* const* d_in, const int* in_sizes, int n_in,
                              void* d_out, int out_size, void* d_ws, size_t ws_size,
                              hipStream_t stream) {
    const float* x   = (const float*)d_in[0];
    const float* w1  = (const float*)d_in[1];
    const float* b1  = (const float*)d_in[2];
    const float* w2  = (const float*)d_in[3];
    const float* b2  = (const float*)d_in[4];
    const float* wq  = (const float*)d_in[5];
    const float* wk  = (const float*)d_in[6];
    const float* wvv = (const float*)d_in[7];
    const float* lng = (const float*)d_in[8];
    const float* lnb = (const float*)d_in[9];
    const float* wo  = (const float*)d_in[10];
    const float* lg2 = (const float*)d_in[11];
    const float* lb2 = (const float*)d_in[12];
    const float* mw  = (const float*)d_in[13];
    const float* mb  = (const float*)d_in[14];

    char* ws = (char*)d_ws;
    size_t off = 0;
    auto alloc = [&](size_t bytes) {
        void* p = ws + off;
        off = (off + bytes + 255) & ~(size_t)255;
        return p;
    };
    bf16*   y1t   = (bf16*)  alloc((size_t)BB * P1 * 64 * 2);       // 13.1 MB
    bf16*   ebf   = (bf16*)  alloc((size_t)MR * DM * 2);            // 21.2 MB
    bf16*   qkv3  = (bf16*)  alloc((size_t)MR * QS * 2);            // 127.4 MB
    bf16*   vt    = (bf16*)  alloc((size_t)BB * NH * DK * 96 * 2);  // 50.3 MB
    bf16*   nv    = (bf16*)  alloc((size_t)MR * HID * 2);           // 42.5 MB
    bf16*   ao    = (bf16*)  alloc((size_t)MR * DM * 2);            // 21.2 MB
    float*  pool  = (float*) alloc((size_t)BB * DM * 4);
    float2* part1 = (float2*)alloc((size_t)MR * 48 * 8);            // 8 MB
    float2* part2 = (float2*)alloc((size_t)MR * 8 * 8);             // 1.3 MB
    float2* stQKV = (float2*)alloc((size_t)3 * MR * 8);             // 0.5 MB
    float2* st2   = (float2*)alloc((size_t)MR * 8);
    bf16*   w1b   = (bf16*)  alloc((size_t)C1 * CIN * 64 * 2);
    bf16*   w2b   = (bf16*)  alloc((size_t)512 * HID * 2);
    float*  b2p   = (float*) alloc(512 * 4);
    bf16*   wqkv  = (bf16*)  alloc((size_t)3072 * DM * 2);          // 3 MB
    bf16*   wob   = (bf16*)  alloc((size_t)DM * HID * 2);           // 1 MB
    float*  outp  = (float*)d_out;

    // fused weight prep
    k_prep<<<4166, 256, 0, stream>>>(w1, w2, b2, wq, wk, wvv, wo,
                                     w1b, w2b, b2p, wqkv, wob);

    // conv1 -> y1t bf16
    k_conv1_mfma<<<BB, 512, 0, stream>>>(x, w1b, b1, y1t);

    // conv2 (implicit im2col, +bias +lrelu, coord fused) -> ebf
    k_gemm_conv2<<<dim3(4, MR / 128), 256, 0, stream>>>(y1t, w2b, b2p, ebf);

    // QKV projection GEMM (BK=32 round-4 structure, no swizzle) + partials
    k_gemm32<0><<<dim3(24, MR / 128), 256, 0, stream>>>(ebf, wqkv, nullptr,
                                                        qkv3, part1, DM, QS, 48);
    k_red<<<(3 * MR + 255) / 256, 256, 0, stream>>>(part1, stQKV, 3 * MR, 16, 3,
                                                    1.f / 1024.f);

    // V transpose + LN -> vt
    k_vt<<<BB * NH, 256, 0, stream>>>(qkv3, stQKV + 2 * MR, lng, lnb, vt);

    // attention (LN applied on the fly for Q and K)
    k_attn3<<<BB * NH, 512, 0, stream>>>(qkv3, stQKV, lng, lnb, vt, nv);

    // out projection + residual + partials (BK=32, no swizzle)
    k_gemm32<1><<<dim3(4, MR / 128), 256, 0, stream>>>(nv, wob, ebf,
                                                       ao, part2, HID, DM, 8);
    k_red<<<(MR + 255) / 256, 256, 0, stream>>>(part2, st2, MR, 8, 1, 1.f / 512.f);

    // maxpool with fused LN + relu
    k_maxpool_ln<<<(BB * DM) / 256, 256, 0, stream>>>(ao, st2, lg2, lb2, pool);
    k_final<<<BB, 256, 0, stream>>>(pool, mw, mb, outp);
}

// Round 12
// 361.986 us; speedup vs baseline: 1.0681x; 1.0681x over previous
//
#include <hip/hip_runtime.h>
#include <hip/hip_bf16.h>
#include <math.h>

typedef __hip_bfloat16 bf16;
using f32x4 = __attribute__((ext_vector_type(4))) float;
using s16x8 = __attribute__((ext_vector_type(8))) short;

#define DEV_INLINE __device__ __forceinline__

static constexpr int BB   = 256;
static constexpr int CIN  = 17;
static constexpr int WIN  = 84;
static constexpr int C1   = 64;
static constexpr int W1   = 20;
static constexpr int P1   = W1 * W1;     // 400
static constexpr int C2   = 510;
static constexpr int W2   = 9;
static constexpr int NE   = 81;
static constexpr int DM   = 512;
static constexpr int HID  = 1024;
static constexpr int NH   = 4;
static constexpr int DK   = 256;
static constexpr int MR   = BB * NE;     // 20736
static constexpr int ODIM = 256;
static constexpr int PLANE = WIN * WIN;  // 7056
static constexpr int QS   = 3 * HID;     // 3072

DEV_INLINE float lrelu_f(float v) { return v > 0.f ? v : 0.1f * v; }
DEV_INLINE float bf2f(ushort u) { return __uint_as_float((unsigned)u << 16); }
DEV_INLINE short f2bs(float f) { bf16 t = __float2bfloat16(f); return *reinterpret_cast<short*>(&t); }

DEV_INLINE void gll16(const void* g, const void* l) {
    __builtin_amdgcn_global_load_lds(
        (const __attribute__((address_space(1))) unsigned int*)g,
        (__attribute__((address_space(3))) unsigned int*)l, 16, 0, 0);
}
DEV_INLINE f32x4 mfma16(s16x8 a, s16x8 b, f32x4 c) {
    return __builtin_amdgcn_mfma_f32_16x16x32_bf16(a, b, c, 0, 0, 0);
}

// ---------------- fused weight prep (all casts/packs in ONE launch) ---------
__global__ void k_prep(const float* __restrict__ w1, const float* __restrict__ w2,
        const float* __restrict__ b2, const float* __restrict__ wq,
        const float* __restrict__ wk, const float* __restrict__ wv,
        const float* __restrict__ wo, bf16* __restrict__ w1b,
        bf16* __restrict__ w2b, float* __restrict__ b2p,
        bf16* __restrict__ wqkv, bf16* __restrict__ wob) {
    int i = blockIdx.x * 256 + threadIdx.x;
    if (i < 17408) {
        const size_t o = (size_t)i * 4;
        const float4 v = *(const float4*)(w1 + o);
        short r[4] = { f2bs(v.x), f2bs(v.y), f2bs(v.z), f2bs(v.w) };
        *(ushort4*)(w1b + o) = *(ushort4*)r;
        return;
    }
    i -= 17408;
    if (i < 524288) {   // w2 cast + K-permute to (kh,kw,ic), zero-pad rows 510/511
        const int n = i >> 10, rem = i & 1023;
        const int khkw = rem >> 6, ic = rem & 63;
        w2b[i] = (n < C2) ? __float2bfloat16(w2[n * 1024 + ic * 16 + khkw])
                          : __float2bfloat16(0.f);
        return;
    }
    i -= 524288;
    if (i < 512) { b2p[i] = (i < C2) ? b2[i] : 0.f; return; }
    i -= 512;
    if (i < 393216) {   // wq|wk|wv concat -> wqkv[3072][512]
        const size_t o = (size_t)i * 4;
        const int n = (int)(o >> 9), c = (int)(o & 511);
        const float* src = (n < 1024) ? wq : (n < 2048) ? wk : wv;
        const float4 v = *(const float4*)(src + (size_t)(n & 1023) * 512 + c);
        short r[4] = { f2bs(v.x), f2bs(v.y), f2bs(v.z), f2bs(v.w) };
        *(ushort4*)(wqkv + o) = *(ushort4*)r;
        return;
    }
    i -= 393216;
    if (i < 131072) {
        const size_t o = (size_t)i * 4;
        const float4 v = *(const float4*)(wo + o);
        short r[4] = { f2bs(v.x), f2bs(v.y), f2bs(v.z), f2bs(v.w) };
        *(ushort4*)(wob + o) = *(ushort4*)r;
    }
}

// ---------------- conv1 as implicit-GEMM MFMA -------------------------------
__global__ __launch_bounds__(512, 1) void k_conv1_mfma(const float* __restrict__ x,
        const bf16* __restrict__ w1b, const float* __restrict__ bias,
        bf16* __restrict__ y1t) {
    __shared__ __align__(16) char pl[2][28224];
    const int b = blockIdx.x;
    const int tid = threadIdx.x;
    const int w = tid >> 6, l = tid & 63;
    const int l15 = l & 15, l4 = l >> 4;
    const float* xb = x + (size_t)b * CIN * PLANE;

    int baseA[4], tval[4];
    #pragma unroll
    for (int j = 0; j < 4; ++j) {
        const int t = w + 8 * j; tval[j] = t;
        int p = t * 16 + l15; if (t >= 25) p = 0;
        const int oh = p / 20, ow = p % 20;
        baseA[j] = (oh * 4 + l4) * 336 + ow * 16;
    }
    float bias_r[4];
    #pragma unroll
    for (int nt = 0; nt < 4; ++nt) bias_r[nt] = bias[nt * 16 + l15];

    #pragma unroll
    for (int it = 0; it < 4; ++it) {
        const int g = it * 512 + tid;
        if (g < 1764) gll16(xb + (size_t)g * 4, pl[0] + (size_t)g * 16);
    }
    __syncthreads();

    f32x4 acc[4][4] = {};
    int cur = 0;
    for (int ic = 0; ic < CIN; ++ic) {
        if (ic + 1 < CIN) {
            const float* src = xb + (size_t)(ic + 1) * PLANE;
            #pragma unroll
            for (int it = 0; it < 4; ++it) {
                const int g = it * 512 + tid;
                if (g < 1764) gll16(src + (size_t)g * 4, pl[cur ^ 1] + (size_t)g * 16);
            }
        }
        s16x8 bq[4][2];
        #pragma unroll
        for (int nt = 0; nt < 4; ++nt)
            #pragma unroll
            for (int ks = 0; ks < 2; ++ks)
                bq[nt][ks] = *(const s16x8*)(w1b + (size_t)(nt * 16 + l15) * 1088
                                             + ic * 64 + (ks * 4 + l4) * 8);
        const char* P = pl[cur];
        #pragma unroll
        for (int j = 0; j < 4; ++j) {
            if (tval[j] < 25) {
                #pragma unroll
                for (int ks = 0; ks < 2; ++ks) {
                    const float* fp = (const float*)(P + baseA[j] + ks * 1344);
                    const f32x4 f0 = *(const f32x4*)fp;
                    const f32x4 f1 = *(const f32x4*)(fp + 4);
                    s16x8 af;
                    #pragma unroll
                    for (int jj = 0; jj < 4; ++jj) {
                        af[jj]     = f2bs(f0[jj]);
                        af[jj + 4] = f2bs(f1[jj]);
                    }
                    #pragma unroll
                    for (int nt = 0; nt < 4; ++nt)
                        acc[j][nt] = mfma16(af, bq[nt][ks], acc[j][nt]);
                }
            }
        }
        __syncthreads();
        cur ^= 1;
    }
    #pragma unroll
    for (int j = 0; j < 4; ++j) {
        if (tval[j] < 25) {
            #pragma unroll
            for (int nt = 0; nt < 4; ++nt) {
                #pragma unroll
                for (int q = 0; q < 4; ++q) {
                    const int pix = tval[j] * 16 + l4 * 4 + q;
                    const int oc  = nt * 16 + l15;
                    y1t[((size_t)b * P1 + pix) * 64 + oc] =
                        __float2bfloat16(lrelu_f(acc[j][nt][q] + bias_r[nt]));
                }
            }
        }
    }
}

// ---------------- conv2 GEMM (128x128, dbuf pipeline, implicit im2col) ------
__global__ __launch_bounds__(256) void k_gemm_conv2(const bf16* __restrict__ A,
        const bf16* __restrict__ B, const float* __restrict__ bias,
        bf16* __restrict__ Cb) {
    __shared__ __align__(16) char Asm[2][128 * 64];
    __shared__ __align__(16) char Bsm[2][128 * 64];
    const int tid = threadIdx.x;
    const int m0 = blockIdx.y * 128, n0 = blockIdx.x * 128;
    const int w = tid >> 6, l = tid & 63;
    const int wm = w >> 1, wn = w & 1;
    const int l15 = l & 15, l4 = l >> 4;
    const int r0 = tid >> 2, p0 = tid & 3;
    const int r1 = 64 + r0;
    const int sw0 = (p0 ^ ((r0 >> 1) & 3)) << 3;
    const int sw1 = (p0 ^ ((r1 >> 1) & 3)) << 3;
    int bimg[2], ohh[2], oww[2];
    #pragma unroll
    for (int it = 0; it < 2; ++it) {
        const int m = m0 + (it ? r1 : r0);
        bimg[it] = m / 81;
        const int n = m - bimg[it] * 81;
        ohh[it] = n / 9; oww[it] = n - ohh[it] * 9;
    }
    auto stage = [&](int buf, int k0) {
        const int khkw = k0 >> 6, icb = k0 & 63;
        const int kh = khkw >> 2, kwv = khkw & 3;
        const int pix0 = (ohh[0] * 2 + kh) * 20 + oww[0] * 2 + kwv;
        const int pix1 = (ohh[1] * 2 + kh) * 20 + oww[1] * 2 + kwv;
        gll16(A + ((size_t)bimg[0] * P1 + pix0) * 64 + icb + sw0, Asm[buf] + tid * 16);
        gll16(A + ((size_t)bimg[1] * P1 + pix1) * 64 + icb + sw1, Asm[buf] + (256 + tid) * 16);
        gll16(B + (size_t)(n0 + r0) * HID + k0 + sw0, Bsm[buf] + tid * 16);
        gll16(B + (size_t)(n0 + r1) * HID + k0 + sw1, Bsm[buf] + (256 + tid) * 16);
    };
    stage(0, 0);
    __syncthreads();
    f32x4 acc[4][4] = {};
    int cur = 0;
    for (int t = 0; t < 32; ++t) {
        if (t < 31) stage(cur ^ 1, (t + 1) * 32);
        s16x8 af[4], bfv[4];
        #pragma unroll
        for (int i = 0; i < 4; ++i) {
            const int ra = wm * 64 + i * 16 + l15;
            af[i]  = *(const s16x8*)(Asm[cur] + ra * 64 + ((l4 ^ ((ra >> 1) & 3)) << 4));
            const int rb = wn * 64 + i * 16 + l15;
            bfv[i] = *(const s16x8*)(Bsm[cur] + rb * 64 + ((l4 ^ ((rb >> 1) & 3)) << 4));
        }
        #pragma unroll
        for (int i = 0; i < 4; ++i)
            #pragma unroll
            for (int j = 0; j < 4; ++j)
                acc[i][j] = mfma16(af[i], bfv[j], acc[i][j]);
        __syncthreads();
        cur ^= 1;
    }
    #pragma unroll
    for (int i = 0; i < 4; ++i) {
        #pragma unroll
        for (int j = 0; j < 4; ++j) {
            const int col = n0 + wn * 64 + j * 16 + l15;
            #pragma unroll
            for (int q = 0; q < 4; ++q) {
                const int row = m0 + wm * 64 + i * 16 + l4 * 4 + q;
                float v = lrelu_f(acc[i][j][q] + bias[col]);
                if (col >= 510) {
                    const int n = row % 81;
                    v = (col == 510) ? (float)(n / 9) * (1.f / 9.f)
                                     : (float)(n % 9) * (1.f / 9.f);
                }
                Cb[(size_t)row * DM + col] = __float2bfloat16(v);
            }
        }
    }
}

// ============ QKV GEMM: 256x256 8-phase (T3+T4+T5), BK=64, 8 waves ==========
// Round-9 verbatim (best measured with fused stats: 126us, total 371).
#define QKV_PHASE(QD, STAGING, TAIL)                                           \
    {                                                                          \
        s16x8 areg[2][2];                                                      \
        _Pragma("unroll")                                                      \
        for (int ii = 0; ii < 2; ++ii) {                                       \
            const int fr = QD * 32 + ii * 16 + l15;                            \
            _Pragma("unroll")                                                  \
            for (int kk = 0; kk < 2; ++kk)                                     \
                areg[ii][kk] = *(const s16x8*)(Abase + fr * 128 +              \
                                   (((kk * 4 + l4) ^ (fr & 7)) << 4));         \
        }                                                                      \
        STAGING;                                                               \
        __builtin_amdgcn_s_barrier();                                          \
        asm volatile("s_waitcnt lgkmcnt(0)" ::: "memory");                     \
        __builtin_amdgcn_sched_barrier(0);                                     \
        __builtin_amdgcn_s_setprio(1);                                         \
        _Pragma("unroll")                                                      \
        for (int ii = 0; ii < 2; ++ii)                                         \
            _Pragma("unroll")                                                  \
            for (int j = 0; j < 4; ++j)                                        \
                _Pragma("unroll")                                              \
                for (int kk = 0; kk < 2; ++kk)                                 \
                    acc[QD * 2 + ii][j] =                                      \
                        mfma16(areg[ii][kk], breg[j][kk], acc[QD * 2 + ii][j]);\
        __builtin_amdgcn_s_setprio(0);                                         \
        TAIL;                                                                  \
        __builtin_amdgcn_s_barrier();                                          \
        __builtin_amdgcn_sched_barrier(0);                                     \
    }

__global__ __launch_bounds__(512, 2) void k_gemm_qkv8(const bf16* __restrict__ A,
        const bf16* __restrict__ B, bf16* __restrict__ Cb,
        float2* __restrict__ part) {
    __shared__ __align__(16) char lds[131072];
    const int tid = threadIdx.x;
    const int m0 = blockIdx.y * 256, n0 = blockIdx.x * 256;
    const int wid = tid >> 6, l = tid & 63;
    const int wm = wid >> 2, wn = wid & 3;
    const int l15 = l & 15, l4 = l >> 4;
    const int rA = tid >> 3, pA = tid & 7;

    auto stageA = [&](int buf, int kt, int qa) {
        char* dst = lds + buf * 32768 + (qa >> 1) * 16384 + (qa & 1) * 8192 + tid * 16;
        gll16(A + (size_t)(m0 + qa * 64 + rA) * 512 + kt * 64 + ((pA ^ (rA & 7)) << 3), dst);
    };
    auto stageB = [&](int buf, int kt, int hb) {
        char* base = lds + 65536 + buf * 32768 + hb * 16384;
        #pragma unroll
        for (int i2 = 0; i2 < 2; ++i2) {
            const int s = i2 * 512 + tid;
            const int c = s >> 3, pp = s & 7;
            gll16(B + (size_t)(n0 + hb * 128 + c) * 512 + kt * 64 + ((pp ^ (c & 7)) << 3),
                  base + s * 16);
        }
    };

    stageA(0, 0, 0); stageA(0, 0, 1); stageA(0, 0, 2); stageA(0, 0, 3);
    stageB(0, 0, 0); stageB(0, 0, 1);
    stageB(1, 1, 0); stageB(1, 1, 1);
    stageA(1, 1, 0); stageA(1, 1, 2);
    asm volatile("s_waitcnt vmcnt(6)" ::: "memory");
    __builtin_amdgcn_s_barrier();
    __builtin_amdgcn_sched_barrier(0);

    f32x4 acc[8][4] = {};
    for (int kt = 0; kt < 8; ++kt) {
        const int cur = kt & 1;
        const char* Abase = lds + cur * 32768 + wm * 16384;
        const char* Bbase = lds + 65536 + cur * 32768 + (wn >> 1) * 16384;
        s16x8 breg[4][2];
        #pragma unroll
        for (int j = 0; j < 4; ++j) {
            const int fc = (wn & 1) * 64 + j * 16 + l15;
            #pragma unroll
            for (int kk = 0; kk < 2; ++kk)
                breg[j][kk] = *(const s16x8*)(Bbase + fc * 128 +
                                  (((kk * 4 + l4) ^ (fc & 7)) << 4));
        }
        QKV_PHASE(0, { if (kt + 1 < 8) { stageA(cur ^ 1, kt + 1, 1); stageA(cur ^ 1, kt + 1, 3); } }, {})
        QKV_PHASE(1, { if (kt + 2 < 8) { stageB(cur, kt + 2, 0); } }, {})
        QKV_PHASE(2, { if (kt + 2 < 8) { stageB(cur, kt + 2, 1); stageA(cur, kt + 2, 0); stageA(cur, kt + 2, 2); } }, {})
        QKV_PHASE(3, { }, {
            if (kt < 6)       { asm volatile("s_waitcnt vmcnt(6)" ::: "memory"); }
            else if (kt == 6) { asm volatile("s_waitcnt vmcnt(0)" ::: "memory"); }
        })
    }

    #pragma unroll
    for (int fi = 0; fi < 8; ++fi) {
        #pragma unroll
        for (int q = 0; q < 4; ++q) {
            const int row = m0 + wm * 128 + fi * 16 + l4 * 4 + q;
            float s = 0.f, s2 = 0.f;
            #pragma unroll
            for (int j = 0; j < 4; ++j) {
                const float v = acc[fi][j][q];
                s += v; s2 += v * v;
            }
            #pragma unroll
            for (int o = 1; o < 16; o <<= 1) {
                s  += __shfl_xor(s, o, 64);
                s2 += __shfl_xor(s2, o, 64);
            }
            if (l15 == 0)
                part[(size_t)row * 48 + blockIdx.x * 4 + wn] = make_float2(s, s2);
            bf16* cr = Cb + (size_t)row * QS + n0 + wn * 64;
            #pragma unroll
            for (int j = 0; j < 4; ++j)
                cr[j * 16 + l15] = __float2bfloat16(acc[fi][j][q]);
        }
    }
}

// ---------------- GEMM 128x128, BK=64, dbuf, + row-partial stats (out-proj) -
template <int RESID>
__global__ __launch_bounds__(256) void k_gemm_stats(const bf16* __restrict__ A,
        const bf16* __restrict__ B, const bf16* __restrict__ resid,
        bf16* __restrict__ Cb, float2* __restrict__ part,
        int K, int ldc, int nPH) {
    __shared__ __align__(16) char Asm[2][16384];
    __shared__ __align__(16) char Bsm[2][16384];
    const int tid = threadIdx.x;
    const int m0 = blockIdx.y * 128, n0 = blockIdx.x * 128;
    const int w = tid >> 6, l = tid & 63;
    const int wm = w >> 1, wn = w & 1;
    const int l15 = l & 15, l4 = l >> 4;

    auto stage = [&](int buf, int k0) {
        #pragma unroll
        for (int it = 0; it < 4; ++it) {
            const int g = it * 256 + tid;
            const int r = g >> 3, p = g & 7;
            const int sw = (p ^ (r & 7)) << 3;
            gll16(A + (size_t)(m0 + r) * K + k0 + sw, Asm[buf] + g * 16);
            gll16(B + (size_t)(n0 + r) * K + k0 + sw, Bsm[buf] + g * 16);
        }
    };
    stage(0, 0);
    __syncthreads();
    f32x4 acc[4][4] = {};
    int cur = 0;
    const int nt = K >> 6;
    for (int t = 0; t < nt; ++t) {
        if (t + 1 < nt) stage(cur ^ 1, (t + 1) * 64);
        #pragma unroll
        for (int kk = 0; kk < 2; ++kk) {
            s16x8 af[4], bfv[4];
            const int pz = kk * 4 + l4;
            #pragma unroll
            for (int i = 0; i < 4; ++i) {
                const int ra = wm * 64 + i * 16 + l15;
                af[i]  = *(const s16x8*)(Asm[cur] + ra * 128 + ((pz ^ (ra & 7)) << 4));
                const int rb = wn * 64 + i * 16 + l15;
                bfv[i] = *(const s16x8*)(Bsm[cur] + rb * 128 + ((pz ^ (rb & 7)) << 4));
            }
            #pragma unroll
            for (int i = 0; i < 4; ++i)
                #pragma unroll
                for (int j = 0; j < 4; ++j)
                    acc[i][j] = mfma16(af[i], bfv[j], acc[i][j]);
        }
        __syncthreads();
        cur ^= 1;
    }
    #pragma unroll
    for (int i = 0; i < 4; ++i) {
        #pragma unroll
        for (int q = 0; q < 4; ++q) {
            const int row = m0 + wm * 64 + i * 16 + l4 * 4 + q;
            if (RESID) {
                const bf16* rr = resid + (size_t)row * ldc;
                #pragma unroll
                for (int j = 0; j < 4; ++j)
                    acc[i][j][q] += bf2f(*(const ushort*)(rr + n0 + wn * 64 + j * 16 + l15));
            }
            float s = 0.f, s2 = 0.f;
            #pragma unroll
            for (int j = 0; j < 4; ++j) {
                const float v = acc[i][j][q];
                s += v; s2 += v * v;
            }
            #pragma unroll
            for (int o = 1; o < 16; o <<= 1) {
                s  += __shfl_xor(s, o, 64);
                s2 += __shfl_xor(s2, o, 64);
            }
            if (l15 == 0)
                part[(size_t)row * nPH + (n0 >> 6) + wn] = make_float2(s, s2);
            bf16* cr = Cb + (size_t)row * ldc + n0 + wn * 64;
            #pragma unroll
            for (int j = 0; j < 4; ++j)
                cr[j * 16 + l15] = __float2bfloat16(acc[i][j][q]);
        }
    }
}

// ---------------- partial stats -> per-row (mean, inv-sigma) ----------------
__global__ void k_red(const float2* __restrict__ part, float2* __restrict__ stats,
                      int total, int nPH, int groups, float invD) {
    const int gid = blockIdx.x * 256 + threadIdx.x;
    if (gid >= total) return;
    const int proj = gid / MR, row = gid - proj * MR;
    const float2* p = part + (size_t)row * (nPH * groups) + proj * nPH;
    float s = 0.f, s2 = 0.f;
    for (int h = 0; h < nPH; ++h) { s += p[h].x; s2 += p[h].y; }
    const float mean = s * invD;
    const float var  = s2 * invD - mean * mean;
    stats[gid] = make_float2(mean, rsqrtf(var + 1e-6f));
}

// ---------------- V transpose + LN: qkv3 v-slice -> vt[bh][256][96] ---------
__global__ __launch_bounds__(256) void k_vt(const bf16* __restrict__ qkv3,
        const float2* __restrict__ vstats, const float* __restrict__ g,
        const float* __restrict__ bprm, bf16* __restrict__ vt) {
    __shared__ bf16 T[81 * 264];
    const int tid = threadIdx.x;
    const int bh = blockIdx.x;
    const int b = bh >> 2, h = bh & 3;
    const int brow = b * NE;
    const int hoff = h * DK;
    for (int gidx = tid; gidx < 81 * 32; gidx += 256) {
        const int m = gidx >> 5, c8 = gidx & 31;
        const int row = brow + m;
        const s16x8 vv = *(const s16x8*)(qkv3 + (size_t)row * QS + 2048 + hoff + c8 * 8);
        const float2 st = vstats[row];
        const int col0 = hoff + c8 * 8;
        const float4 g0 = *(const float4*)(g + col0), g1 = *(const float4*)(g + col0 + 4);
        const float4 b0 = *(const float4*)(bprm + col0), b1 = *(const float4*)(bprm + col0 + 4);
        const float ga[8] = { g0.x, g0.y, g0.z, g0.w, g1.x, g1.y, g1.z, g1.w };
        const float ba[8] = { b0.x, b0.y, b0.z, b0.w, b1.x, b1.y, b1.z, b1.w };
        short o[8];
        #pragma unroll
        for (int jj = 0; jj < 8; ++jj) {
            const float a = st.y * ga[jj];
            o[jj] = f2bs(bf2f((ushort)vv[jj]) * a + (ba[jj] - st.x * a));
        }
        *(s16x8*)(T + m * 264 + c8 * 8) = *(s16x8*)o;
    }
    __syncthreads();
    const int d = tid;
    bf16 row[96];
    #pragma unroll
    for (int m = 0; m < 81; ++m) row[m] = T[m * 264 + d];
    #pragma unroll
    for (int m = 81; m < 96; ++m) row[m] = __float2bfloat16(0.f);
    bf16* out = vt + ((size_t)bh * DK + d) * 96;
    #pragma unroll
    for (int g8 = 0; g8 < 12; ++g8)
        *(s16x8*)(out + g8 * 8) = *(const s16x8*)(&row[g8 * 8]);
}

// ---------------- attention v3: LN-on-the-fly Q/K, K in LDS -----------------
__global__ __launch_bounds__(512) void k_attn3(const bf16* __restrict__ qkv3,
        const float2* __restrict__ stats, const float* __restrict__ g,
        const float* __restrict__ bprm, const bf16* __restrict__ vt,
        bf16* __restrict__ nv) {
    __shared__ __align__(16) char smem[49152 + 96 * 104 * 2];
    char* Ks = smem;
    bf16* Pb = (bf16*)(smem + 49152);
    const int tid = threadIdx.x;
    const int bh = blockIdx.x;
    const int b = bh >> 2, h = bh & 3;
    const int brow = b * NE;
    const int hoff = h * DK;
    const int w = tid >> 6, l = tid & 63;
    const int l15 = l & 15, l4 = l >> 4;

    for (int gidx = tid; gidx < 96 * 32; gidx += 512) {
        const int r = gidx >> 5, c8 = gidx & 31;
        int krow = brow + r; if (krow >= MR) krow = MR - 1;
        const s16x8 kv = *(const s16x8*)(qkv3 + (size_t)krow * QS + 1024 + hoff + c8 * 8);
        const float2 st = stats[MR + krow];
        const int col0 = hoff + c8 * 8;
        const float4 g0 = *(const float4*)(g + col0), g1 = *(const float4*)(g + col0 + 4);
        const float4 b0 = *(const float4*)(bprm + col0), b1 = *(const float4*)(bprm + col0 + 4);
        const float ga[8] = { g0.x, g0.y, g0.z, g0.w, g1.x, g1.y, g1.z, g1.w };
        const float ba[8] = { b0.x, b0.y, b0.z, b0.w, b1.x, b1.y, b1.z, b1.w };
        short o[8];
        #pragma unroll
        for (int jj = 0; jj < 8; ++jj) {
            const float a = st.y * ga[jj];
            o[jj] = f2bs(bf2f((ushort)kv[jj]) * a + (ba[jj] - st.x * a));
        }
        *(s16x8*)(Ks + r * 512 + ((c8 ^ (r & 7)) << 4)) = *(s16x8*)o;
    }
    __syncthreads();

    if (w < 6) {
        int qrow = brow + w * 16 + l15; if (qrow >= MR) qrow = MR - 1;
        const float2 stq = stats[qrow];
        s16x8 qa[8];
        #pragma unroll
        for (int kk = 0; kk < 8; ++kk) {
            const int col0 = hoff + kk * 32 + l4 * 8;
            const s16x8 qv = *(const s16x8*)(qkv3 + (size_t)qrow * QS + col0);
            const float4 g0 = *(const float4*)(g + col0), g1 = *(const float4*)(g + col0 + 4);
            const float4 b0 = *(const float4*)(bprm + col0), b1 = *(const float4*)(bprm + col0 + 4);
            const float ga[8] = { g0.x, g0.y, g0.z, g0.w, g1.x, g1.y, g1.z, g1.w };
            const float ba[8] = { b0.x, b0.y, b0.z, b0.w, b1.x, b1.y, b1.z, b1.w };
            short o[8];
            #pragma unroll
            for (int jj = 0; jj < 8; ++jj) {
                const float a = stq.y * ga[jj];
                o[jj] = f2bs(bf2f((ushort)qv[jj]) * a + (ba[jj] - stq.x * a));
            }
            qa[kk] = *(s16x8*)o;
        }
        f32x4 sacc[6];
        #pragma unroll
        for (int j = 0; j < 6; ++j) {
            f32x4 a = {};
            const int rb = j * 16 + l15;
            #pragma unroll
            for (int kk = 0; kk < 8; ++kk) {
                const s16x8 kf = *(const s16x8*)(Ks + rb * 512 + (((kk * 4 + l4) ^ (rb & 7)) << 4));
                a = mfma16(qa[kk], kf, a);
            }
            sacc[j] = a;
        }
        float px[6][4];
        #pragma unroll
        for (int q = 0; q < 4; ++q) {
            float m = -1e30f;
            #pragma unroll
            for (int j = 0; j < 6; ++j) {
                const int key = j * 16 + l15;
                const float v = (key < NE) ? sacc[j][q] : -1e30f;
                px[j][q] = v;
                m = fmaxf(m, v);
            }
            #pragma unroll
            for (int o = 1; o < 16; o <<= 1) m = fmaxf(m, __shfl_xor(m, o, 64));
            float s = 0.f;
            #pragma unroll
            for (int j = 0; j < 6; ++j) {
                const float e = __expf((px[j][q] - m) * 0.0625f);
                px[j][q] = e; s += e;
            }
            #pragma unroll
            for (int o = 1; o < 16; o <<= 1) s += __shfl_xor(s, o, 64);
            const float r = 1.f / s;
            #pragma unroll
            for (int j = 0; j < 6; ++j) px[j][q] *= r;
        }
        #pragma unroll
        for (int j = 0; j < 6; ++j)
            #pragma unroll
            for (int q = 0; q < 4; ++q)
                Pb[(w * 16 + l4 * 4 + q) * 104 + j * 16 + l15] =
                    __float2bfloat16(px[j][q]);
    }
    __syncthreads();

    const bf16* vtb = vt + (size_t)bh * DK * 96;
    s16x8 vf[2][3];
    #pragma unroll
    for (int dj = 0; dj < 2; ++dj) {
        const int d = (2 * w + dj) * 16 + l15;
        #pragma unroll
        for (int ks = 0; ks < 3; ++ks)
            vf[dj][ks] = *(const s16x8*)(vtb + (size_t)d * 96 + (ks * 4 + l4) * 8);
    }
    f32x4 oacc[6][2] = {};
    #pragma unroll
    for (int i = 0; i < 6; ++i) {
        s16x8 pa[3];
        #pragma unroll
        for (int ks = 0; ks < 3; ++ks)
            pa[ks] = *(const s16x8*)(Pb + (i * 16 + l15) * 104 + (ks * 4 + l4) * 8);
        #pragma unroll
        for (int dj = 0; dj < 2; ++dj)
            #pragma unroll
            for (int ks = 0; ks < 3; ++ks)
                oacc[i][dj] = mfma16(pa[ks], vf[dj][ks], oacc[i][dj]);
    }
    #pragma unroll
    for (int i = 0; i < 6; ++i) {
        #pragma unroll
        for (int q = 0; q < 4; ++q) {
            const int n = i * 16 + l4 * 4 + q;
            if (n < NE) {
                #pragma unroll
                for (int dj = 0; dj < 2; ++dj) {
                    const int d = (2 * w + dj) * 16 + l15;
                    nv[(size_t)(brow + n) * HID + hoff + d] =
                        __float2bfloat16(oacc[i][dj][q]);
                }
            }
        }
    }
}

// ---------------- maxpool with fused LN + relu ------------------------------
__global__ void k_maxpool_ln(const bf16* __restrict__ X, const float2* __restrict__ st,
        const float* __restrict__ g, const float* __restrict__ bprm,
        float* __restrict__ P) {
    const int i = blockIdx.x * 256 + threadIdx.x;
    const int bb = i >> 9, c = i & 511;
    const float gc = g[c], bc = bprm[c];
    const bf16* xp = X + (size_t)bb * NE * DM + c;
    const float2* sp = st + (size_t)bb * NE;
    float mx = -1e30f;
    for (int n = 0; n < NE; ++n) {
        const float2 s = sp[n];
        const float a = s.y * gc;
        const float v = __bfloat162float(xp[(size_t)n * DM]) * a + (bc - s.x * a);
        mx = fmaxf(mx, fmaxf(v, 0.f));
    }
    P[i] = mx;
}

// ---------------- final mapping ---------------------------------------------
__global__ __launch_bounds__(256) void k_final(const float* __restrict__ P,
        const float* __restrict__ W, const float* __restrict__ bias,
        float* __restrict__ out) {
    const int bb = blockIdx.x;
    __shared__ float pr[DM];
    for (int i = threadIdx.x; i < DM; i += 256) pr[i] = P[(size_t)bb * DM + i];
    __syncthreads();
    const int o = threadIdx.x;
    const float4* w4 = (const float4*)(W + (size_t)o * DM);
    float acc = 0.f;
    for (int c4 = 0; c4 < DM / 4; ++c4) {
        const float4 wv = w4[c4];
        acc += wv.x * pr[c4 * 4] + wv.y * pr[c4 * 4 + 1]
             + wv.z * pr[c4 * 4 + 2] + wv.w * pr[c4 * 4 + 3];
    }
    out[(size_t)bb * ODIM + o] = lrelu_f(acc + bias[o]);
}

extern "C" void kernel_launch(void* const* d_in, const int* in_sizes, int n_in,
                              void* d_out, int out_size, void* d_ws, size_t ws_size,
                              hipStream_t stream) {
    const float* x   = (const float*)d_in[0];
    const float* w1  = (const float*)d_in[1];
    const float* b1  = (const float*)d_in[2];
    const float* w2  = (const float*)d_in[3];
    const float* b2  = (const float*)d_in[4];
    const float* wq  = (const float*)d_in[5];
    const float* wk  = (const float*)d_in[6];
    const float* wvv = (const float*)d_in[7];
    const float* lng = (const float*)d_in[8];
    const float* lnb = (const float*)d_in[9];
    const float* wo  = (const float*)d_in[10];
    const float* lg2 = (const float*)d_in[11];
    const float* lb2 = (const float*)d_in[12];
    const float* mw  = (const float*)d_in[13];
    const float* mb  = (const float*)d_in[14];

    char* ws = (char*)d_ws;
    size_t off = 0;
    auto alloc = [&](size_t bytes) {
        void* p = ws + off;
        off = (off + bytes + 255) & ~(size_t)255;
        return p;
    };
    bf16*   y1t   = (bf16*)  alloc((size_t)BB * P1 * 64 * 2);       // 13.1 MB
    bf16*   ebf   = (bf16*)  alloc((size_t)MR * DM * 2);            // 21.2 MB
    bf16*   qkv3  = (bf16*)  alloc((size_t)MR * QS * 2);            // 127.4 MB
    bf16*   vt    = (bf16*)  alloc((size_t)BB * NH * DK * 96 * 2);  // 50.3 MB
    bf16*   nv    = (bf16*)  alloc((size_t)MR * HID * 2);           // 42.5 MB
    bf16*   ao    = (bf16*)  alloc((size_t)MR * DM * 2);            // 21.2 MB
    float*  pool  = (float*) alloc((size_t)BB * DM * 4);
    float2* part1 = (float2*)alloc((size_t)MR * 48 * 8);            // 8 MB
    float2* part2 = (float2*)alloc((size_t)MR * 8 * 8);             // 1.3 MB
    float2* stQKV = (float2*)alloc((size_t)3 * MR * 8);             // 0.5 MB
    float2* st2   = (float2*)alloc((size_t)MR * 8);
    bf16*   w1b   = (bf16*)  alloc((size_t)C1 * CIN * 64 * 2);
    bf16*   w2b   = (bf16*)  alloc((size_t)512 * HID * 2);
    float*  b2p   = (float*) alloc(512 * 4);
    bf16*   wqkv  = (bf16*)  alloc((size_t)3072 * DM * 2);          // 3 MB
    bf16*   wob   = (bf16*)  alloc((size_t)DM * HID * 2);           // 1 MB
    float*  outp  = (float*)d_out;

    // fused weight prep
    k_prep<<<4166, 256, 0, stream>>>(w1, w2, b2, wq, wk, wvv, wo,
                                     w1b, w2b, b2p, wqkv, wob);

    // conv1 -> y1t bf16
    k_conv1_mfma<<<BB, 512, 0, stream>>>(x, w1b, b1, y1t);

    // conv2 (implicit im2col, +bias +lrelu, coord fused) -> ebf
    k_gemm_conv2<<<dim3(4, MR / 128), 256, 0, stream>>>(y1t, w2b, b2p, ebf);

    // QKV projection GEMM (256x256 8-phase, round-9 proven) + partials
    k_gemm_qkv8<<<dim3(12, MR / 256), 512, 0, stream>>>(ebf, wqkv, qkv3, part1);
    k_red<<<(3 * MR + 255) / 256, 256, 0, stream>>>(part1, stQKV, 3 * MR, 16, 3,
                                                    1.f / 1024.f);

    // V transpose + LN -> vt
    k_vt<<<BB * NH, 256, 0, stream>>>(qkv3, stQKV + 2 * MR, lng, lnb, vt);

    // attention (LN applied on the fly for Q and K)
    k_attn3<<<BB * NH, 512, 0, stream>>>(qkv3, stQKV, lng, lnb, vt, nv);

    // out projection + residual + partials (BK=64 dbuf, round-7 proven)
    k_gemm_stats<1><<<dim3(4, MR / 128), 256, 0, stream>>>(nv, wob, ebf,
                                                           ao, part2, HID, DM, 8);
    k_red<<<(MR + 255) / 256, 256, 0, stream>>>(part2, st2, MR, 8, 1, 1.f / 512.f);

    // maxpool with fused LN + relu
    k_maxpool_ln<<<(BB * DM) / 256, 256, 0, stream>>>(ao, st2, lg2, lb2, pool);
    k_final<<<BB, 256, 0, stream>>>(pool, mw, mb, outp);
}

// Round 13
// 348.648 us; speedup vs baseline: 1.1090x; 1.0383x over previous
//
#include <hip/hip_runtime.h>
#include <hip/hip_bf16.h>
#include <math.h>

typedef __hip_bfloat16 bf16;
using f32x4 = __attribute__((ext_vector_type(4))) float;
using s16x8 = __attribute__((ext_vector_type(8))) short;

#define DEV_INLINE __device__ __forceinline__

static constexpr int BB   = 256;
static constexpr int CIN  = 17;
static constexpr int WIN  = 84;
static constexpr int C1   = 64;
static constexpr int W1   = 20;
static constexpr int P1   = W1 * W1;     // 400
static constexpr int C2   = 510;
static constexpr int W2   = 9;
static constexpr int NE   = 81;
static constexpr int DM   = 512;
static constexpr int HID  = 1024;
static constexpr int NH   = 4;
static constexpr int DK   = 256;
static constexpr int MR   = BB * NE;     // 20736
static constexpr int ODIM = 256;
static constexpr int PLANE = WIN * WIN;  // 7056
static constexpr int QS   = 3 * HID;     // 3072

DEV_INLINE float lrelu_f(float v) { return v > 0.f ? v : 0.1f * v; }
DEV_INLINE float bf2f(ushort u) { return __uint_as_float((unsigned)u << 16); }
DEV_INLINE short f2bs(float f) { bf16 t = __float2bfloat16(f); return *reinterpret_cast<short*>(&t); }

DEV_INLINE void gll16(const void* g, const void* l) {
    __builtin_amdgcn_global_load_lds(
        (const __attribute__((address_space(1))) unsigned int*)g,
        (__attribute__((address_space(3))) unsigned int*)l, 16, 0, 0);
}
DEV_INLINE f32x4 mfma16(s16x8 a, s16x8 b, f32x4 c) {
    return __builtin_amdgcn_mfma_f32_16x16x32_bf16(a, b, c, 0, 0, 0);
}

// ---------------- fused weight prep (all casts/packs in ONE launch) ---------
__global__ void k_prep(const float* __restrict__ w1, const float* __restrict__ w2,
        const float* __restrict__ b2, const float* __restrict__ wq,
        const float* __restrict__ wk, const float* __restrict__ wv,
        const float* __restrict__ wo, bf16* __restrict__ w1b,
        bf16* __restrict__ w2b, float* __restrict__ b2p,
        bf16* __restrict__ wqkv, bf16* __restrict__ wob) {
    int i = blockIdx.x * 256 + threadIdx.x;
    if (i < 17408) {
        const size_t o = (size_t)i * 4;
        const float4 v = *(const float4*)(w1 + o);
        short r[4] = { f2bs(v.x), f2bs(v.y), f2bs(v.z), f2bs(v.w) };
        *(ushort4*)(w1b + o) = *(ushort4*)r;
        return;
    }
    i -= 17408;
    if (i < 524288) {   // w2 cast + K-permute to (kh,kw,ic), zero-pad rows 510/511
        const int n = i >> 10, rem = i & 1023;
        const int khkw = rem >> 6, ic = rem & 63;
        w2b[i] = (n < C2) ? __float2bfloat16(w2[n * 1024 + ic * 16 + khkw])
                          : __float2bfloat16(0.f);
        return;
    }
    i -= 524288;
    if (i < 512) { b2p[i] = (i < C2) ? b2[i] : 0.f; return; }
    i -= 512;
    if (i < 393216) {   // wq|wk|wv concat -> wqkv[3072][512]
        const size_t o = (size_t)i * 4;
        const int n = (int)(o >> 9), c = (int)(o & 511);
        const float* src = (n < 1024) ? wq : (n < 2048) ? wk : wv;
        const float4 v = *(const float4*)(src + (size_t)(n & 1023) * 512 + c);
        short r[4] = { f2bs(v.x), f2bs(v.y), f2bs(v.z), f2bs(v.w) };
        *(ushort4*)(wqkv + o) = *(ushort4*)r;
        return;
    }
    i -= 393216;
    if (i < 131072) {
        const size_t o = (size_t)i * 4;
        const float4 v = *(const float4*)(wo + o);
        short r[4] = { f2bs(v.x), f2bs(v.y), f2bs(v.z), f2bs(v.w) };
        *(ushort4*)(wob + o) = *(ushort4*)r;
    }
}

// ---------------- conv1 as implicit-GEMM MFMA -------------------------------
__global__ __launch_bounds__(512, 1) void k_conv1_mfma(const float* __restrict__ x,
        const bf16* __restrict__ w1b, const float* __restrict__ bias,
        bf16* __restrict__ y1t) {
    __shared__ __align__(16) char pl[2][28224];
    const int b = blockIdx.x;
    const int tid = threadIdx.x;
    const int w = tid >> 6, l = tid & 63;
    const int l15 = l & 15, l4 = l >> 4;
    const float* xb = x + (size_t)b * CIN * PLANE;

    int baseA[4], tval[4];
    #pragma unroll
    for (int j = 0; j < 4; ++j) {
        const int t = w + 8 * j; tval[j] = t;
        int p = t * 16 + l15; if (t >= 25) p = 0;
        const int oh = p / 20, ow = p % 20;
        baseA[j] = (oh * 4 + l4) * 336 + ow * 16;
    }
    float bias_r[4];
    #pragma unroll
    for (int nt = 0; nt < 4; ++nt) bias_r[nt] = bias[nt * 16 + l15];

    #pragma unroll
    for (int it = 0; it < 4; ++it) {
        const int g = it * 512 + tid;
        if (g < 1764) gll16(xb + (size_t)g * 4, pl[0] + (size_t)g * 16);
    }
    __syncthreads();

    f32x4 acc[4][4] = {};
    int cur = 0;
    for (int ic = 0; ic < CIN; ++ic) {
        if (ic + 1 < CIN) {
            const float* src = xb + (size_t)(ic + 1) * PLANE;
            #pragma unroll
            for (int it = 0; it < 4; ++it) {
                const int g = it * 512 + tid;
                if (g < 1764) gll16(src + (size_t)g * 4, pl[cur ^ 1] + (size_t)g * 16);
            }
        }
        s16x8 bq[4][2];
        #pragma unroll
        for (int nt = 0; nt < 4; ++nt)
            #pragma unroll
            for (int ks = 0; ks < 2; ++ks)
                bq[nt][ks] = *(const s16x8*)(w1b + (size_t)(nt * 16 + l15) * 1088
                                             + ic * 64 + (ks * 4 + l4) * 8);
        const char* P = pl[cur];
        #pragma unroll
        for (int j = 0; j < 4; ++j) {
            if (tval[j] < 25) {
                #pragma unroll
                for (int ks = 0; ks < 2; ++ks) {
                    const float* fp = (const float*)(P + baseA[j] + ks * 1344);
                    const f32x4 f0 = *(const f32x4*)fp;
                    const f32x4 f1 = *(const f32x4*)(fp + 4);
                    s16x8 af;
                    #pragma unroll
                    for (int jj = 0; jj < 4; ++jj) {
                        af[jj]     = f2bs(f0[jj]);
                        af[jj + 4] = f2bs(f1[jj]);
                    }
                    #pragma unroll
                    for (int nt = 0; nt < 4; ++nt)
                        acc[j][nt] = mfma16(af, bq[nt][ks], acc[j][nt]);
                }
            }
        }
        __syncthreads();
        cur ^= 1;
    }
    #pragma unroll
    for (int j = 0; j < 4; ++j) {
        if (tval[j] < 25) {
            #pragma unroll
            for (int nt = 0; nt < 4; ++nt) {
                #pragma unroll
                for (int q = 0; q < 4; ++q) {
                    const int pix = tval[j] * 16 + l4 * 4 + q;
                    const int oc  = nt * 16 + l15;
                    y1t[((size_t)b * P1 + pix) * 64 + oc] =
                        __float2bfloat16(lrelu_f(acc[j][nt][q] + bias_r[nt]));
                }
            }
        }
    }
}

// ---------------- conv2 GEMM (128x128, dbuf pipeline, implicit im2col) ------
__global__ __launch_bounds__(256) void k_gemm_conv2(const bf16* __restrict__ A,
        const bf16* __restrict__ B, const float* __restrict__ bias,
        bf16* __restrict__ Cb) {
    __shared__ __align__(16) char Asm[2][128 * 64];
    __shared__ __align__(16) char Bsm[2][128 * 64];
    const int tid = threadIdx.x;
    const int m0 = blockIdx.y * 128, n0 = blockIdx.x * 128;
    const int w = tid >> 6, l = tid & 63;
    const int wm = w >> 1, wn = w & 1;
    const int l15 = l & 15, l4 = l >> 4;
    const int r0 = tid >> 2, p0 = tid & 3;
    const int r1 = 64 + r0;
    const int sw0 = (p0 ^ ((r0 >> 1) & 3)) << 3;
    const int sw1 = (p0 ^ ((r1 >> 1) & 3)) << 3;
    int bimg[2], ohh[2], oww[2];
    #pragma unroll
    for (int it = 0; it < 2; ++it) {
        const int m = m0 + (it ? r1 : r0);
        bimg[it] = m / 81;
        const int n = m - bimg[it] * 81;
        ohh[it] = n / 9; oww[it] = n - ohh[it] * 9;
    }
    auto stage = [&](int buf, int k0) {
        const int khkw = k0 >> 6, icb = k0 & 63;
        const int kh = khkw >> 2, kwv = khkw & 3;
        const int pix0 = (ohh[0] * 2 + kh) * 20 + oww[0] * 2 + kwv;
        const int pix1 = (ohh[1] * 2 + kh) * 20 + oww[1] * 2 + kwv;
        gll16(A + ((size_t)bimg[0] * P1 + pix0) * 64 + icb + sw0, Asm[buf] + tid * 16);
        gll16(A + ((size_t)bimg[1] * P1 + pix1) * 64 + icb + sw1, Asm[buf] + (256 + tid) * 16);
        gll16(B + (size_t)(n0 + r0) * HID + k0 + sw0, Bsm[buf] + tid * 16);
        gll16(B + (size_t)(n0 + r1) * HID + k0 + sw1, Bsm[buf] + (256 + tid) * 16);
    };
    stage(0, 0);
    __syncthreads();
    f32x4 acc[4][4] = {};
    int cur = 0;
    for (int t = 0; t < 32; ++t) {
        if (t < 31) stage(cur ^ 1, (t + 1) * 32);
        s16x8 af[4], bfv[4];
        #pragma unroll
        for (int i = 0; i < 4; ++i) {
            const int ra = wm * 64 + i * 16 + l15;
            af[i]  = *(const s16x8*)(Asm[cur] + ra * 64 + ((l4 ^ ((ra >> 1) & 3)) << 4));
            const int rb = wn * 64 + i * 16 + l15;
            bfv[i] = *(const s16x8*)(Bsm[cur] + rb * 64 + ((l4 ^ ((rb >> 1) & 3)) << 4));
        }
        #pragma unroll
        for (int i = 0; i < 4; ++i)
            #pragma unroll
            for (int j = 0; j < 4; ++j)
                acc[i][j] = mfma16(af[i], bfv[j], acc[i][j]);
        __syncthreads();
        cur ^= 1;
    }
    #pragma unroll
    for (int i = 0; i < 4; ++i) {
        #pragma unroll
        for (int j = 0; j < 4; ++j) {
            const int col = n0 + wn * 64 + j * 16 + l15;
            #pragma unroll
            for (int q = 0; q < 4; ++q) {
                const int row = m0 + wm * 64 + i * 16 + l4 * 4 + q;
                float v = lrelu_f(acc[i][j][q] + bias[col]);
                if (col >= 510) {
                    const int n = row % 81;
                    v = (col == 510) ? (float)(n / 9) * (1.f / 9.f)
                                     : (float)(n % 9) * (1.f / 9.f);
                }
                Cb[(size_t)row * DM + col] = __float2bfloat16(v);
            }
        }
    }
}

// ============ QKV GEMM: 256x256 8-phase (T3+T4+T5), BK=64, 8 waves ==========
#define QKV_PHASE(QD, STAGING, TAIL)                                           \
    {                                                                          \
        s16x8 areg[2][2];                                                      \
        _Pragma("unroll")                                                      \
        for (int ii = 0; ii < 2; ++ii) {                                       \
            const int fr = QD * 32 + ii * 16 + l15;                            \
            _Pragma("unroll")                                                  \
            for (int kk = 0; kk < 2; ++kk)                                     \
                areg[ii][kk] = *(const s16x8*)(Abase + fr * 128 +              \
                                   (((kk * 4 + l4) ^ (fr & 7)) << 4));         \
        }                                                                      \
        STAGING;                                                               \
        __builtin_amdgcn_s_barrier();                                          \
        asm volatile("s_waitcnt lgkmcnt(0)" ::: "memory");                     \
        __builtin_amdgcn_sched_barrier(0);                                     \
        __builtin_amdgcn_s_setprio(1);                                         \
        _Pragma("unroll")                                                      \
        for (int ii = 0; ii < 2; ++ii)                                         \
            _Pragma("unroll")                                                  \
            for (int j = 0; j < 4; ++j)                                        \
                _Pragma("unroll")                                              \
                for (int kk = 0; kk < 2; ++kk)                                 \
                    acc[QD * 2 + ii][j] =                                      \
                        mfma16(areg[ii][kk], breg[j][kk], acc[QD * 2 + ii][j]);\
        __builtin_amdgcn_s_setprio(0);                                         \
        TAIL;                                                                  \
        __builtin_amdgcn_s_barrier();                                          \
        __builtin_amdgcn_sched_barrier(0);                                     \
    }

__global__ __launch_bounds__(512, 2) void k_gemm_qkv8(const bf16* __restrict__ A,
        const bf16* __restrict__ B, bf16* __restrict__ Cb,
        float2* __restrict__ part) {
    __shared__ __align__(16) char lds[131072];
    const int tid = threadIdx.x;
    const int m0 = blockIdx.y * 256, n0 = blockIdx.x * 256;
    const int wid = tid >> 6, l = tid & 63;
    const int wm = wid >> 2, wn = wid & 3;
    const int l15 = l & 15, l4 = l >> 4;
    const int rA = tid >> 3, pA = tid & 7;

    auto stageA = [&](int buf, int kt, int qa) {
        char* dst = lds + buf * 32768 + (qa >> 1) * 16384 + (qa & 1) * 8192 + tid * 16;
        gll16(A + (size_t)(m0 + qa * 64 + rA) * 512 + kt * 64 + ((pA ^ (rA & 7)) << 3), dst);
    };
    auto stageB = [&](int buf, int kt, int hb) {
        char* base = lds + 65536 + buf * 32768 + hb * 16384;
        #pragma unroll
        for (int i2 = 0; i2 < 2; ++i2) {
            const int s = i2 * 512 + tid;
            const int c = s >> 3, pp = s & 7;
            gll16(B + (size_t)(n0 + hb * 128 + c) * 512 + kt * 64 + ((pp ^ (c & 7)) << 3),
                  base + s * 16);
        }
    };

    stageA(0, 0, 0); stageA(0, 0, 1); stageA(0, 0, 2); stageA(0, 0, 3);
    stageB(0, 0, 0); stageB(0, 0, 1);
    stageB(1, 1, 0); stageB(1, 1, 1);
    stageA(1, 1, 0); stageA(1, 1, 2);
    asm volatile("s_waitcnt vmcnt(6)" ::: "memory");
    __builtin_amdgcn_s_barrier();
    __builtin_amdgcn_sched_barrier(0);

    f32x4 acc[8][4] = {};
    for (int kt = 0; kt < 8; ++kt) {
        const int cur = kt & 1;
        const char* Abase = lds + cur * 32768 + wm * 16384;
        const char* Bbase = lds + 65536 + cur * 32768 + (wn >> 1) * 16384;
        s16x8 breg[4][2];
        #pragma unroll
        for (int j = 0; j < 4; ++j) {
            const int fc = (wn & 1) * 64 + j * 16 + l15;
            #pragma unroll
            for (int kk = 0; kk < 2; ++kk)
                breg[j][kk] = *(const s16x8*)(Bbase + fc * 128 +
                                  (((kk * 4 + l4) ^ (fc & 7)) << 4));
        }
        QKV_PHASE(0, { if (kt + 1 < 8) { stageA(cur ^ 1, kt + 1, 1); stageA(cur ^ 1, kt + 1, 3); } }, {})
        QKV_PHASE(1, { if (kt + 2 < 8) { stageB(cur, kt + 2, 0); } }, {})
        QKV_PHASE(2, { if (kt + 2 < 8) { stageB(cur, kt + 2, 1); stageA(cur, kt + 2, 0); stageA(cur, kt + 2, 2); } }, {})
        QKV_PHASE(3, { }, {
            if (kt < 6)       { asm volatile("s_waitcnt vmcnt(6)" ::: "memory"); }
            else if (kt == 6) { asm volatile("s_waitcnt vmcnt(0)" ::: "memory"); }
        })
    }

    #pragma unroll
    for (int fi = 0; fi < 8; ++fi) {
        #pragma unroll
        for (int q = 0; q < 4; ++q) {
            const int row = m0 + wm * 128 + fi * 16 + l4 * 4 + q;
            float s = 0.f, s2 = 0.f;
            #pragma unroll
            for (int j = 0; j < 4; ++j) {
                const float v = acc[fi][j][q];
                s += v; s2 += v * v;
            }
            #pragma unroll
            for (int o = 1; o < 16; o <<= 1) {
                s  += __shfl_xor(s, o, 64);
                s2 += __shfl_xor(s2, o, 64);
            }
            if (l15 == 0)
                part[(size_t)row * 48 + blockIdx.x * 4 + wn] = make_float2(s, s2);
            bf16* cr = Cb + (size_t)row * QS + n0 + wn * 64;
            #pragma unroll
            for (int j = 0; j < 4; ++j)
                cr[j * 16 + l15] = __float2bfloat16(acc[fi][j][q]);
        }
    }
}

// ---------------- GEMM 128x128, BK=64, dbuf, + row-partial stats (out-proj) -
template <int RESID>
__global__ __launch_bounds__(256) void k_gemm_stats(const bf16* __restrict__ A,
        const bf16* __restrict__ B, const bf16* __restrict__ resid,
        bf16* __restrict__ Cb, float2* __restrict__ part,
        int K, int ldc, int nPH) {
    __shared__ __align__(16) char Asm[2][16384];
    __shared__ __align__(16) char Bsm[2][16384];
    const int tid = threadIdx.x;
    const int m0 = blockIdx.y * 128, n0 = blockIdx.x * 128;
    const int w = tid >> 6, l = tid & 63;
    const int wm = w >> 1, wn = w & 1;
    const int l15 = l & 15, l4 = l >> 4;

    auto stage = [&](int buf, int k0) {
        #pragma unroll
        for (int it = 0; it < 4; ++it) {
            const int g = it * 256 + tid;
            const int r = g >> 3, p = g & 7;
            const int sw = (p ^ (r & 7)) << 3;
            gll16(A + (size_t)(m0 + r) * K + k0 + sw, Asm[buf] + g * 16);
            gll16(B + (size_t)(n0 + r) * K + k0 + sw, Bsm[buf] + g * 16);
        }
    };
    stage(0, 0);
    __syncthreads();
    f32x4 acc[4][4] = {};
    int cur = 0;
    const int nt = K >> 6;
    for (int t = 0; t < nt; ++t) {
        if (t + 1 < nt) stage(cur ^ 1, (t + 1) * 64);
        #pragma unroll
        for (int kk = 0; kk < 2; ++kk) {
            s16x8 af[4], bfv[4];
            const int pz = kk * 4 + l4;
            #pragma unroll
            for (int i = 0; i < 4; ++i) {
                const int ra = wm * 64 + i * 16 + l15;
                af[i]  = *(const s16x8*)(Asm[cur] + ra * 128 + ((pz ^ (ra & 7)) << 4));
                const int rb = wn * 64 + i * 16 + l15;
                bfv[i] = *(const s16x8*)(Bsm[cur] + rb * 128 + ((pz ^ (rb & 7)) << 4));
            }
            #pragma unroll
            for (int i = 0; i < 4; ++i)
                #pragma unroll
                for (int j = 0; j < 4; ++j)
                    acc[i][j] = mfma16(af[i], bfv[j], acc[i][j]);
        }
        __syncthreads();
        cur ^= 1;
    }
    #pragma unroll
    for (int i = 0; i < 4; ++i) {
        #pragma unroll
        for (int q = 0; q < 4; ++q) {
            const int row = m0 + wm * 64 + i * 16 + l4 * 4 + q;
            if (RESID) {
                const bf16* rr = resid + (size_t)row * ldc;
                #pragma unroll
                for (int j = 0; j < 4; ++j)
                    acc[i][j][q] += bf2f(*(const ushort*)(rr + n0 + wn * 64 + j * 16 + l15));
            }
            float s = 0.f, s2 = 0.f;
            #pragma unroll
            for (int j = 0; j < 4; ++j) {
                const float v = acc[i][j][q];
                s += v; s2 += v * v;
            }
            #pragma unroll
            for (int o = 1; o < 16; o <<= 1) {
                s  += __shfl_xor(s, o, 64);
                s2 += __shfl_xor(s2, o, 64);
            }
            if (l15 == 0)
                part[(size_t)row * nPH + (n0 >> 6) + wn] = make_float2(s, s2);
            bf16* cr = Cb + (size_t)row * ldc + n0 + wn * 64;
            #pragma unroll
            for (int j = 0; j < 4; ++j)
                cr[j * 16 + l15] = __float2bfloat16(acc[i][j][q]);
        }
    }
}

// ---------------- partial stats -> per-row (mean, inv-sigma) ----------------
__global__ void k_red(const float2* __restrict__ part, float2* __restrict__ stats,
                      int total, int nPH, int groups, float invD) {
    const int gid = blockIdx.x * 256 + threadIdx.x;
    if (gid >= total) return;
    const int proj = gid / MR, row = gid - proj * MR;
    const float2* p = part + (size_t)row * (nPH * groups) + proj * nPH;
    float s = 0.f, s2 = 0.f;
    for (int h = 0; h < nPH; ++h) { s += p[h].x; s2 += p[h].y; }
    const float mean = s * invD;
    const float var  = s2 * invD - mean * mean;
    stats[gid] = make_float2(mean, rsqrtf(var + 1e-6f));
}

// ---------------- attention v4: LN Q/K/V on the fly; V staged in LDS --------
// LDS: Ks[96][512B swz] 48K | Pb[96][104] 20K | Vs[81][264] 42.8K = 110.9 KB
__global__ __launch_bounds__(512) void k_attn4(const bf16* __restrict__ qkv3,
        const float2* __restrict__ stats, const float* __restrict__ g,
        const float* __restrict__ bprm, bf16* __restrict__ nv) {
    __shared__ __align__(16) char smem[49152 + 96 * 104 * 2 + 81 * 264 * 2];
    char* Ks = smem;
    bf16* Pb = (bf16*)(smem + 49152);
    char* Vs = smem + 49152 + 96 * 104 * 2;
    const int tid = threadIdx.x;
    const int bh = blockIdx.x;
    const int b = bh >> 2, h = bh & 3;
    const int brow = b * NE;
    const int hoff = h * DK;
    const int w = tid >> 6, l = tid & 63;
    const int l15 = l & 15, l4 = l >> 4;

    // ---- stage K (LN'd, swizzled) ----
    for (int gidx = tid; gidx < 96 * 32; gidx += 512) {
        const int r = gidx >> 5, c8 = gidx & 31;
        int krow = brow + r; if (krow >= MR) krow = MR - 1;
        const s16x8 kv = *(const s16x8*)(qkv3 + (size_t)krow * QS + 1024 + hoff + c8 * 8);
        const float2 st = stats[MR + krow];
        const int col0 = hoff + c8 * 8;
        const float4 g0 = *(const float4*)(g + col0), g1 = *(const float4*)(g + col0 + 4);
        const float4 b0 = *(const float4*)(bprm + col0), b1 = *(const float4*)(bprm + col0 + 4);
        const float ga[8] = { g0.x, g0.y, g0.z, g0.w, g1.x, g1.y, g1.z, g1.w };
        const float ba[8] = { b0.x, b0.y, b0.z, b0.w, b1.x, b1.y, b1.z, b1.w };
        short o[8];
        #pragma unroll
        for (int jj = 0; jj < 8; ++jj) {
            const float a = st.y * ga[jj];
            o[jj] = f2bs(bf2f((ushort)kv[jj]) * a + (ba[jj] - st.x * a));
        }
        *(s16x8*)(Ks + r * 512 + ((c8 ^ (r & 7)) << 4)) = *(s16x8*)o;
    }
    // ---- stage V (LN'd, row-major [81][264]) ----
    for (int gidx = tid; gidx < NE * 32; gidx += 512) {
        const int m = gidx >> 5, c8 = gidx & 31;
        const int row = brow + m;
        const s16x8 vv = *(const s16x8*)(qkv3 + (size_t)row * QS + 2048 + hoff + c8 * 8);
        const float2 st = stats[2 * MR + row];
        const int col0 = hoff + c8 * 8;
        const float4 g0 = *(const float4*)(g + col0), g1 = *(const float4*)(g + col0 + 4);
        const float4 b0 = *(const float4*)(bprm + col0), b1 = *(const float4*)(bprm + col0 + 4);
        const float ga[8] = { g0.x, g0.y, g0.z, g0.w, g1.x, g1.y, g1.z, g1.w };
        const float ba[8] = { b0.x, b0.y, b0.z, b0.w, b1.x, b1.y, b1.z, b1.w };
        short o[8];
        #pragma unroll
        for (int jj = 0; jj < 8; ++jj) {
            const float a = st.y * ga[jj];
            o[jj] = f2bs(bf2f((ushort)vv[jj]) * a + (ba[jj] - st.x * a));
        }
        *(s16x8*)(Vs + (size_t)(m * 264 + c8 * 8) * 2) = *(s16x8*)o;
    }
    __syncthreads();

    if (w < 6) {    // ---- QK^T (LN'd Q read per-lane from global) ----
        int qrow = brow + w * 16 + l15; if (qrow >= MR) qrow = MR - 1;
        const float2 stq = stats[qrow];
        s16x8 qa[8];
        #pragma unroll
        for (int kk = 0; kk < 8; ++kk) {
            const int col0 = hoff + kk * 32 + l4 * 8;
            const s16x8 qv = *(const s16x8*)(qkv3 + (size_t)qrow * QS + col0);
            const float4 g0 = *(const float4*)(g + col0), g1 = *(const float4*)(g + col0 + 4);
            const float4 b0 = *(const float4*)(bprm + col0), b1 = *(const float4*)(bprm + col0 + 4);
            const float ga[8] = { g0.x, g0.y, g0.z, g0.w, g1.x, g1.y, g1.z, g1.w };
            const float ba[8] = { b0.x, b0.y, b0.z, b0.w, b1.x, b1.y, b1.z, b1.w };
            short o[8];
            #pragma unroll
            for (int jj = 0; jj < 8; ++jj) {
                const float a = stq.y * ga[jj];
                o[jj] = f2bs(bf2f((ushort)qv[jj]) * a + (ba[jj] - stq.x * a));
            }
            qa[kk] = *(s16x8*)o;
        }
        f32x4 sacc[6];
        #pragma unroll
        for (int j = 0; j < 6; ++j) {
            f32x4 a = {};
            const int rb = j * 16 + l15;
            #pragma unroll
            for (int kk = 0; kk < 8; ++kk) {
                const s16x8 kf = *(const s16x8*)(Ks + rb * 512 + (((kk * 4 + l4) ^ (rb & 7)) << 4));
                a = mfma16(qa[kk], kf, a);
            }
            sacc[j] = a;
        }
        float px[6][4];
        #pragma unroll
        for (int q = 0; q < 4; ++q) {
            float m = -1e30f;
            #pragma unroll
            for (int j = 0; j < 6; ++j) {
                const int key = j * 16 + l15;
                const float v = (key < NE) ? sacc[j][q] : -1e30f;
                px[j][q] = v;
                m = fmaxf(m, v);
            }
            #pragma unroll
            for (int o = 1; o < 16; o <<= 1) m = fmaxf(m, __shfl_xor(m, o, 64));
            float s = 0.f;
            #pragma unroll
            for (int j = 0; j < 6; ++j) {
                const float e = __expf((px[j][q] - m) * 0.0625f);
                px[j][q] = e; s += e;
            }
            #pragma unroll
            for (int o = 1; o < 16; o <<= 1) s += __shfl_xor(s, o, 64);
            const float r = 1.f / s;
            #pragma unroll
            for (int j = 0; j < 6; ++j) px[j][q] *= r;
        }
        #pragma unroll
        for (int j = 0; j < 6; ++j)
            #pragma unroll
            for (int q = 0; q < 4; ++q)
                Pb[(w * 16 + l4 * 4 + q) * 104 + j * 16 + l15] =
                    __float2bfloat16(px[j][q]);
    }
    __syncthreads();

    // ---- O = P V ; V^T fragments gathered from Vs (predicated scalar) ----
    s16x8 vf[2][3];
    #pragma unroll
    for (int dj = 0; dj < 2; ++dj) {
        const int d = (2 * w + dj) * 16 + l15;
        #pragma unroll
        for (int ks = 0; ks < 3; ++ks) {
            #pragma unroll
            for (int jj = 0; jj < 8; ++jj) {
                const int m = (ks * 4 + l4) * 8 + jj;
                vf[dj][ks][jj] = (m < NE)
                    ? *(const short*)(Vs + (size_t)(m * 264 + d) * 2) : (short)0;
            }
        }
    }
    f32x4 oacc[6][2] = {};
    #pragma unroll
    for (int i = 0; i < 6; ++i) {
        s16x8 pa[3];
        #pragma unroll
        for (int ks = 0; ks < 3; ++ks)
            pa[ks] = *(const s16x8*)(Pb + (i * 16 + l15) * 104 + (ks * 4 + l4) * 8);
        #pragma unroll
        for (int dj = 0; dj < 2; ++dj)
            #pragma unroll
            for (int ks = 0; ks < 3; ++ks)
                oacc[i][dj] = mfma16(pa[ks], vf[dj][ks], oacc[i][dj]);
    }
    #pragma unroll
    for (int i = 0; i < 6; ++i) {
        #pragma unroll
        for (int q = 0; q < 4; ++q) {
            const int n = i * 16 + l4 * 4 + q;
            if (n < NE) {
                #pragma unroll
                for (int dj = 0; dj < 2; ++dj) {
                    const int d = (2 * w + dj) * 16 + l15;
                    nv[(size_t)(brow + n) * HID + hoff + d] =
                        __float2bfloat16(oacc[i][dj][q]);
                }
            }
        }
    }
}

// ---------------- fused maxpool(LN+relu) + final mapping --------------------
__global__ __launch_bounds__(512) void k_pool_final(const bf16* __restrict__ X,
        const float2* __restrict__ st, const float* __restrict__ g,
        const float* __restrict__ bprm, const float* __restrict__ W,
        const float* __restrict__ bias, float* __restrict__ out) {
    __shared__ float pr[DM];
    const int bb = blockIdx.x;
    const int c = threadIdx.x;          // 512
    const float gc = g[c], bc = bprm[c];
    const bf16* xp = X + (size_t)bb * NE * DM + c;
    const float2* sp = st + (size_t)bb * NE;
    float mx = -1e30f;
    for (int n = 0; n < NE; ++n) {
        const float2 s = sp[n];
        const float a = s.y * gc;
        const float v = bf2f(*(const ushort*)(xp + (size_t)n * DM)) * a + (bc - s.x * a);
        mx = fmaxf(mx, fmaxf(v, 0.f));
    }
    pr[c] = mx;
    __syncthreads();
    if (c < ODIM) {
        const float4* w4 = (const float4*)(W + (size_t)c * DM);
        float acc = 0.f;
        #pragma unroll 4
        for (int c4 = 0; c4 < DM / 4; ++c4) {
            const float4 wv = w4[c4];
            acc += wv.x * pr[c4 * 4] + wv.y * pr[c4 * 4 + 1]
                 + wv.z * pr[c4 * 4 + 2] + wv.w * pr[c4 * 4 + 3];
        }
        out[(size_t)bb * ODIM + c] = lrelu_f(acc + bias[c]);
    }
}

extern "C" void kernel_launch(void* const* d_in, const int* in_sizes, int n_in,
                              void* d_out, int out_size, void* d_ws, size_t ws_size,
                              hipStream_t stream) {
    const float* x   = (const float*)d_in[0];
    const float* w1  = (const float*)d_in[1];
    const float* b1  = (const float*)d_in[2];
    const float* w2  = (const float*)d_in[3];
    const float* b2  = (const float*)d_in[4];
    const float* wq  = (const float*)d_in[5];
    const float* wk  = (const float*)d_in[6];
    const float* wvv = (const float*)d_in[7];
    const float* lng = (const float*)d_in[8];
    const float* lnb = (const float*)d_in[9];
    const float* wo  = (const float*)d_in[10];
    const float* lg2 = (const float*)d_in[11];
    const float* lb2 = (const float*)d_in[12];
    const float* mw  = (const float*)d_in[13];
    const float* mb  = (const float*)d_in[14];

    char* ws = (char*)d_ws;
    size_t off = 0;
    auto alloc = [&](size_t bytes) {
        void* p = ws + off;
        off = (off + bytes + 255) & ~(size_t)255;
        return p;
    };
    bf16*   y1t   = (bf16*)  alloc((size_t)BB * P1 * 64 * 2);       // 13.1 MB
    bf16*   ebf   = (bf16*)  alloc((size_t)MR * DM * 2);            // 21.2 MB
    bf16*   qkv3  = (bf16*)  alloc((size_t)MR * QS * 2);            // 127.4 MB
    bf16*   nv    = (bf16*)  alloc((size_t)MR * HID * 2);           // 42.5 MB
    bf16*   ao    = (bf16*)  alloc((size_t)MR * DM * 2);            // 21.2 MB
    float2* part1 = (float2*)alloc((size_t)MR * 48 * 8);            // 8 MB
    float2* part2 = (float2*)alloc((size_t)MR * 8 * 8);             // 1.3 MB
    float2* stQKV = (float2*)alloc((size_t)3 * MR * 8);             // 0.5 MB
    float2* st2   = (float2*)alloc((size_t)MR * 8);
    bf16*   w1b   = (bf16*)  alloc((size_t)C1 * CIN * 64 * 2);
    bf16*   w2b   = (bf16*)  alloc((size_t)512 * HID * 2);
    float*  b2p   = (float*) alloc(512 * 4);
    bf16*   wqkv  = (bf16*)  alloc((size_t)3072 * DM * 2);          // 3 MB
    bf16*   wob   = (bf16*)  alloc((size_t)DM * HID * 2);           // 1 MB
    float*  outp  = (float*)d_out;

    // fused weight prep
    k_prep<<<4166, 256, 0, stream>>>(w1, w2, b2, wq, wk, wvv, wo,
                                     w1b, w2b, b2p, wqkv, wob);

    // conv1 -> y1t bf16
    k_conv1_mfma<<<BB, 512, 0, stream>>>(x, w1b, b1, y1t);

    // conv2 (implicit im2col, +bias +lrelu, coord fused) -> ebf
    k_gemm_conv2<<<dim3(4, MR / 128), 256, 0, stream>>>(y1t, w2b, b2p, ebf);

    // QKV projection GEMM (256x256 8-phase) + partials
    k_gemm_qkv8<<<dim3(12, MR / 256), 512, 0, stream>>>(ebf, wqkv, qkv3, part1);
    k_red<<<(3 * MR + 255) / 256, 256, 0, stream>>>(part1, stQKV, 3 * MR, 16, 3,
                                                    1.f / 1024.f);

    // attention (LN for Q/K/V on the fly; V staged+transposed in LDS)
    k_attn4<<<BB * NH, 512, 0, stream>>>(qkv3, stQKV, lng, lnb, nv);

    // out projection + residual + partials (BK=64 dbuf)
    k_gemm_stats<1><<<dim3(4, MR / 128), 256, 0, stream>>>(nv, wob, ebf,
                                                           ao, part2, HID, DM, 8);
    k_red<<<(MR + 255) / 256, 256, 0, stream>>>(part2, st2, MR, 8, 1, 1.f / 512.f);

    // fused maxpool(LN+relu) + final mapping
    k_pool_final<<<BB, 512, 0, stream>>>(ao, st2, lg2, lb2, mw, mb, outp);
}

// Round 14
// 345.917 us; speedup vs baseline: 1.1177x; 1.0079x over previous
//
#include <hip/hip_runtime.h>
#include <hip/hip_bf16.h>
#include <math.h>

typedef __hip_bfloat16 bf16;
using f32x4 = __attribute__((ext_vector_type(4))) float;
using s16x8 = __attribute__((ext_vector_type(8))) short;

#define DEV_INLINE __device__ __forceinline__

static constexpr int BB   = 256;
static constexpr int CIN  = 17;
static constexpr int WIN  = 84;
static constexpr int C1   = 64;
static constexpr int W1   = 20;
static constexpr int P1   = W1 * W1;     // 400
static constexpr int C2   = 510;
static constexpr int W2   = 9;
static constexpr int NE   = 81;
static constexpr int DM   = 512;
static constexpr int HID  = 1024;
static constexpr int NH   = 4;
static constexpr int DK   = 256;
static constexpr int MR   = BB * NE;     // 20736
static constexpr int ODIM = 256;
static constexpr int PLANE = WIN * WIN;  // 7056
static constexpr int QS   = 3 * HID;     // 3072

DEV_INLINE float lrelu_f(float v) { return v > 0.f ? v : 0.1f * v; }
DEV_INLINE float bf2f(ushort u) { return __uint_as_float((unsigned)u << 16); }
DEV_INLINE short f2bs(float f) { bf16 t = __float2bfloat16(f); return *reinterpret_cast<short*>(&t); }

DEV_INLINE void gll16(const void* g, const void* l) {
    __builtin_amdgcn_global_load_lds(
        (const __attribute__((address_space(1))) unsigned int*)g,
        (__attribute__((address_space(3))) unsigned int*)l, 16, 0, 0);
}
DEV_INLINE f32x4 mfma16(s16x8 a, s16x8 b, f32x4 c) {
    return __builtin_amdgcn_mfma_f32_16x16x32_bf16(a, b, c, 0, 0, 0);
}

// ---------------- fused weight prep (all casts/packs in ONE launch) ---------
__global__ void k_prep(const float* __restrict__ w1, const float* __restrict__ w2,
        const float* __restrict__ b2, const float* __restrict__ wq,
        const float* __restrict__ wk, const float* __restrict__ wv,
        const float* __restrict__ wo, bf16* __restrict__ w1b,
        bf16* __restrict__ w2b, float* __restrict__ b2p,
        bf16* __restrict__ wqkv, bf16* __restrict__ wob) {
    int i = blockIdx.x * 256 + threadIdx.x;
    if (i < 17408) {
        const size_t o = (size_t)i * 4;
        const float4 v = *(const float4*)(w1 + o);
        short r[4] = { f2bs(v.x), f2bs(v.y), f2bs(v.z), f2bs(v.w) };
        *(ushort4*)(w1b + o) = *(ushort4*)r;
        return;
    }
    i -= 17408;
    if (i < 524288) {   // w2 cast + K-permute to (kh,kw,ic), zero-pad rows 510/511
        const int n = i >> 10, rem = i & 1023;
        const int khkw = rem >> 6, ic = rem & 63;
        w2b[i] = (n < C2) ? __float2bfloat16(w2[n * 1024 + ic * 16 + khkw])
                          : __float2bfloat16(0.f);
        return;
    }
    i -= 524288;
    if (i < 512) { b2p[i] = (i < C2) ? b2[i] : 0.f; return; }
    i -= 512;
    if (i < 393216) {   // wq|wk|wv concat -> wqkv[3072][512]
        const size_t o = (size_t)i * 4;
        const int n = (int)(o >> 9), c = (int)(o & 511);
        const float* src = (n < 1024) ? wq : (n < 2048) ? wk : wv;
        const float4 v = *(const float4*)(src + (size_t)(n & 1023) * 512 + c);
        short r[4] = { f2bs(v.x), f2bs(v.y), f2bs(v.z), f2bs(v.w) };
        *(ushort4*)(wqkv + o) = *(ushort4*)r;
        return;
    }
    i -= 393216;
    if (i < 131072) {
        const size_t o = (size_t)i * 4;
        const float4 v = *(const float4*)(wo + o);
        short r[4] = { f2bs(v.x), f2bs(v.y), f2bs(v.z), f2bs(v.w) };
        *(ushort4*)(wob + o) = *(ushort4*)r;
    }
}

// ---------------- conv1 as implicit-GEMM MFMA -------------------------------
__global__ __launch_bounds__(512, 1) void k_conv1_mfma(const float* __restrict__ x,
        const bf16* __restrict__ w1b, const float* __restrict__ bias,
        bf16* __restrict__ y1t) {
    __shared__ __align__(16) char pl[2][28224];
    const int b = blockIdx.x;
    const int tid = threadIdx.x;
    const int w = tid >> 6, l = tid & 63;
    const int l15 = l & 15, l4 = l >> 4;
    const float* xb = x + (size_t)b * CIN * PLANE;

    int baseA[4], tval[4];
    #pragma unroll
    for (int j = 0; j < 4; ++j) {
        const int t = w + 8 * j; tval[j] = t;
        int p = t * 16 + l15; if (t >= 25) p = 0;
        const int oh = p / 20, ow = p % 20;
        baseA[j] = (oh * 4 + l4) * 336 + ow * 16;
    }
    float bias_r[4];
    #pragma unroll
    for (int nt = 0; nt < 4; ++nt) bias_r[nt] = bias[nt * 16 + l15];

    #pragma unroll
    for (int it = 0; it < 4; ++it) {
        const int g = it * 512 + tid;
        if (g < 1764) gll16(xb + (size_t)g * 4, pl[0] + (size_t)g * 16);
    }
    __syncthreads();

    f32x4 acc[4][4] = {};
    int cur = 0;
    for (int ic = 0; ic < CIN; ++ic) {
        if (ic + 1 < CIN) {
            const float* src = xb + (size_t)(ic + 1) * PLANE;
            #pragma unroll
            for (int it = 0; it < 4; ++it) {
                const int g = it * 512 + tid;
                if (g < 1764) gll16(src + (size_t)g * 4, pl[cur ^ 1] + (size_t)g * 16);
            }
        }
        s16x8 bq[4][2];
        #pragma unroll
        for (int nt = 0; nt < 4; ++nt)
            #pragma unroll
            for (int ks = 0; ks < 2; ++ks)
                bq[nt][ks] = *(const s16x8*)(w1b + (size_t)(nt * 16 + l15) * 1088
                                             + ic * 64 + (ks * 4 + l4) * 8);
        const char* P = pl[cur];
        #pragma unroll
        for (int j = 0; j < 4; ++j) {
            if (tval[j] < 25) {
                #pragma unroll
                for (int ks = 0; ks < 2; ++ks) {
                    const float* fp = (const float*)(P + baseA[j] + ks * 1344);
                    const f32x4 f0 = *(const f32x4*)fp;
                    const f32x4 f1 = *(const f32x4*)(fp + 4);
                    s16x8 af;
                    #pragma unroll
                    for (int jj = 0; jj < 4; ++jj) {
                        af[jj]     = f2bs(f0[jj]);
                        af[jj + 4] = f2bs(f1[jj]);
                    }
                    #pragma unroll
                    for (int nt = 0; nt < 4; ++nt)
                        acc[j][nt] = mfma16(af, bq[nt][ks], acc[j][nt]);
                }
            }
        }
        __syncthreads();
        cur ^= 1;
    }
    #pragma unroll
    for (int j = 0; j < 4; ++j) {
        if (tval[j] < 25) {
            #pragma unroll
            for (int nt = 0; nt < 4; ++nt) {
                #pragma unroll
                for (int q = 0; q < 4; ++q) {
                    const int pix = tval[j] * 16 + l4 * 4 + q;
                    const int oc  = nt * 16 + l15;
                    y1t[((size_t)b * P1 + pix) * 64 + oc] =
                        __float2bfloat16(lrelu_f(acc[j][nt][q] + bias_r[nt]));
                }
            }
        }
    }
}

// ---------------- conv2 GEMM (128x128, dbuf pipeline, implicit im2col) ------
__global__ __launch_bounds__(256) void k_gemm_conv2(const bf16* __restrict__ A,
        const bf16* __restrict__ B, const float* __restrict__ bias,
        bf16* __restrict__ Cb) {
    __shared__ __align__(16) char Asm[2][128 * 64];
    __shared__ __align__(16) char Bsm[2][128 * 64];
    const int tid = threadIdx.x;
    const int m0 = blockIdx.y * 128, n0 = blockIdx.x * 128;
    const int w = tid >> 6, l = tid & 63;
    const int wm = w >> 1, wn = w & 1;
    const int l15 = l & 15, l4 = l >> 4;
    const int r0 = tid >> 2, p0 = tid & 3;
    const int r1 = 64 + r0;
    const int sw0 = (p0 ^ ((r0 >> 1) & 3)) << 3;
    const int sw1 = (p0 ^ ((r1 >> 1) & 3)) << 3;
    int bimg[2], ohh[2], oww[2];
    #pragma unroll
    for (int it = 0; it < 2; ++it) {
        const int m = m0 + (it ? r1 : r0);
        bimg[it] = m / 81;
        const int n = m - bimg[it] * 81;
        ohh[it] = n / 9; oww[it] = n - ohh[it] * 9;
    }
    auto stage = [&](int buf, int k0) {
        const int khkw = k0 >> 6, icb = k0 & 63;
        const int kh = khkw >> 2, kwv = khkw & 3;
        const int pix0 = (ohh[0] * 2 + kh) * 20 + oww[0] * 2 + kwv;
        const int pix1 = (ohh[1] * 2 + kh) * 20 + oww[1] * 2 + kwv;
        gll16(A + ((size_t)bimg[0] * P1 + pix0) * 64 + icb + sw0, Asm[buf] + tid * 16);
        gll16(A + ((size_t)bimg[1] * P1 + pix1) * 64 + icb + sw1, Asm[buf] + (256 + tid) * 16);
        gll16(B + (size_t)(n0 + r0) * HID + k0 + sw0, Bsm[buf] + tid * 16);
        gll16(B + (size_t)(n0 + r1) * HID + k0 + sw1, Bsm[buf] + (256 + tid) * 16);
    };
    stage(0, 0);
    __syncthreads();
    f32x4 acc[4][4] = {};
    int cur = 0;
    for (int t = 0; t < 32; ++t) {
        if (t < 31) stage(cur ^ 1, (t + 1) * 32);
        s16x8 af[4], bfv[4];
        #pragma unroll
        for (int i = 0; i < 4; ++i) {
            const int ra = wm * 64 + i * 16 + l15;
            af[i]  = *(const s16x8*)(Asm[cur] + ra * 64 + ((l4 ^ ((ra >> 1) & 3)) << 4));
            const int rb = wn * 64 + i * 16 + l15;
            bfv[i] = *(const s16x8*)(Bsm[cur] + rb * 64 + ((l4 ^ ((rb >> 1) & 3)) << 4));
        }
        #pragma unroll
        for (int i = 0; i < 4; ++i)
            #pragma unroll
            for (int j = 0; j < 4; ++j)
                acc[i][j] = mfma16(af[i], bfv[j], acc[i][j]);
        __syncthreads();
        cur ^= 1;
    }
    #pragma unroll
    for (int i = 0; i < 4; ++i) {
        #pragma unroll
        for (int j = 0; j < 4; ++j) {
            const int col = n0 + wn * 64 + j * 16 + l15;
            #pragma unroll
            for (int q = 0; q < 4; ++q) {
                const int row = m0 + wm * 64 + i * 16 + l4 * 4 + q;
                float v = lrelu_f(acc[i][j][q] + bias[col]);
                if (col >= 510) {
                    const int n = row % 81;
                    v = (col == 510) ? (float)(n / 9) * (1.f / 9.f)
                                     : (float)(n % 9) * (1.f / 9.f);
                }
                Cb[(size_t)row * DM + col] = __float2bfloat16(v);
            }
        }
    }
}

// ============ QKV GEMM: 256x256 8-phase (T3+T4+T5), BK=64, 8 waves ==========
#define QKV_PHASE(QD, STAGING, TAIL)                                           \
    {                                                                          \
        s16x8 areg[2][2];                                                      \
        _Pragma("unroll")                                                      \
        for (int ii = 0; ii < 2; ++ii) {                                       \
            const int fr = QD * 32 + ii * 16 + l15;                            \
            _Pragma("unroll")                                                  \
            for (int kk = 0; kk < 2; ++kk)                                     \
                areg[ii][kk] = *(const s16x8*)(Abase + fr * 128 +              \
                                   (((kk * 4 + l4) ^ (fr & 7)) << 4));         \
        }                                                                      \
        STAGING;                                                               \
        __builtin_amdgcn_s_barrier();                                          \
        asm volatile("s_waitcnt lgkmcnt(0)" ::: "memory");                     \
        __builtin_amdgcn_sched_barrier(0);                                     \
        __builtin_amdgcn_s_setprio(1);                                         \
        _Pragma("unroll")                                                      \
        for (int ii = 0; ii < 2; ++ii)                                         \
            _Pragma("unroll")                                                  \
            for (int j = 0; j < 4; ++j)                                        \
                _Pragma("unroll")                                              \
                for (int kk = 0; kk < 2; ++kk)                                 \
                    acc[QD * 2 + ii][j] =                                      \
                        mfma16(areg[ii][kk], breg[j][kk], acc[QD * 2 + ii][j]);\
        __builtin_amdgcn_s_setprio(0);                                         \
        TAIL;                                                                  \
        __builtin_amdgcn_s_barrier();                                          \
        __builtin_amdgcn_sched_barrier(0);                                     \
    }

__global__ __launch_bounds__(512, 2) void k_gemm_qkv8(const bf16* __restrict__ A,
        const bf16* __restrict__ B, bf16* __restrict__ Cb,
        float2* __restrict__ part) {
    __shared__ __align__(16) char lds[131072];
    const int tid = threadIdx.x;
    const int m0 = blockIdx.y * 256, n0 = blockIdx.x * 256;
    const int wid = tid >> 6, l = tid & 63;
    const int wm = wid >> 2, wn = wid & 3;
    const int l15 = l & 15, l4 = l >> 4;
    const int rA = tid >> 3, pA = tid & 7;

    auto stageA = [&](int buf, int kt, int qa) {
        char* dst = lds + buf * 32768 + (qa >> 1) * 16384 + (qa & 1) * 8192 + tid * 16;
        gll16(A + (size_t)(m0 + qa * 64 + rA) * 512 + kt * 64 + ((pA ^ (rA & 7)) << 3), dst);
    };
    auto stageB = [&](int buf, int kt, int hb) {
        char* base = lds + 65536 + buf * 32768 + hb * 16384;
        #pragma unroll
        for (int i2 = 0; i2 < 2; ++i2) {
            const int s = i2 * 512 + tid;
            const int c = s >> 3, pp = s & 7;
            gll16(B + (size_t)(n0 + hb * 128 + c) * 512 + kt * 64 + ((pp ^ (c & 7)) << 3),
                  base + s * 16);
        }
    };

    stageA(0, 0, 0); stageA(0, 0, 1); stageA(0, 0, 2); stageA(0, 0, 3);
    stageB(0, 0, 0); stageB(0, 0, 1);
    stageB(1, 1, 0); stageB(1, 1, 1);
    stageA(1, 1, 0); stageA(1, 1, 2);
    asm volatile("s_waitcnt vmcnt(6)" ::: "memory");
    __builtin_amdgcn_s_barrier();
    __builtin_amdgcn_sched_barrier(0);

    f32x4 acc[8][4] = {};
    for (int kt = 0; kt < 8; ++kt) {
        const int cur = kt & 1;
        const char* Abase = lds + cur * 32768 + wm * 16384;
        const char* Bbase = lds + 65536 + cur * 32768 + (wn >> 1) * 16384;
        s16x8 breg[4][2];
        #pragma unroll
        for (int j = 0; j < 4; ++j) {
            const int fc = (wn & 1) * 64 + j * 16 + l15;
            #pragma unroll
            for (int kk = 0; kk < 2; ++kk)
                breg[j][kk] = *(const s16x8*)(Bbase + fc * 128 +
                                  (((kk * 4 + l4) ^ (fc & 7)) << 4));
        }
        QKV_PHASE(0, { if (kt + 1 < 8) { stageA(cur ^ 1, kt + 1, 1); stageA(cur ^ 1, kt + 1, 3); } }, {})
        QKV_PHASE(1, { if (kt + 2 < 8) { stageB(cur, kt + 2, 0); } }, {})
        QKV_PHASE(2, { if (kt + 2 < 8) { stageB(cur, kt + 2, 1); stageA(cur, kt + 2, 0); stageA(cur, kt + 2, 2); } }, {})
        QKV_PHASE(3, { }, {
            if (kt < 6)       { asm volatile("s_waitcnt vmcnt(6)" ::: "memory"); }
            else if (kt == 6) { asm volatile("s_waitcnt vmcnt(0)" ::: "memory"); }
        })
    }

    #pragma unroll
    for (int fi = 0; fi < 8; ++fi) {
        #pragma unroll
        for (int q = 0; q < 4; ++q) {
            const int row = m0 + wm * 128 + fi * 16 + l4 * 4 + q;
            float s = 0.f, s2 = 0.f;
            #pragma unroll
            for (int j = 0; j < 4; ++j) {
                const float v = acc[fi][j][q];
                s += v; s2 += v * v;
            }
            #pragma unroll
            for (int o = 1; o < 16; o <<= 1) {
                s  += __shfl_xor(s, o, 64);
                s2 += __shfl_xor(s2, o, 64);
            }
            if (l15 == 0)
                part[(size_t)row * 48 + blockIdx.x * 4 + wn] = make_float2(s, s2);
            bf16* cr = Cb + (size_t)row * QS + n0 + wn * 64;
            #pragma unroll
            for (int j = 0; j < 4; ++j)
                cr[j * 16 + l15] = __float2bfloat16(acc[fi][j][q]);
        }
    }
}

// ---------------- GEMM 128x128, BK=64, dbuf, + row-partial stats (out-proj) -
template <int RESID>
__global__ __launch_bounds__(256) void k_gemm_stats(const bf16* __restrict__ A,
        const bf16* __restrict__ B, const bf16* __restrict__ resid,
        bf16* __restrict__ Cb, float2* __restrict__ part,
        int K, int ldc, int nPH) {
    __shared__ __align__(16) char Asm[2][16384];
    __shared__ __align__(16) char Bsm[2][16384];
    const int tid = threadIdx.x;
    const int m0 = blockIdx.y * 128, n0 = blockIdx.x * 128;
    const int w = tid >> 6, l = tid & 63;
    const int wm = w >> 1, wn = w & 1;
    const int l15 = l & 15, l4 = l >> 4;

    auto stage = [&](int buf, int k0) {
        #pragma unroll
        for (int it = 0; it < 4; ++it) {
            const int g = it * 256 + tid;
            const int r = g >> 3, p = g & 7;
            const int sw = (p ^ (r & 7)) << 3;
            gll16(A + (size_t)(m0 + r) * K + k0 + sw, Asm[buf] + g * 16);
            gll16(B + (size_t)(n0 + r) * K + k0 + sw, Bsm[buf] + g * 16);
        }
    };
    stage(0, 0);
    __syncthreads();
    f32x4 acc[4][4] = {};
    int cur = 0;
    const int nt = K >> 6;
    for (int t = 0; t < nt; ++t) {
        if (t + 1 < nt) stage(cur ^ 1, (t + 1) * 64);
        #pragma unroll
        for (int kk = 0; kk < 2; ++kk) {
            s16x8 af[4], bfv[4];
            const int pz = kk * 4 + l4;
            #pragma unroll
            for (int i = 0; i < 4; ++i) {
                const int ra = wm * 64 + i * 16 + l15;
                af[i]  = *(const s16x8*)(Asm[cur] + ra * 128 + ((pz ^ (ra & 7)) << 4));
                const int rb = wn * 64 + i * 16 + l15;
                bfv[i] = *(const s16x8*)(Bsm[cur] + rb * 128 + ((pz ^ (rb & 7)) << 4));
            }
            #pragma unroll
            for (int i = 0; i < 4; ++i)
                #pragma unroll
                for (int j = 0; j < 4; ++j)
                    acc[i][j] = mfma16(af[i], bfv[j], acc[i][j]);
        }
        __syncthreads();
        cur ^= 1;
    }
    #pragma unroll
    for (int i = 0; i < 4; ++i) {
        #pragma unroll
        for (int q = 0; q < 4; ++q) {
            const int row = m0 + wm * 64 + i * 16 + l4 * 4 + q;
            if (RESID) {
                const bf16* rr = resid + (size_t)row * ldc;
                #pragma unroll
                for (int j = 0; j < 4; ++j)
                    acc[i][j][q] += bf2f(*(const ushort*)(rr + n0 + wn * 64 + j * 16 + l15));
            }
            float s = 0.f, s2 = 0.f;
            #pragma unroll
            for (int j = 0; j < 4; ++j) {
                const float v = acc[i][j][q];
                s += v; s2 += v * v;
            }
            #pragma unroll
            for (int o = 1; o < 16; o <<= 1) {
                s  += __shfl_xor(s, o, 64);
                s2 += __shfl_xor(s2, o, 64);
            }
            if (l15 == 0)
                part[(size_t)row * nPH + (n0 >> 6) + wn] = make_float2(s, s2);
            bf16* cr = Cb + (size_t)row * ldc + n0 + wn * 64;
            #pragma unroll
            for (int j = 0; j < 4; ++j)
                cr[j * 16 + l15] = __float2bfloat16(acc[i][j][q]);
        }
    }
}

// ---------------- attention v5: in-kernel LN stats; LN Q/K/V on the fly -----
// LDS: Ks 48K | Pb 20K | Vs[81][264] 42.8K | stQ/stK/stV[96] 2.3K = 113.2 KB
__global__ __launch_bounds__(512) void k_attn5(const bf16* __restrict__ qkv3,
        const float2* __restrict__ part1, const float* __restrict__ g,
        const float* __restrict__ bprm, bf16* __restrict__ nv) {
    __shared__ __align__(16) char smem[49152 + 96 * 104 * 2 + 81 * 264 * 2];
    __shared__ float2 stQ[96], stK[96], stV[96];
    char* Ks = smem;
    bf16* Pb = (bf16*)(smem + 49152);
    char* Vs = smem + 49152 + 96 * 104 * 2;
    const int tid = threadIdx.x;
    const int bh = blockIdx.x;
    const int b = bh >> 2, h = bh & 3;
    const int brow = b * NE;
    const int hoff = h * DK;
    const int w = tid >> 6, l = tid & 63;
    const int l15 = l & 15, l4 = l >> 4;

    // ---- per-row LN stats from part1 (rows >= NE clamp to NE-1; masked later)
    if (tid < 288) {
        const int proj = tid / 96, r = tid - proj * 96;
        const int row = brow + (r < NE ? r : NE - 1);
        const float2* p = part1 + (size_t)row * 48 + proj * 16;
        float s = 0.f, s2 = 0.f;
        #pragma unroll 4
        for (int h2 = 0; h2 < 16; ++h2) { s += p[h2].x; s2 += p[h2].y; }
        const float mean = s * (1.f / 1024.f);
        const float var  = s2 * (1.f / 1024.f) - mean * mean;
        const float2 st = make_float2(mean, rsqrtf(var + 1e-6f));
        if (proj == 0) stQ[r] = st; else if (proj == 1) stK[r] = st; else stV[r] = st;
    }
    __syncthreads();

    // ---- stage K (LN'd, swizzled) ----
    for (int gidx = tid; gidx < 96 * 32; gidx += 512) {
        const int r = gidx >> 5, c8 = gidx & 31;
        int krow = brow + r; if (krow >= MR) krow = MR - 1;
        const s16x8 kv = *(const s16x8*)(qkv3 + (size_t)krow * QS + 1024 + hoff + c8 * 8);
        const float2 st = stK[r];
        const int col0 = hoff + c8 * 8;
        const float4 g0 = *(const float4*)(g + col0), g1 = *(const float4*)(g + col0 + 4);
        const float4 b0 = *(const float4*)(bprm + col0), b1 = *(const float4*)(bprm + col0 + 4);
        const float ga[8] = { g0.x, g0.y, g0.z, g0.w, g1.x, g1.y, g1.z, g1.w };
        const float ba[8] = { b0.x, b0.y, b0.z, b0.w, b1.x, b1.y, b1.z, b1.w };
        short o[8];
        #pragma unroll
        for (int jj = 0; jj < 8; ++jj) {
            const float a = st.y * ga[jj];
            o[jj] = f2bs(bf2f((ushort)kv[jj]) * a + (ba[jj] - st.x * a));
        }
        *(s16x8*)(Ks + r * 512 + ((c8 ^ (r & 7)) << 4)) = *(s16x8*)o;
    }
    // ---- stage V (LN'd, row-major [81][264]) ----
    for (int gidx = tid; gidx < NE * 32; gidx += 512) {
        const int m = gidx >> 5, c8 = gidx & 31;
        const int row = brow + m;
        const s16x8 vv = *(const s16x8*)(qkv3 + (size_t)row * QS + 2048 + hoff + c8 * 8);
        const float2 st = stV[m];
        const int col0 = hoff + c8 * 8;
        const float4 g0 = *(const float4*)(g + col0), g1 = *(const float4*)(g + col0 + 4);
        const float4 b0 = *(const float4*)(bprm + col0), b1 = *(const float4*)(bprm + col0 + 4);
        const float ga[8] = { g0.x, g0.y, g0.z, g0.w, g1.x, g1.y, g1.z, g1.w };
        const float ba[8] = { b0.x, b0.y, b0.z, b0.w, b1.x, b1.y, b1.z, b1.w };
        short o[8];
        #pragma unroll
        for (int jj = 0; jj < 8; ++jj) {
            const float a = st.y * ga[jj];
            o[jj] = f2bs(bf2f((ushort)vv[jj]) * a + (ba[jj] - st.x * a));
        }
        *(s16x8*)(Vs + (size_t)(m * 264 + c8 * 8) * 2) = *(s16x8*)o;
    }
    __syncthreads();

    if (w < 6) {    // ---- QK^T (LN'd Q read per-lane from global) ----
        const int rq = w * 16 + l15;
        int qrow = brow + rq; if (qrow >= MR) qrow = MR - 1;
        const float2 stq = stQ[rq];
        s16x8 qa[8];
        #pragma unroll
        for (int kk = 0; kk < 8; ++kk) {
            const int col0 = hoff + kk * 32 + l4 * 8;
            const s16x8 qv = *(const s16x8*)(qkv3 + (size_t)qrow * QS + col0);
            const float4 g0 = *(const float4*)(g + col0), g1 = *(const float4*)(g + col0 + 4);
            const float4 b0 = *(const float4*)(bprm + col0), b1 = *(const float4*)(bprm + col0 + 4);
            const float ga[8] = { g0.x, g0.y, g0.z, g0.w, g1.x, g1.y, g1.z, g1.w };
            const float ba[8] = { b0.x, b0.y, b0.z, b0.w, b1.x, b1.y, b1.z, b1.w };
            short o[8];
            #pragma unroll
            for (int jj = 0; jj < 8; ++jj) {
                const float a = stq.y * ga[jj];
                o[jj] = f2bs(bf2f((ushort)qv[jj]) * a + (ba[jj] - stq.x * a));
            }
            qa[kk] = *(s16x8*)o;
        }
        f32x4 sacc[6];
        #pragma unroll
        for (int j = 0; j < 6; ++j) {
            f32x4 a = {};
            const int rb = j * 16 + l15;
            #pragma unroll
            for (int kk = 0; kk < 8; ++kk) {
                const s16x8 kf = *(const s16x8*)(Ks + rb * 512 + (((kk * 4 + l4) ^ (rb & 7)) << 4));
                a = mfma16(qa[kk], kf, a);
            }
            sacc[j] = a;
        }
        float px[6][4];
        #pragma unroll
        for (int q = 0; q < 4; ++q) {
            float m = -1e30f;
            #pragma unroll
            for (int j = 0; j < 6; ++j) {
                const int key = j * 16 + l15;
                const float v = (key < NE) ? sacc[j][q] : -1e30f;
                px[j][q] = v;
                m = fmaxf(m, v);
            }
            #pragma unroll
            for (int o = 1; o < 16; o <<= 1) m = fmaxf(m, __shfl_xor(m, o, 64));
            float s = 0.f;
            #pragma unroll
            for (int j = 0; j < 6; ++j) {
                const float e = __expf((px[j][q] - m) * 0.0625f);
                px[j][q] = e; s += e;
            }
            #pragma unroll
            for (int o = 1; o < 16; o <<= 1) s += __shfl_xor(s, o, 64);
            const float r = 1.f / s;
            #pragma unroll
            for (int j = 0; j < 6; ++j) px[j][q] *= r;
        }
        #pragma unroll
        for (int j = 0; j < 6; ++j)
            #pragma unroll
            for (int q = 0; q < 4; ++q)
                Pb[(w * 16 + l4 * 4 + q) * 104 + j * 16 + l15] =
                    __float2bfloat16(px[j][q]);
    }
    __syncthreads();

    // ---- O = P V ; V^T fragments gathered from Vs (predicated scalar) ----
    s16x8 vf[2][3];
    #pragma unroll
    for (int dj = 0; dj < 2; ++dj) {
        const int d = (2 * w + dj) * 16 + l15;
        #pragma unroll
        for (int ks = 0; ks < 3; ++ks) {
            #pragma unroll
            for (int jj = 0; jj < 8; ++jj) {
                const int m = (ks * 4 + l4) * 8 + jj;
                vf[dj][ks][jj] = (m < NE)
                    ? *(const short*)(Vs + (size_t)(m * 264 + d) * 2) : (short)0;
            }
        }
    }
    f32x4 oacc[6][2] = {};
    #pragma unroll
    for (int i = 0; i < 6; ++i) {
        s16x8 pa[3];
        #pragma unroll
        for (int ks = 0; ks < 3; ++ks)
            pa[ks] = *(const s16x8*)(Pb + (i * 16 + l15) * 104 + (ks * 4 + l4) * 8);
        #pragma unroll
        for (int dj = 0; dj < 2; ++dj)
            #pragma unroll
            for (int ks = 0; ks < 3; ++ks)
                oacc[i][dj] = mfma16(pa[ks], vf[dj][ks], oacc[i][dj]);
    }
    #pragma unroll
    for (int i = 0; i < 6; ++i) {
        #pragma unroll
        for (int q = 0; q < 4; ++q) {
            const int n = i * 16 + l4 * 4 + q;
            if (n < NE) {
                #pragma unroll
                for (int dj = 0; dj < 2; ++dj) {
                    const int d = (2 * w + dj) * 16 + l15;
                    nv[(size_t)(brow + n) * HID + hoff + d] =
                        __float2bfloat16(oacc[i][dj][q]);
                }
            }
        }
    }
}

// ---------------- fused: out-LN stats + maxpool(LN+relu) + final mapping ----
__global__ __launch_bounds__(512) void k_pool_final(const bf16* __restrict__ X,
        const float2* __restrict__ part2, const float* __restrict__ g,
        const float* __restrict__ bprm, const float* __restrict__ W,
        const float* __restrict__ bias, float* __restrict__ out) {
    __shared__ float pr[DM];
    __shared__ float2 st_sh[NE];
    const int bb = blockIdx.x;
    const int c = threadIdx.x;          // 512
    if (c < NE) {
        const float2* p = part2 + (size_t)(bb * NE + c) * 8;
        float s = 0.f, s2 = 0.f;
        #pragma unroll
        for (int h2 = 0; h2 < 8; ++h2) { s += p[h2].x; s2 += p[h2].y; }
        const float mean = s * (1.f / 512.f);
        const float var  = s2 * (1.f / 512.f) - mean * mean;
        st_sh[c] = make_float2(mean, rsqrtf(var + 1e-6f));
    }
    __syncthreads();
    const float gc = g[c], bc = bprm[c];
    const bf16* xp = X + (size_t)bb * NE * DM + c;
    float mx = -1e30f;
    for (int n = 0; n < NE; ++n) {
        const float2 s = st_sh[n];
        const float a = s.y * gc;
        const float v = bf2f(*(const ushort*)(xp + (size_t)n * DM)) * a + (bc - s.x * a);
        mx = fmaxf(mx, fmaxf(v, 0.f));
    }
    pr[c] = mx;
    __syncthreads();
    if (c < ODIM) {
        const float4* w4 = (const float4*)(W + (size_t)c * DM);
        float acc = 0.f;
        #pragma unroll 4
        for (int c4 = 0; c4 < DM / 4; ++c4) {
            const float4 wv = w4[c4];
            acc += wv.x * pr[c4 * 4] + wv.y * pr[c4 * 4 + 1]
                 + wv.z * pr[c4 * 4 + 2] + wv.w * pr[c4 * 4 + 3];
        }
        out[(size_t)bb * ODIM + c] = lrelu_f(acc + bias[c]);
    }
}

extern "C" void kernel_launch(void* const* d_in, const int* in_sizes, int n_in,
                              void* d_out, int out_size, void* d_ws, size_t ws_size,
                              hipStream_t stream) {
    const float* x   = (const float*)d_in[0];
    const float* w1  = (const float*)d_in[1];
    const float* b1  = (const float*)d_in[2];
    const float* w2  = (const float*)d_in[3];
    const float* b2  = (const float*)d_in[4];
    const float* wq  = (const float*)d_in[5];
    const float* wk  = (const float*)d_in[6];
    const float* wvv = (const float*)d_in[7];
    const float* lng = (const float*)d_in[8];
    const float* lnb = (const float*)d_in[9];
    const float* wo  = (const float*)d_in[10];
    const float* lg2 = (const float*)d_in[11];
    const float* lb2 = (const float*)d_in[12];
    const float* mw  = (const float*)d_in[13];
    const float* mb  = (const float*)d_in[14];

    char* ws = (char*)d_ws;
    size_t off = 0;
    auto alloc = [&](size_t bytes) {
        void* p = ws + off;
        off = (off + bytes + 255) & ~(size_t)255;
        return p;
    };
    bf16*   y1t   = (bf16*)  alloc((size_t)BB * P1 * 64 * 2);       // 13.1 MB
    bf16*   ebf   = (bf16*)  alloc((size_t)MR * DM * 2);            // 21.2 MB
    bf16*   qkv3  = (bf16*)  alloc((size_t)MR * QS * 2);            // 127.4 MB
    bf16*   nv    = (bf16*)  alloc((size_t)MR * HID * 2);           // 42.5 MB
    bf16*   ao    = (bf16*)  alloc((size_t)MR * DM * 2);            // 21.2 MB
    float2* part1 = (float2*)alloc((size_t)MR * 48 * 8);            // 8 MB
    float2* part2 = (float2*)alloc((size_t)MR * 8 * 8);             // 1.3 MB
    bf16*   w1b   = (bf16*)  alloc((size_t)C1 * CIN * 64 * 2);
    bf16*   w2b   = (bf16*)  alloc((size_t)512 * HID * 2);
    float*  b2p   = (float*) alloc(512 * 4);
    bf16*   wqkv  = (bf16*)  alloc((size_t)3072 * DM * 2);          // 3 MB
    bf16*   wob   = (bf16*)  alloc((size_t)DM * HID * 2);           // 1 MB
    float*  outp  = (float*)d_out;

    // fused weight prep
    k_prep<<<4166, 256, 0, stream>>>(w1, w2, b2, wq, wk, wvv, wo,
                                     w1b, w2b, b2p, wqkv, wob);

    // conv1 -> y1t bf16
    k_conv1_mfma<<<BB, 512, 0, stream>>>(x, w1b, b1, y1t);

    // conv2 (implicit im2col, +bias +lrelu, coord fused) -> ebf
    k_gemm_conv2<<<dim3(4, MR / 128), 256, 0, stream>>>(y1t, w2b, b2p, ebf);

    // QKV projection GEMM (256x256 8-phase) + partials
    k_gemm_qkv8<<<dim3(12, MR / 256), 512, 0, stream>>>(ebf, wqkv, qkv3, part1);

    // attention (in-kernel LN stats; LN Q/K/V on the fly; V staged in LDS)
    k_attn5<<<BB * NH, 512, 0, stream>>>(qkv3, part1, lng, lnb, nv);

    // out projection + residual + partials (BK=64 dbuf)
    k_gemm_stats<1><<<dim3(4, MR / 128), 256, 0, stream>>>(nv, wob, ebf,
                                                           ao, part2, HID, DM, 8);

    // fused: out-LN stats + maxpool(LN+relu) + final mapping
    k_pool_final<<<BB, 512, 0, stream>>>(ao, part2, lg2, lb2, mw, mb, outp);
}

// Round 15
// 339.241 us; speedup vs baseline: 1.1397x; 1.0197x over previous
//
#include <hip/hip_runtime.h>
#include <hip/hip_bf16.h>
#include <math.h>

typedef __hip_bfloat16 bf16;
using f32x4 = __attribute__((ext_vector_type(4))) float;
using s16x8 = __attribute__((ext_vector_type(8))) short;

#define DEV_INLINE __device__ __forceinline__

static constexpr int BB   = 256;
static constexpr int CIN  = 17;
static constexpr int WIN  = 84;
static constexpr int C1   = 64;
static constexpr int W1   = 20;
static constexpr int P1   = W1 * W1;     // 400
static constexpr int C2   = 510;
static constexpr int W2   = 9;
static constexpr int NE   = 81;
static constexpr int DM   = 512;
static constexpr int HID  = 1024;
static constexpr int NH   = 4;
static constexpr int DK   = 256;
static constexpr int MR   = BB * NE;     // 20736
static constexpr int ODIM = 256;
static constexpr int PLANE = WIN * WIN;  // 7056
static constexpr int QS   = 3 * HID;     // 3072

DEV_INLINE float lrelu_f(float v) { return v > 0.f ? v : 0.1f * v; }
DEV_INLINE float bf2f(ushort u) { return __uint_as_float((unsigned)u << 16); }
DEV_INLINE short f2bs(float f) { bf16 t = __float2bfloat16(f); return *reinterpret_cast<short*>(&t); }

DEV_INLINE void gll16(const void* g, const void* l) {
    __builtin_amdgcn_global_load_lds(
        (const __attribute__((address_space(1))) unsigned int*)g,
        (__attribute__((address_space(3))) unsigned int*)l, 16, 0, 0);
}
DEV_INLINE f32x4 mfma16(s16x8 a, s16x8 b, f32x4 c) {
    return __builtin_amdgcn_mfma_f32_16x16x32_bf16(a, b, c, 0, 0, 0);
}

// ---------------- fused weight prep (all casts/packs in ONE launch) ---------
__global__ void k_prep(const float* __restrict__ w1, const float* __restrict__ w2,
        const float* __restrict__ b2, const float* __restrict__ wq,
        const float* __restrict__ wk, const float* __restrict__ wv,
        const float* __restrict__ wo, bf16* __restrict__ w1b,
        bf16* __restrict__ w2b, float* __restrict__ b2p,
        bf16* __restrict__ wqkv, bf16* __restrict__ wob) {
    int i = blockIdx.x * 256 + threadIdx.x;
    if (i < 17408) {
        const size_t o = (size_t)i * 4;
        const float4 v = *(const float4*)(w1 + o);
        short r[4] = { f2bs(v.x), f2bs(v.y), f2bs(v.z), f2bs(v.w) };
        *(ushort4*)(w1b + o) = *(ushort4*)r;
        return;
    }
    i -= 17408;
    if (i < 524288) {   // w2 cast + K-permute to (kh,kw,ic), zero-pad rows 510/511
        const int n = i >> 10, rem = i & 1023;
        const int khkw = rem >> 6, ic = rem & 63;
        w2b[i] = (n < C2) ? __float2bfloat16(w2[n * 1024 + ic * 16 + khkw])
                          : __float2bfloat16(0.f);
        return;
    }
    i -= 524288;
    if (i < 512) { b2p[i] = (i < C2) ? b2[i] : 0.f; return; }
    i -= 512;
    if (i < 393216) {   // wq|wk|wv concat -> wqkv[3072][512]
        const size_t o = (size_t)i * 4;
        const int n = (int)(o >> 9), c = (int)(o & 511);
        const float* src = (n < 1024) ? wq : (n < 2048) ? wk : wv;
        const float4 v = *(const float4*)(src + (size_t)(n & 1023) * 512 + c);
        short r[4] = { f2bs(v.x), f2bs(v.y), f2bs(v.z), f2bs(v.w) };
        *(ushort4*)(wqkv + o) = *(ushort4*)r;
        return;
    }
    i -= 393216;
    if (i < 131072) {
        const size_t o = (size_t)i * 4;
        const float4 v = *(const float4*)(wo + o);
        short r[4] = { f2bs(v.x), f2bs(v.y), f2bs(v.z), f2bs(v.w) };
        *(ushort4*)(wob + o) = *(ushort4*)r;
    }
}

// ---------------- conv1 as implicit-GEMM MFMA -------------------------------
__global__ __launch_bounds__(512, 1) void k_conv1_mfma(const float* __restrict__ x,
        const bf16* __restrict__ w1b, const float* __restrict__ bias,
        bf16* __restrict__ y1t) {
    __shared__ __align__(16) char pl[2][28224];
    const int b = blockIdx.x;
    const int tid = threadIdx.x;
    const int w = tid >> 6, l = tid & 63;
    const int l15 = l & 15, l4 = l >> 4;
    const float* xb = x + (size_t)b * CIN * PLANE;

    int baseA[4], tval[4];
    #pragma unroll
    for (int j = 0; j < 4; ++j) {
        const int t = w + 8 * j; tval[j] = t;
        int p = t * 16 + l15; if (t >= 25) p = 0;
        const int oh = p / 20, ow = p % 20;
        baseA[j] = (oh * 4 + l4) * 336 + ow * 16;
    }
    float bias_r[4];
    #pragma unroll
    for (int nt = 0; nt < 4; ++nt) bias_r[nt] = bias[nt * 16 + l15];

    #pragma unroll
    for (int it = 0; it < 4; ++it) {
        const int g = it * 512 + tid;
        if (g < 1764) gll16(xb + (size_t)g * 4, pl[0] + (size_t)g * 16);
    }
    __syncthreads();

    f32x4 acc[4][4] = {};
    int cur = 0;
    for (int ic = 0; ic < CIN; ++ic) {
        if (ic + 1 < CIN) {
            const float* src = xb + (size_t)(ic + 1) * PLANE;
            #pragma unroll
            for (int it = 0; it < 4; ++it) {
                const int g = it * 512 + tid;
                if (g < 1764) gll16(src + (size_t)g * 4, pl[cur ^ 1] + (size_t)g * 16);
            }
        }
        s16x8 bq[4][2];
        #pragma unroll
        for (int nt = 0; nt < 4; ++nt)
            #pragma unroll
            for (int ks = 0; ks < 2; ++ks)
                bq[nt][ks] = *(const s16x8*)(w1b + (size_t)(nt * 16 + l15) * 1088
                                             + ic * 64 + (ks * 4 + l4) * 8);
        const char* P = pl[cur];
        #pragma unroll
        for (int j = 0; j < 4; ++j) {
            if (tval[j] < 25) {
                #pragma unroll
                for (int ks = 0; ks < 2; ++ks) {
                    const float* fp = (const float*)(P + baseA[j] + ks * 1344);
                    const f32x4 f0 = *(const f32x4*)fp;
                    const f32x4 f1 = *(const f32x4*)(fp + 4);
                    s16x8 af;
                    #pragma unroll
                    for (int jj = 0; jj < 4; ++jj) {
                        af[jj]     = f2bs(f0[jj]);
                        af[jj + 4] = f2bs(f1[jj]);
                    }
                    #pragma unroll
                    for (int nt = 0; nt < 4; ++nt)
                        acc[j][nt] = mfma16(af, bq[nt][ks], acc[j][nt]);
                }
            }
        }
        __syncthreads();
        cur ^= 1;
    }
    #pragma unroll
    for (int j = 0; j < 4; ++j) {
        if (tval[j] < 25) {
            #pragma unroll
            for (int nt = 0; nt < 4; ++nt) {
                #pragma unroll
                for (int q = 0; q < 4; ++q) {
                    const int pix = tval[j] * 16 + l4 * 4 + q;
                    const int oc  = nt * 16 + l15;
                    y1t[((size_t)b * P1 + pix) * 64 + oc] =
                        __float2bfloat16(lrelu_f(acc[j][nt][q] + bias_r[nt]));
                }
            }
        }
    }
}

// ---------------- conv2 GEMM (128x128, dbuf pipeline, implicit im2col) ------
__global__ __launch_bounds__(256) void k_gemm_conv2(const bf16* __restrict__ A,
        const bf16* __restrict__ B, const float* __restrict__ bias,
        bf16* __restrict__ Cb) {
    __shared__ __align__(16) char Asm[2][128 * 64];
    __shared__ __align__(16) char Bsm[2][128 * 64];
    const int tid = threadIdx.x;
    const int m0 = blockIdx.y * 128, n0 = blockIdx.x * 128;
    const int w = tid >> 6, l = tid & 63;
    const int wm = w >> 1, wn = w & 1;
    const int l15 = l & 15, l4 = l >> 4;
    const int r0 = tid >> 2, p0 = tid & 3;
    const int r1 = 64 + r0;
    const int sw0 = (p0 ^ ((r0 >> 1) & 3)) << 3;
    const int sw1 = (p0 ^ ((r1 >> 1) & 3)) << 3;
    int bimg[2], ohh[2], oww[2];
    #pragma unroll
    for (int it = 0; it < 2; ++it) {
        const int m = m0 + (it ? r1 : r0);
        bimg[it] = m / 81;
        const int n = m - bimg[it] * 81;
        ohh[it] = n / 9; oww[it] = n - ohh[it] * 9;
    }
    auto stage = [&](int buf, int k0) {
        const int khkw = k0 >> 6, icb = k0 & 63;
        const int kh = khkw >> 2, kwv = khkw & 3;
        const int pix0 = (ohh[0] * 2 + kh) * 20 + oww[0] * 2 + kwv;
        const int pix1 = (ohh[1] * 2 + kh) * 20 + oww[1] * 2 + kwv;
        gll16(A + ((size_t)bimg[0] * P1 + pix0) * 64 + icb + sw0, Asm[buf] + tid * 16);
        gll16(A + ((size_t)bimg[1] * P1 + pix1) * 64 + icb + sw1, Asm[buf] + (256 + tid) * 16);
        gll16(B + (size_t)(n0 + r0) * HID + k0 + sw0, Bsm[buf] + tid * 16);
        gll16(B + (size_t)(n0 + r1) * HID + k0 + sw1, Bsm[buf] + (256 + tid) * 16);
    };
    stage(0, 0);
    __syncthreads();
    f32x4 acc[4][4] = {};
    int cur = 0;
    for (int t = 0; t < 32; ++t) {
        if (t < 31) stage(cur ^ 1, (t + 1) * 32);
        s16x8 af[4], bfv[4];
        #pragma unroll
        for (int i = 0; i < 4; ++i) {
            const int ra = wm * 64 + i * 16 + l15;
            af[i]  = *(const s16x8*)(Asm[cur] + ra * 64 + ((l4 ^ ((ra >> 1) & 3)) << 4));
            const int rb = wn * 64 + i * 16 + l15;
            bfv[i] = *(const s16x8*)(Bsm[cur] + rb * 64 + ((l4 ^ ((rb >> 1) & 3)) << 4));
        }
        #pragma unroll
        for (int i = 0; i < 4; ++i)
            #pragma unroll
            for (int j = 0; j < 4; ++j)
                acc[i][j] = mfma16(af[i], bfv[j], acc[i][j]);
        __syncthreads();
        cur ^= 1;
    }
    #pragma unroll
    for (int i = 0; i < 4; ++i) {
        #pragma unroll
        for (int j = 0; j < 4; ++j) {
            const int col = n0 + wn * 64 + j * 16 + l15;
            #pragma unroll
            for (int q = 0; q < 4; ++q) {
                const int row = m0 + wm * 64 + i * 16 + l4 * 4 + q;
                float v = lrelu_f(acc[i][j][q] + bias[col]);
                if (col >= 510) {
                    const int n = row % 81;
                    v = (col == 510) ? (float)(n / 9) * (1.f / 9.f)
                                     : (float)(n % 9) * (1.f / 9.f);
                }
                Cb[(size_t)row * DM + col] = __float2bfloat16(v);
            }
        }
    }
}

// ============ QKV GEMM: 256x256 8-phase + stripe-major XCD mapping ==========
// 12 N-blocks of one M-stripe co-located on one XCD (A-stripe L2-resident).
#define QKV_PHASE(QD, STAGING, TAIL)                                           \
    {                                                                          \
        s16x8 areg[2][2];                                                      \
        _Pragma("unroll")                                                      \
        for (int ii = 0; ii < 2; ++ii) {                                       \
            const int fr = QD * 32 + ii * 16 + l15;                            \
            _Pragma("unroll")                                                  \
            for (int kk = 0; kk < 2; ++kk)                                     \
                areg[ii][kk] = *(const s16x8*)(Abase + fr * 128 +              \
                                   (((kk * 4 + l4) ^ (fr & 7)) << 4));         \
        }                                                                      \
        STAGING;                                                               \
        __builtin_amdgcn_s_barrier();                                          \
        asm volatile("s_waitcnt lgkmcnt(0)" ::: "memory");                     \
        __builtin_amdgcn_sched_barrier(0);                                     \
        __builtin_amdgcn_s_setprio(1);                                         \
        _Pragma("unroll")                                                      \
        for (int ii = 0; ii < 2; ++ii)                                         \
            _Pragma("unroll")                                                  \
            for (int j = 0; j < 4; ++j)                                        \
                _Pragma("unroll")                                              \
                for (int kk = 0; kk < 2; ++kk)                                 \
                    acc[QD * 2 + ii][j] =                                      \
                        mfma16(areg[ii][kk], breg[j][kk], acc[QD * 2 + ii][j]);\
        __builtin_amdgcn_s_setprio(0);                                         \
        TAIL;                                                                  \
        __builtin_amdgcn_s_barrier();                                          \
        __builtin_amdgcn_sched_barrier(0);                                     \
    }

__global__ __launch_bounds__(512, 2) void k_gemm_qkv8(const bf16* __restrict__ A,
        const bf16* __restrict__ B, bf16* __restrict__ Cb,
        float2* __restrict__ part) {
    __shared__ __align__(16) char lds[131072];
    const int tid = threadIdx.x;
    // stripe-major XCD mapping: stripe y's 12 N-blocks land on XCD y%8.
    // bijective over 972 = 8*120 + 12 (y=80 tail handled separately).
    int bx, by;
    {
        const int lin = blockIdx.x;
        if (lin >= 960) { by = 80; bx = lin - 960; }
        else { bx = (lin >> 3) % 12; by = ((lin >> 3) / 12) * 8 + (lin & 7); }
    }
    const int m0 = by * 256, n0 = bx * 256;
    const int wid = tid >> 6, l = tid & 63;
    const int wm = wid >> 2, wn = wid & 3;
    const int l15 = l & 15, l4 = l >> 4;
    const int rA = tid >> 3, pA = tid & 7;

    auto stageA = [&](int buf, int kt, int qa) {
        char* dst = lds + buf * 32768 + (qa >> 1) * 16384 + (qa & 1) * 8192 + tid * 16;
        gll16(A + (size_t)(m0 + qa * 64 + rA) * 512 + kt * 64 + ((pA ^ (rA & 7)) << 3), dst);
    };
    auto stageB = [&](int buf, int kt, int hb) {
        char* base = lds + 65536 + buf * 32768 + hb * 16384;
        #pragma unroll
        for (int i2 = 0; i2 < 2; ++i2) {
            const int s = i2 * 512 + tid;
            const int c = s >> 3, pp = s & 7;
            gll16(B + (size_t)(n0 + hb * 128 + c) * 512 + kt * 64 + ((pp ^ (c & 7)) << 3),
                  base + s * 16);
        }
    };

    stageA(0, 0, 0); stageA(0, 0, 1); stageA(0, 0, 2); stageA(0, 0, 3);
    stageB(0, 0, 0); stageB(0, 0, 1);
    stageB(1, 1, 0); stageB(1, 1, 1);
    stageA(1, 1, 0); stageA(1, 1, 2);
    asm volatile("s_waitcnt vmcnt(6)" ::: "memory");
    __builtin_amdgcn_s_barrier();
    __builtin_amdgcn_sched_barrier(0);

    f32x4 acc[8][4] = {};
    for (int kt = 0; kt < 8; ++kt) {
        const int cur = kt & 1;
        const char* Abase = lds + cur * 32768 + wm * 16384;
        const char* Bbase = lds + 65536 + cur * 32768 + (wn >> 1) * 16384;
        s16x8 breg[4][2];
        #pragma unroll
        for (int j = 0; j < 4; ++j) {
            const int fc = (wn & 1) * 64 + j * 16 + l15;
            #pragma unroll
            for (int kk = 0; kk < 2; ++kk)
                breg[j][kk] = *(const s16x8*)(Bbase + fc * 128 +
                                  (((kk * 4 + l4) ^ (fc & 7)) << 4));
        }
        QKV_PHASE(0, { if (kt + 1 < 8) { stageA(cur ^ 1, kt + 1, 1); stageA(cur ^ 1, kt + 1, 3); } }, {})
        QKV_PHASE(1, { if (kt + 2 < 8) { stageB(cur, kt + 2, 0); } }, {})
        QKV_PHASE(2, { if (kt + 2 < 8) { stageB(cur, kt + 2, 1); stageA(cur, kt + 2, 0); stageA(cur, kt + 2, 2); } }, {})
        QKV_PHASE(3, { }, {
            if (kt < 6)       { asm volatile("s_waitcnt vmcnt(6)" ::: "memory"); }
            else if (kt == 6) { asm volatile("s_waitcnt vmcnt(0)" ::: "memory"); }
        })
    }

    #pragma unroll
    for (int fi = 0; fi < 8; ++fi) {
        #pragma unroll
        for (int q = 0; q < 4; ++q) {
            const int row = m0 + wm * 128 + fi * 16 + l4 * 4 + q;
            float s = 0.f, s2 = 0.f;
            #pragma unroll
            for (int j = 0; j < 4; ++j) {
                const float v = acc[fi][j][q];
                s += v; s2 += v * v;
            }
            #pragma unroll
            for (int o = 1; o < 16; o <<= 1) {
                s  += __shfl_xor(s, o, 64);
                s2 += __shfl_xor(s2, o, 64);
            }
            if (l15 == 0)
                part[(size_t)row * 48 + bx * 4 + wn] = make_float2(s, s2);
            bf16* cr = Cb + (size_t)row * QS + n0 + wn * 64;
            #pragma unroll
            for (int j = 0; j < 4; ++j)
                cr[j * 16 + l15] = __float2bfloat16(acc[fi][j][q]);
        }
    }
}

// ---------------- GEMM 128x128, BK=64, dbuf, + row-partial stats (out-proj) -
template <int RESID>
__global__ __launch_bounds__(256) void k_gemm_stats(const bf16* __restrict__ A,
        const bf16* __restrict__ B, const bf16* __restrict__ resid,
        bf16* __restrict__ Cb, float2* __restrict__ part,
        int K, int ldc, int nPH) {
    __shared__ __align__(16) char Asm[2][16384];
    __shared__ __align__(16) char Bsm[2][16384];
    const int tid = threadIdx.x;
    const int m0 = blockIdx.y * 128, n0 = blockIdx.x * 128;
    const int w = tid >> 6, l = tid & 63;
    const int wm = w >> 1, wn = w & 1;
    const int l15 = l & 15, l4 = l >> 4;

    auto stage = [&](int buf, int k0) {
        #pragma unroll
        for (int it = 0; it < 4; ++it) {
            const int g = it * 256 + tid;
            const int r = g >> 3, p = g & 7;
            const int sw = (p ^ (r & 7)) << 3;
            gll16(A + (size_t)(m0 + r) * K + k0 + sw, Asm[buf] + g * 16);
            gll16(B + (size_t)(n0 + r) * K + k0 + sw, Bsm[buf] + g * 16);
        }
    };
    stage(0, 0);
    __syncthreads();
    f32x4 acc[4][4] = {};
    int cur = 0;
    const int nt = K >> 6;
    for (int t = 0; t < nt; ++t) {
        if (t + 1 < nt) stage(cur ^ 1, (t + 1) * 64);
        #pragma unroll
        for (int kk = 0; kk < 2; ++kk) {
            s16x8 af[4], bfv[4];
            const int pz = kk * 4 + l4;
            #pragma unroll
            for (int i = 0; i < 4; ++i) {
                const int ra = wm * 64 + i * 16 + l15;
                af[i]  = *(const s16x8*)(Asm[cur] + ra * 128 + ((pz ^ (ra & 7)) << 4));
                const int rb = wn * 64 + i * 16 + l15;
                bfv[i] = *(const s16x8*)(Bsm[cur] + rb * 128 + ((pz ^ (rb & 7)) << 4));
            }
            #pragma unroll
            for (int i = 0; i < 4; ++i)
                #pragma unroll
                for (int j = 0; j < 4; ++j)
                    acc[i][j] = mfma16(af[i], bfv[j], acc[i][j]);
        }
        __syncthreads();
        cur ^= 1;
    }
    #pragma unroll
    for (int i = 0; i < 4; ++i) {
        #pragma unroll
        for (int q = 0; q < 4; ++q) {
            const int row = m0 + wm * 64 + i * 16 + l4 * 4 + q;
            if (RESID) {
                const bf16* rr = resid + (size_t)row * ldc;
                #pragma unroll
                for (int j = 0; j < 4; ++j)
                    acc[i][j][q] += bf2f(*(const ushort*)(rr + n0 + wn * 64 + j * 16 + l15));
            }
            float s = 0.f, s2 = 0.f;
            #pragma unroll
            for (int j = 0; j < 4; ++j) {
                const float v = acc[i][j][q];
                s += v; s2 += v * v;
            }
            #pragma unroll
            for (int o = 1; o < 16; o <<= 1) {
                s  += __shfl_xor(s, o, 64);
                s2 += __shfl_xor(s2, o, 64);
            }
            if (l15 == 0)
                part[(size_t)row * nPH + (n0 >> 6) + wn] = make_float2(s, s2);
            bf16* cr = Cb + (size_t)row * ldc + n0 + wn * 64;
            #pragma unroll
            for (int j = 0; j < 4; ++j)
                cr[j * 16 + l15] = __float2bfloat16(acc[i][j][q]);
        }
    }
}

// ---------------- attention v5: in-kernel LN stats; LN Q/K/V on the fly -----
__global__ __launch_bounds__(512) void k_attn5(const bf16* __restrict__ qkv3,
        const float2* __restrict__ part1, const float* __restrict__ g,
        const float* __restrict__ bprm, bf16* __restrict__ nv) {
    __shared__ __align__(16) char smem[49152 + 96 * 104 * 2 + 81 * 264 * 2];
    __shared__ float2 stQ[96], stK[96], stV[96];
    char* Ks = smem;
    bf16* Pb = (bf16*)(smem + 49152);
    char* Vs = smem + 49152 + 96 * 104 * 2;
    const int tid = threadIdx.x;
    const int bh = blockIdx.x;
    const int b = bh >> 2, h = bh & 3;
    const int brow = b * NE;
    const int hoff = h * DK;
    const int w = tid >> 6, l = tid & 63;
    const int l15 = l & 15, l4 = l >> 4;

    if (tid < 288) {
        const int proj = tid / 96, r = tid - proj * 96;
        const int row = brow + (r < NE ? r : NE - 1);
        const float2* p = part1 + (size_t)row * 48 + proj * 16;
        float s = 0.f, s2 = 0.f;
        #pragma unroll 4
        for (int h2 = 0; h2 < 16; ++h2) { s += p[h2].x; s2 += p[h2].y; }
        const float mean = s * (1.f / 1024.f);
        const float var  = s2 * (1.f / 1024.f) - mean * mean;
        const float2 st = make_float2(mean, rsqrtf(var + 1e-6f));
        if (proj == 0) stQ[r] = st; else if (proj == 1) stK[r] = st; else stV[r] = st;
    }
    __syncthreads();

    for (int gidx = tid; gidx < 96 * 32; gidx += 512) {
        const int r = gidx >> 5, c8 = gidx & 31;
        int krow = brow + r; if (krow >= MR) krow = MR - 1;
        const s16x8 kv = *(const s16x8*)(qkv3 + (size_t)krow * QS + 1024 + hoff + c8 * 8);
        const float2 st = stK[r];
        const int col0 = hoff + c8 * 8;
        const float4 g0 = *(const float4*)(g + col0), g1 = *(const float4*)(g + col0 + 4);
        const float4 b0 = *(const float4*)(bprm + col0), b1 = *(const float4*)(bprm + col0 + 4);
        const float ga[8] = { g0.x, g0.y, g0.z, g0.w, g1.x, g1.y, g1.z, g1.w };
        const float ba[8] = { b0.x, b0.y, b0.z, b0.w, b1.x, b1.y, b1.z, b1.w };
        short o[8];
        #pragma unroll
        for (int jj = 0; jj < 8; ++jj) {
            const float a = st.y * ga[jj];
            o[jj] = f2bs(bf2f((ushort)kv[jj]) * a + (ba[jj] - st.x * a));
        }
        *(s16x8*)(Ks + r * 512 + ((c8 ^ (r & 7)) << 4)) = *(s16x8*)o;
    }
    for (int gidx = tid; gidx < NE * 32; gidx += 512) {
        const int m = gidx >> 5, c8 = gidx & 31;
        const int row = brow + m;
        const s16x8 vv = *(const s16x8*)(qkv3 + (size_t)row * QS + 2048 + hoff + c8 * 8);
        const float2 st = stV[m];
        const int col0 = hoff + c8 * 8;
        const float4 g0 = *(const float4*)(g + col0), g1 = *(const float4*)(g + col0 + 4);
        const float4 b0 = *(const float4*)(bprm + col0), b1 = *(const float4*)(bprm + col0 + 4);
        const float ga[8] = { g0.x, g0.y, g0.z, g0.w, g1.x, g1.y, g1.z, g1.w };
        const float ba[8] = { b0.x, b0.y, b0.z, b0.w, b1.x, b1.y, b1.z, b1.w };
        short o[8];
        #pragma unroll
        for (int jj = 0; jj < 8; ++jj) {
            const float a = st.y * ga[jj];
            o[jj] = f2bs(bf2f((ushort)vv[jj]) * a + (ba[jj] - st.x * a));
        }
        *(s16x8*)(Vs + (size_t)(m * 264 + c8 * 8) * 2) = *(s16x8*)o;
    }
    __syncthreads();

    if (w < 6) {
        const int rq = w * 16 + l15;
        int qrow = brow + rq; if (qrow >= MR) qrow = MR - 1;
        const float2 stq = stQ[rq];
        s16x8 qa[8];
        #pragma unroll
        for (int kk = 0; kk < 8; ++kk) {
            const int col0 = hoff + kk * 32 + l4 * 8;
            const s16x8 qv = *(const s16x8*)(qkv3 + (size_t)qrow * QS + col0);
            const float4 g0 = *(const float4*)(g + col0), g1 = *(const float4*)(g + col0 + 4);
            const float4 b0 = *(const float4*)(bprm + col0), b1 = *(const float4*)(bprm + col0 + 4);
            const float ga[8] = { g0.x, g0.y, g0.z, g0.w, g1.x, g1.y, g1.z, g1.w };
            const float ba[8] = { b0.x, b0.y, b0.z, b0.w, b1.x, b1.y, b1.z, b1.w };
            short o[8];
            #pragma unroll
            for (int jj = 0; jj < 8; ++jj) {
                const float a = stq.y * ga[jj];
                o[jj] = f2bs(bf2f((ushort)qv[jj]) * a + (ba[jj] - stq.x * a));
            }
            qa[kk] = *(s16x8*)o;
        }
        f32x4 sacc[6];
        #pragma unroll
        for (int j = 0; j < 6; ++j) {
            f32x4 a = {};
            const int rb = j * 16 + l15;
            #pragma unroll
            for (int kk = 0; kk < 8; ++kk) {
                const s16x8 kf = *(const s16x8*)(Ks + rb * 512 + (((kk * 4 + l4) ^ (rb & 7)) << 4));
                a = mfma16(qa[kk], kf, a);
            }
            sacc[j] = a;
        }
        float px[6][4];
        #pragma unroll
        for (int q = 0; q < 4; ++q) {
            float m = -1e30f;
            #pragma unroll
            for (int j = 0; j < 6; ++j) {
                const int key = j * 16 + l15;
                const float v = (key < NE) ? sacc[j][q] : -1e30f;
                px[j][q] = v;
                m = fmaxf(m, v);
            }
            #pragma unroll
            for (int o = 1; o < 16; o <<= 1) m = fmaxf(m, __shfl_xor(m, o, 64));
            float s = 0.f;
            #pragma unroll
            for (int j = 0; j < 6; ++j) {
                const float e = __expf((px[j][q] - m) * 0.0625f);
                px[j][q] = e; s += e;
            }
            #pragma unroll
            for (int o = 1; o < 16; o <<= 1) s += __shfl_xor(s, o, 64);
            const float r = 1.f / s;
            #pragma unroll
            for (int j = 0; j < 6; ++j) px[j][q] *= r;
        }
        #pragma unroll
        for (int j = 0; j < 6; ++j)
            #pragma unroll
            for (int q = 0; q < 4; ++q)
                Pb[(w * 16 + l4 * 4 + q) * 104 + j * 16 + l15] =
                    __float2bfloat16(px[j][q]);
    }
    __syncthreads();

    s16x8 vf[2][3];
    #pragma unroll
    for (int dj = 0; dj < 2; ++dj) {
        const int d = (2 * w + dj) * 16 + l15;
        #pragma unroll
        for (int ks = 0; ks < 3; ++ks) {
            #pragma unroll
            for (int jj = 0; jj < 8; ++jj) {
                const int m = (ks * 4 + l4) * 8 + jj;
                vf[dj][ks][jj] = (m < NE)
                    ? *(const short*)(Vs + (size_t)(m * 264 + d) * 2) : (short)0;
            }
        }
    }
    f32x4 oacc[6][2] = {};
    #pragma unroll
    for (int i = 0; i < 6; ++i) {
        s16x8 pa[3];
        #pragma unroll
        for (int ks = 0; ks < 3; ++ks)
            pa[ks] = *(const s16x8*)(Pb + (i * 16 + l15) * 104 + (ks * 4 + l4) * 8);
        #pragma unroll
        for (int dj = 0; dj < 2; ++dj)
            #pragma unroll
            for (int ks = 0; ks < 3; ++ks)
                oacc[i][dj] = mfma16(pa[ks], vf[dj][ks], oacc[i][dj]);
    }
    #pragma unroll
    for (int i = 0; i < 6; ++i) {
        #pragma unroll
        for (int q = 0; q < 4; ++q) {
            const int n = i * 16 + l4 * 4 + q;
            if (n < NE) {
                #pragma unroll
                for (int dj = 0; dj < 2; ++dj) {
                    const int d = (2 * w + dj) * 16 + l15;
                    nv[(size_t)(brow + n) * HID + hoff + d] =
                        __float2bfloat16(oacc[i][dj][q]);
                }
            }
        }
    }
}

// ---------------- fused: out-LN stats + maxpool(LN+relu) + final mapping ----
__global__ __launch_bounds__(512) void k_pool_final(const bf16* __restrict__ X,
        const float2* __restrict__ part2, const float* __restrict__ g,
        const float* __restrict__ bprm, const float* __restrict__ W,
        const float* __restrict__ bias, float* __restrict__ out) {
    __shared__ float pr[DM];
    __shared__ float2 st_sh[NE];
    const int bb = blockIdx.x;
    const int c = threadIdx.x;          // 512
    if (c < NE) {
        const float2* p = part2 + (size_t)(bb * NE + c) * 8;
        float s = 0.f, s2 = 0.f;
        #pragma unroll
        for (int h2 = 0; h2 < 8; ++h2) { s += p[h2].x; s2 += p[h2].y; }
        const float mean = s * (1.f / 512.f);
        const float var  = s2 * (1.f / 512.f) - mean * mean;
        st_sh[c] = make_float2(mean, rsqrtf(var + 1e-6f));
    }
    __syncthreads();
    const float gc = g[c], bc = bprm[c];
    const bf16* xp = X + (size_t)bb * NE * DM + c;
    float mx = -1e30f;
    for (int n = 0; n < NE; ++n) {
        const float2 s = st_sh[n];
        const float a = s.y * gc;
        const float v = bf2f(*(const ushort*)(xp + (size_t)n * DM)) * a + (bc - s.x * a);
        mx = fmaxf(mx, fmaxf(v, 0.f));
    }
    pr[c] = mx;
    __syncthreads();
    if (c < ODIM) {
        const float4* w4 = (const float4*)(W + (size_t)c * DM);
        float acc = 0.f;
        #pragma unroll 4
        for (int c4 = 0; c4 < DM / 4; ++c4) {
            const float4 wv = w4[c4];
            acc += wv.x * pr[c4 * 4] + wv.y * pr[c4 * 4 + 1]
                 + wv.z * pr[c4 * 4 + 2] + wv.w * pr[c4 * 4 + 3];
        }
        out[(size_t)bb * ODIM + c] = lrelu_f(acc + bias[c]);
    }
}

extern "C" void kernel_launch(void* const* d_in, const int* in_sizes, int n_in,
                              void* d_out, int out_size, void* d_ws, size_t ws_size,
                              hipStream_t stream) {
    const float* x   = (const float*)d_in[0];
    const float* w1  = (const float*)d_in[1];
    const float* b1  = (const float*)d_in[2];
    const float* w2  = (const float*)d_in[3];
    const float* b2  = (const float*)d_in[4];
    const float* wq  = (const float*)d_in[5];
    const float* wk  = (const float*)d_in[6];
    const float* wvv = (const float*)d_in[7];
    const float* lng = (const float*)d_in[8];
    const float* lnb = (const float*)d_in[9];
    const float* wo  = (const float*)d_in[10];
    const float* lg2 = (const float*)d_in[11];
    const float* lb2 = (const float*)d_in[12];
    const float* mw  = (const float*)d_in[13];
    const float* mb  = (const float*)d_in[14];

    char* ws = (char*)d_ws;
    size_t off = 0;
    auto alloc = [&](size_t bytes) {
        void* p = ws + off;
        off = (off + bytes + 255) & ~(size_t)255;
        return p;
    };
    bf16*   y1t   = (bf16*)  alloc((size_t)BB * P1 * 64 * 2);       // 13.1 MB
    bf16*   ebf   = (bf16*)  alloc((size_t)MR * DM * 2);            // 21.2 MB
    bf16*   qkv3  = (bf16*)  alloc((size_t)MR * QS * 2);            // 127.4 MB
    bf16*   nv    = (bf16*)  alloc((size_t)MR * HID * 2);           // 42.5 MB
    bf16*   ao    = (bf16*)  alloc((size_t)MR * DM * 2);            // 21.2 MB
    float2* part1 = (float2*)alloc((size_t)MR * 48 * 8);            // 8 MB
    float2* part2 = (float2*)alloc((size_t)MR * 8 * 8);             // 1.3 MB
    bf16*   w1b   = (bf16*)  alloc((size_t)C1 * CIN * 64 * 2);
    bf16*   w2b   = (bf16*)  alloc((size_t)512 * HID * 2);
    float*  b2p   = (float*) alloc(512 * 4);
    bf16*   wqkv  = (bf16*)  alloc((size_t)3072 * DM * 2);          // 3 MB
    bf16*   wob   = (bf16*)  alloc((size_t)DM * HID * 2);           // 1 MB
    float*  outp  = (float*)d_out;

    // fused weight prep
    k_prep<<<4166, 256, 0, stream>>>(w1, w2, b2, wq, wk, wvv, wo,
                                     w1b, w2b, b2p, wqkv, wob);

    // conv1 -> y1t bf16
    k_conv1_mfma<<<BB, 512, 0, stream>>>(x, w1b, b1, y1t);

    // conv2 (implicit im2col, +bias +lrelu, coord fused) -> ebf
    k_gemm_conv2<<<dim3(4, MR / 128), 256, 0, stream>>>(y1t, w2b, b2p, ebf);

    // QKV projection GEMM (256x256 8-phase, stripe-major XCD mapping) + partials
    k_gemm_qkv8<<<972, 512, 0, stream>>>(ebf, wqkv, qkv3, part1);

    // attention (in-kernel LN stats; LN Q/K/V on the fly; V staged in LDS)
    k_attn5<<<BB * NH, 512, 0, stream>>>(qkv3, part1, lng, lnb, nv);

    // out projection + residual + partials (BK=64 dbuf)
    k_gemm_stats<1><<<dim3(4, MR / 128), 256, 0, stream>>>(nv, wob, ebf,
                                                           ao, part2, HID, DM, 8);

    // fused: out-LN stats + maxpool(LN+relu) + final mapping
    k_pool_final<<<BB, 512, 0, stream>>>(ao, part2, lg2, lb2, mw, mb, outp);
}

// Round 16
// 329.146 us; speedup vs baseline: 1.1747x; 1.0307x over previous
//
#include <hip/hip_runtime.h>
#include <hip/hip_bf16.h>
#include <math.h>

typedef __hip_bfloat16 bf16;
using f32x4 = __attribute__((ext_vector_type(4))) float;
using s16x8 = __attribute__((ext_vector_type(8))) short;

#define DEV_INLINE __device__ __forceinline__

static constexpr int BB   = 256;
static constexpr int CIN  = 17;
static constexpr int WIN  = 84;
static constexpr int C1   = 64;
static constexpr int W1   = 20;
static constexpr int P1   = W1 * W1;     // 400
static constexpr int C2   = 510;
static constexpr int W2   = 9;
static constexpr int NE   = 81;
static constexpr int DM   = 512;
static constexpr int HID  = 1024;
static constexpr int NH   = 4;
static constexpr int DK   = 256;
static constexpr int MR   = BB * NE;     // 20736
static constexpr int ODIM = 256;
static constexpr int PLANE = WIN * WIN;  // 7056
static constexpr int QS   = 3 * HID;     // 3072

DEV_INLINE float lrelu_f(float v) { return v > 0.f ? v : 0.1f * v; }
DEV_INLINE float bf2f(ushort u) { return __uint_as_float((unsigned)u << 16); }
DEV_INLINE short f2bs(float f) { bf16 t = __float2bfloat16(f); return *reinterpret_cast<short*>(&t); }

DEV_INLINE void gll16(const void* g, const void* l) {
    __builtin_amdgcn_global_load_lds(
        (const __attribute__((address_space(1))) unsigned int*)g,
        (__attribute__((address_space(3))) unsigned int*)l, 16, 0, 0);
}
DEV_INLINE f32x4 mfma16(s16x8 a, s16x8 b, f32x4 c) {
    return __builtin_amdgcn_mfma_f32_16x16x32_bf16(a, b, c, 0, 0, 0);
}

// ---------------- fused weight prep (all casts/packs in ONE launch) ---------
__global__ void k_prep(const float* __restrict__ w1, const float* __restrict__ w2,
        const float* __restrict__ b2, const float* __restrict__ wq,
        const float* __restrict__ wk, const float* __restrict__ wv,
        const float* __restrict__ wo, bf16* __restrict__ w1b,
        bf16* __restrict__ w2b, float* __restrict__ b2p,
        bf16* __restrict__ wqkv, bf16* __restrict__ wob) {
    int i = blockIdx.x * 256 + threadIdx.x;
    if (i < 17408) {
        const size_t o = (size_t)i * 4;
        const float4 v = *(const float4*)(w1 + o);
        short r[4] = { f2bs(v.x), f2bs(v.y), f2bs(v.z), f2bs(v.w) };
        *(ushort4*)(w1b + o) = *(ushort4*)r;
        return;
    }
    i -= 17408;
    if (i < 524288) {   // w2 cast + K-permute to (kh,kw,ic), zero-pad rows 510/511
        const int n = i >> 10, rem = i & 1023;
        const int khkw = rem >> 6, ic = rem & 63;
        w2b[i] = (n < C2) ? __float2bfloat16(w2[n * 1024 + ic * 16 + khkw])
                          : __float2bfloat16(0.f);
        return;
    }
    i -= 524288;
    if (i < 512) { b2p[i] = (i < C2) ? b2[i] : 0.f; return; }
    i -= 512;
    if (i < 393216) {   // wq|wk|wv concat -> wqkv[3072][512]
        const size_t o = (size_t)i * 4;
        const int n = (int)(o >> 9), c = (int)(o & 511);
        const float* src = (n < 1024) ? wq : (n < 2048) ? wk : wv;
        const float4 v = *(const float4*)(src + (size_t)(n & 1023) * 512 + c);
        short r[4] = { f2bs(v.x), f2bs(v.y), f2bs(v.z), f2bs(v.w) };
        *(ushort4*)(wqkv + o) = *(ushort4*)r;
        return;
    }
    i -= 393216;
    if (i < 131072) {
        const size_t o = (size_t)i * 4;
        const float4 v = *(const float4*)(wo + o);
        short r[4] = { f2bs(v.x), f2bs(v.y), f2bs(v.z), f2bs(v.w) };
        *(ushort4*)(wob + o) = *(ushort4*)r;
    }
}

// ---------------- conv1 as implicit-GEMM MFMA -------------------------------
__global__ __launch_bounds__(512, 1) void k_conv1_mfma(const float* __restrict__ x,
        const bf16* __restrict__ w1b, const float* __restrict__ bias,
        bf16* __restrict__ y1t) {
    __shared__ __align__(16) char pl[2][28224];
    const int b = blockIdx.x;
    const int tid = threadIdx.x;
    const int w = tid >> 6, l = tid & 63;
    const int l15 = l & 15, l4 = l >> 4;
    const float* xb = x + (size_t)b * CIN * PLANE;

    int baseA[4], tval[4];
    #pragma unroll
    for (int j = 0; j < 4; ++j) {
        const int t = w + 8 * j; tval[j] = t;
        int p = t * 16 + l15; if (t >= 25) p = 0;
        const int oh = p / 20, ow = p % 20;
        baseA[j] = (oh * 4 + l4) * 336 + ow * 16;
    }
    float bias_r[4];
    #pragma unroll
    for (int nt = 0; nt < 4; ++nt) bias_r[nt] = bias[nt * 16 + l15];

    #pragma unroll
    for (int it = 0; it < 4; ++it) {
        const int g = it * 512 + tid;
        if (g < 1764) gll16(xb + (size_t)g * 4, pl[0] + (size_t)g * 16);
    }
    __syncthreads();

    f32x4 acc[4][4] = {};
    int cur = 0;
    for (int ic = 0; ic < CIN; ++ic) {
        if (ic + 1 < CIN) {
            const float* src = xb + (size_t)(ic + 1) * PLANE;
            #pragma unroll
            for (int it = 0; it < 4; ++it) {
                const int g = it * 512 + tid;
                if (g < 1764) gll16(src + (size_t)g * 4, pl[cur ^ 1] + (size_t)g * 16);
            }
        }
        s16x8 bq[4][2];
        #pragma unroll
        for (int nt = 0; nt < 4; ++nt)
            #pragma unroll
            for (int ks = 0; ks < 2; ++ks)
                bq[nt][ks] = *(const s16x8*)(w1b + (size_t)(nt * 16 + l15) * 1088
                                             + ic * 64 + (ks * 4 + l4) * 8);
        const char* P = pl[cur];
        #pragma unroll
        for (int j = 0; j < 4; ++j) {
            if (tval[j] < 25) {
                #pragma unroll
                for (int ks = 0; ks < 2; ++ks) {
                    const float* fp = (const float*)(P + baseA[j] + ks * 1344);
                    const f32x4 f0 = *(const f32x4*)fp;
                    const f32x4 f1 = *(const f32x4*)(fp + 4);
                    s16x8 af;
                    #pragma unroll
                    for (int jj = 0; jj < 4; ++jj) {
                        af[jj]     = f2bs(f0[jj]);
                        af[jj + 4] = f2bs(f1[jj]);
                    }
                    #pragma unroll
                    for (int nt = 0; nt < 4; ++nt)
                        acc[j][nt] = mfma16(af, bq[nt][ks], acc[j][nt]);
                }
            }
        }
        __syncthreads();
        cur ^= 1;
    }
    #pragma unroll
    for (int j = 0; j < 4; ++j) {
        if (tval[j] < 25) {
            #pragma unroll
            for (int nt = 0; nt < 4; ++nt) {
                #pragma unroll
                for (int q = 0; q < 4; ++q) {
                    const int pix = tval[j] * 16 + l4 * 4 + q;
                    const int oc  = nt * 16 + l15;
                    y1t[((size_t)b * P1 + pix) * 64 + oc] =
                        __float2bfloat16(lrelu_f(acc[j][nt][q] + bias_r[nt]));
                }
            }
        }
    }
}

// ---------------- conv2 GEMM (128x128, dbuf pipeline, implicit im2col) ------
__global__ __launch_bounds__(256) void k_gemm_conv2(const bf16* __restrict__ A,
        const bf16* __restrict__ B, const float* __restrict__ bias,
        bf16* __restrict__ Cb) {
    __shared__ __align__(16) char Asm[2][128 * 64];
    __shared__ __align__(16) char Bsm[2][128 * 64];
    const int tid = threadIdx.x;
    const int m0 = blockIdx.y * 128, n0 = blockIdx.x * 128;
    const int w = tid >> 6, l = tid & 63;
    const int wm = w >> 1, wn = w & 1;
    const int l15 = l & 15, l4 = l >> 4;
    const int r0 = tid >> 2, p0 = tid & 3;
    const int r1 = 64 + r0;
    const int sw0 = (p0 ^ ((r0 >> 1) & 3)) << 3;
    const int sw1 = (p0 ^ ((r1 >> 1) & 3)) << 3;
    int bimg[2], ohh[2], oww[2];
    #pragma unroll
    for (int it = 0; it < 2; ++it) {
        const int m = m0 + (it ? r1 : r0);
        bimg[it] = m / 81;
        const int n = m - bimg[it] * 81;
        ohh[it] = n / 9; oww[it] = n - ohh[it] * 9;
    }
    auto stage = [&](int buf, int k0) {
        const int khkw = k0 >> 6, icb = k0 & 63;
        const int kh = khkw >> 2, kwv = khkw & 3;
        const int pix0 = (ohh[0] * 2 + kh) * 20 + oww[0] * 2 + kwv;
        const int pix1 = (ohh[1] * 2 + kh) * 20 + oww[1] * 2 + kwv;
        gll16(A + ((size_t)bimg[0] * P1 + pix0) * 64 + icb + sw0, Asm[buf] + tid * 16);
        gll16(A + ((size_t)bimg[1] * P1 + pix1) * 64 + icb + sw1, Asm[buf] + (256 + tid) * 16);
        gll16(B + (size_t)(n0 + r0) * HID + k0 + sw0, Bsm[buf] + tid * 16);
        gll16(B + (size_t)(n0 + r1) * HID + k0 + sw1, Bsm[buf] + (256 + tid) * 16);
    };
    stage(0, 0);
    __syncthreads();
    f32x4 acc[4][4] = {};
    int cur = 0;
    for (int t = 0; t < 32; ++t) {
        if (t < 31) stage(cur ^ 1, (t + 1) * 32);
        s16x8 af[4], bfv[4];
        #pragma unroll
        for (int i = 0; i < 4; ++i) {
            const int ra = wm * 64 + i * 16 + l15;
            af[i]  = *(const s16x8*)(Asm[cur] + ra * 64 + ((l4 ^ ((ra >> 1) & 3)) << 4));
            const int rb = wn * 64 + i * 16 + l15;
            bfv[i] = *(const s16x8*)(Bsm[cur] + rb * 64 + ((l4 ^ ((rb >> 1) & 3)) << 4));
        }
        #pragma unroll
        for (int i = 0; i < 4; ++i)
            #pragma unroll
            for (int j = 0; j < 4; ++j)
                acc[i][j] = mfma16(af[i], bfv[j], acc[i][j]);
        __syncthreads();
        cur ^= 1;
    }
    #pragma unroll
    for (int i = 0; i < 4; ++i) {
        #pragma unroll
        for (int j = 0; j < 4; ++j) {
            const int col = n0 + wn * 64 + j * 16 + l15;
            #pragma unroll
            for (int q = 0; q < 4; ++q) {
                const int row = m0 + wm * 64 + i * 16 + l4 * 4 + q;
                float v = lrelu_f(acc[i][j][q] + bias[col]);
                if (col >= 510) {
                    const int n = row % 81;
                    v = (col == 510) ? (float)(n / 9) * (1.f / 9.f)
                                     : (float)(n % 9) * (1.f / 9.f);
                }
                Cb[(size_t)row * DM + col] = __float2bfloat16(v);
            }
        }
    }
}

// ============ QKV GEMM: 256x256 8-phase + stripe-major XCD mapping ==========
#define QKV_PHASE(QD, STAGING, TAIL)                                           \
    {                                                                          \
        s16x8 areg[2][2];                                                      \
        _Pragma("unroll")                                                      \
        for (int ii = 0; ii < 2; ++ii) {                                       \
            const int fr = QD * 32 + ii * 16 + l15;                            \
            _Pragma("unroll")                                                  \
            for (int kk = 0; kk < 2; ++kk)                                     \
                areg[ii][kk] = *(const s16x8*)(Abase + fr * 128 +              \
                                   (((kk * 4 + l4) ^ (fr & 7)) << 4));         \
        }                                                                      \
        STAGING;                                                               \
        __builtin_amdgcn_s_barrier();                                          \
        asm volatile("s_waitcnt lgkmcnt(0)" ::: "memory");                     \
        __builtin_amdgcn_sched_barrier(0);                                     \
        __builtin_amdgcn_s_setprio(1);                                         \
        _Pragma("unroll")                                                      \
        for (int ii = 0; ii < 2; ++ii)                                         \
            _Pragma("unroll")                                                  \
            for (int j = 0; j < 4; ++j)                                        \
                _Pragma("unroll")                                              \
                for (int kk = 0; kk < 2; ++kk)                                 \
                    acc[QD * 2 + ii][j] =                                      \
                        mfma16(areg[ii][kk], breg[j][kk], acc[QD * 2 + ii][j]);\
        __builtin_amdgcn_s_setprio(0);                                         \
        TAIL;                                                                  \
        __builtin_amdgcn_s_barrier();                                          \
        __builtin_amdgcn_sched_barrier(0);                                     \
    }

__global__ __launch_bounds__(512, 2) void k_gemm_qkv8(const bf16* __restrict__ A,
        const bf16* __restrict__ B, bf16* __restrict__ Cb,
        float2* __restrict__ part) {
    __shared__ __align__(16) char lds[131072];
    const int tid = threadIdx.x;
    int bx, by;
    {
        const int lin = blockIdx.x;
        if (lin >= 960) { by = 80; bx = lin - 960; }
        else { bx = (lin >> 3) % 12; by = ((lin >> 3) / 12) * 8 + (lin & 7); }
    }
    const int m0 = by * 256, n0 = bx * 256;
    const int wid = tid >> 6, l = tid & 63;
    const int wm = wid >> 2, wn = wid & 3;
    const int l15 = l & 15, l4 = l >> 4;
    const int rA = tid >> 3, pA = tid & 7;

    auto stageA = [&](int buf, int kt, int qa) {
        char* dst = lds + buf * 32768 + (qa >> 1) * 16384 + (qa & 1) * 8192 + tid * 16;
        gll16(A + (size_t)(m0 + qa * 64 + rA) * 512 + kt * 64 + ((pA ^ (rA & 7)) << 3), dst);
    };
    auto stageB = [&](int buf, int kt, int hb) {
        char* base = lds + 65536 + buf * 32768 + hb * 16384;
        #pragma unroll
        for (int i2 = 0; i2 < 2; ++i2) {
            const int s = i2 * 512 + tid;
            const int c = s >> 3, pp = s & 7;
            gll16(B + (size_t)(n0 + hb * 128 + c) * 512 + kt * 64 + ((pp ^ (c & 7)) << 3),
                  base + s * 16);
        }
    };

    stageA(0, 0, 0); stageA(0, 0, 1); stageA(0, 0, 2); stageA(0, 0, 3);
    stageB(0, 0, 0); stageB(0, 0, 1);
    stageB(1, 1, 0); stageB(1, 1, 1);
    stageA(1, 1, 0); stageA(1, 1, 2);
    asm volatile("s_waitcnt vmcnt(6)" ::: "memory");
    __builtin_amdgcn_s_barrier();
    __builtin_amdgcn_sched_barrier(0);

    f32x4 acc[8][4] = {};
    for (int kt = 0; kt < 8; ++kt) {
        const int cur = kt & 1;
        const char* Abase = lds + cur * 32768 + wm * 16384;
        const char* Bbase = lds + 65536 + cur * 32768 + (wn >> 1) * 16384;
        s16x8 breg[4][2];
        #pragma unroll
        for (int j = 0; j < 4; ++j) {
            const int fc = (wn & 1) * 64 + j * 16 + l15;
            #pragma unroll
            for (int kk = 0; kk < 2; ++kk)
                breg[j][kk] = *(const s16x8*)(Bbase + fc * 128 +
                                  (((kk * 4 + l4) ^ (fc & 7)) << 4));
        }
        QKV_PHASE(0, { if (kt + 1 < 8) { stageA(cur ^ 1, kt + 1, 1); stageA(cur ^ 1, kt + 1, 3); } }, {})
        QKV_PHASE(1, { if (kt + 2 < 8) { stageB(cur, kt + 2, 0); } }, {})
        QKV_PHASE(2, { if (kt + 2 < 8) { stageB(cur, kt + 2, 1); stageA(cur, kt + 2, 0); stageA(cur, kt + 2, 2); } }, {})
        QKV_PHASE(3, { }, {
            if (kt < 6)       { asm volatile("s_waitcnt vmcnt(6)" ::: "memory"); }
            else if (kt == 6) { asm volatile("s_waitcnt vmcnt(0)" ::: "memory"); }
        })
    }

    #pragma unroll
    for (int fi = 0; fi < 8; ++fi) {
        #pragma unroll
        for (int q = 0; q < 4; ++q) {
            const int row = m0 + wm * 128 + fi * 16 + l4 * 4 + q;
            float s = 0.f, s2 = 0.f;
            #pragma unroll
            for (int j = 0; j < 4; ++j) {
                const float v = acc[fi][j][q];
                s += v; s2 += v * v;
            }
            #pragma unroll
            for (int o = 1; o < 16; o <<= 1) {
                s  += __shfl_xor(s, o, 64);
                s2 += __shfl_xor(s2, o, 64);
            }
            if (l15 == 0)
                part[(size_t)row * 48 + bx * 4 + wn] = make_float2(s, s2);
            bf16* cr = Cb + (size_t)row * QS + n0 + wn * 64;
            #pragma unroll
            for (int j = 0; j < 4; ++j)
                cr[j * 16 + l15] = __float2bfloat16(acc[fi][j][q]);
        }
    }
}

// ---------------- GEMM 128x128, BK=64, dbuf, + row-partial stats (out-proj) -
template <int RESID>
__global__ __launch_bounds__(256) void k_gemm_stats(const bf16* __restrict__ A,
        const bf16* __restrict__ B, const bf16* __restrict__ resid,
        bf16* __restrict__ Cb, float2* __restrict__ part,
        int K, int ldc, int nPH) {
    __shared__ __align__(16) char Asm[2][16384];
    __shared__ __align__(16) char Bsm[2][16384];
    const int tid = threadIdx.x;
    const int m0 = blockIdx.y * 128, n0 = blockIdx.x * 128;
    const int w = tid >> 6, l = tid & 63;
    const int wm = w >> 1, wn = w & 1;
    const int l15 = l & 15, l4 = l >> 4;

    auto stage = [&](int buf, int k0) {
        #pragma unroll
        for (int it = 0; it < 4; ++it) {
            const int g = it * 256 + tid;
            const int r = g >> 3, p = g & 7;
            const int sw = (p ^ (r & 7)) << 3;
            gll16(A + (size_t)(m0 + r) * K + k0 + sw, Asm[buf] + g * 16);
            gll16(B + (size_t)(n0 + r) * K + k0 + sw, Bsm[buf] + g * 16);
        }
    };
    stage(0, 0);
    __syncthreads();
    f32x4 acc[4][4] = {};
    int cur = 0;
    const int nt = K >> 6;
    for (int t = 0; t < nt; ++t) {
        if (t + 1 < nt) stage(cur ^ 1, (t + 1) * 64);
        #pragma unroll
        for (int kk = 0; kk < 2; ++kk) {
            s16x8 af[4], bfv[4];
            const int pz = kk * 4 + l4;
            #pragma unroll
            for (int i = 0; i < 4; ++i) {
                const int ra = wm * 64 + i * 16 + l15;
                af[i]  = *(const s16x8*)(Asm[cur] + ra * 128 + ((pz ^ (ra & 7)) << 4));
                const int rb = wn * 64 + i * 16 + l15;
                bfv[i] = *(const s16x8*)(Bsm[cur] + rb * 128 + ((pz ^ (rb & 7)) << 4));
            }
            #pragma unroll
            for (int i = 0; i < 4; ++i)
                #pragma unroll
                for (int j = 0; j < 4; ++j)
                    acc[i][j] = mfma16(af[i], bfv[j], acc[i][j]);
        }
        __syncthreads();
        cur ^= 1;
    }
    #pragma unroll
    for (int i = 0; i < 4; ++i) {
        #pragma unroll
        for (int q = 0; q < 4; ++q) {
            const int row = m0 + wm * 64 + i * 16 + l4 * 4 + q;
            if (RESID) {
                const bf16* rr = resid + (size_t)row * ldc;
                #pragma unroll
                for (int j = 0; j < 4; ++j)
                    acc[i][j][q] += bf2f(*(const ushort*)(rr + n0 + wn * 64 + j * 16 + l15));
            }
            float s = 0.f, s2 = 0.f;
            #pragma unroll
            for (int j = 0; j < 4; ++j) {
                const float v = acc[i][j][q];
                s += v; s2 += v * v;
            }
            #pragma unroll
            for (int o = 1; o < 16; o <<= 1) {
                s  += __shfl_xor(s, o, 64);
                s2 += __shfl_xor(s2, o, 64);
            }
            if (l15 == 0)
                part[(size_t)row * nPH + (n0 >> 6) + wn] = make_float2(s, s2);
            bf16* cr = Cb + (size_t)row * ldc + n0 + wn * 64;
            #pragma unroll
            for (int j = 0; j < 4; ++j)
                cr[j * 16 + l15] = __float2bfloat16(acc[i][j][q]);
        }
    }
}

// ---------------- attention v6: V read direct from global (no Vs LDS) -------
// LDS: Ks 48K | Pb 20K | stats 2.3K = 69.8 KB -> 2 blocks/CU.
__global__ __launch_bounds__(512, 4) void k_attn6(const bf16* __restrict__ qkv3,
        const float2* __restrict__ part1, const float* __restrict__ g,
        const float* __restrict__ bprm, bf16* __restrict__ nv) {
    __shared__ __align__(16) char smem[49152 + 96 * 104 * 2];
    __shared__ float2 stQ[96], stK[96], stV[96];
    char* Ks = smem;
    bf16* Pb = (bf16*)(smem + 49152);
    const int tid = threadIdx.x;
    const int bh = blockIdx.x;
    const int b = bh >> 2, h = bh & 3;
    const int brow = b * NE;
    const int hoff = h * DK;
    const int w = tid >> 6, l = tid & 63;
    const int l15 = l & 15, l4 = l >> 4;

    // ---- per-row LN stats from part1 ----
    if (tid < 288) {
        const int proj = tid / 96, r = tid - proj * 96;
        const int row = brow + (r < NE ? r : NE - 1);
        const float2* p = part1 + (size_t)row * 48 + proj * 16;
        float s = 0.f, s2 = 0.f;
        #pragma unroll 4
        for (int h2 = 0; h2 < 16; ++h2) { s += p[h2].x; s2 += p[h2].y; }
        const float mean = s * (1.f / 1024.f);
        const float var  = s2 * (1.f / 1024.f) - mean * mean;
        const float2 st = make_float2(mean, rsqrtf(var + 1e-6f));
        if (proj == 0) stQ[r] = st; else if (proj == 1) stK[r] = st; else stV[r] = st;
    }
    __syncthreads();

    // ---- stage K (LN'd, swizzled) ----
    for (int gidx = tid; gidx < 96 * 32; gidx += 512) {
        const int r = gidx >> 5, c8 = gidx & 31;
        int krow = brow + r; if (krow >= MR) krow = MR - 1;
        const s16x8 kv = *(const s16x8*)(qkv3 + (size_t)krow * QS + 1024 + hoff + c8 * 8);
        const float2 st = stK[r];
        const int col0 = hoff + c8 * 8;
        const float4 g0 = *(const float4*)(g + col0), g1 = *(const float4*)(g + col0 + 4);
        const float4 b0 = *(const float4*)(bprm + col0), b1 = *(const float4*)(bprm + col0 + 4);
        const float ga[8] = { g0.x, g0.y, g0.z, g0.w, g1.x, g1.y, g1.z, g1.w };
        const float ba[8] = { b0.x, b0.y, b0.z, b0.w, b1.x, b1.y, b1.z, b1.w };
        short o[8];
        #pragma unroll
        for (int jj = 0; jj < 8; ++jj) {
            const float a = st.y * ga[jj];
            o[jj] = f2bs(bf2f((ushort)kv[jj]) * a + (ba[jj] - st.x * a));
        }
        *(s16x8*)(Ks + r * 512 + ((c8 ^ (r & 7)) << 4)) = *(s16x8*)o;
    }
    __syncthreads();

    if (w < 6) {    // ---- QK^T (LN'd Q read per-lane from global) ----
        const int rq = w * 16 + l15;
        int qrow = brow + rq; if (qrow >= MR) qrow = MR - 1;
        const float2 stq = stQ[rq];
        s16x8 qa[8];
        #pragma unroll
        for (int kk = 0; kk < 8; ++kk) {
            const int col0 = hoff + kk * 32 + l4 * 8;
            const s16x8 qv = *(const s16x8*)(qkv3 + (size_t)qrow * QS + col0);
            const float4 g0 = *(const float4*)(g + col0), g1 = *(const float4*)(g + col0 + 4);
            const float4 b0 = *(const float4*)(bprm + col0), b1 = *(const float4*)(bprm + col0 + 4);
            const float ga[8] = { g0.x, g0.y, g0.z, g0.w, g1.x, g1.y, g1.z, g1.w };
            const float ba[8] = { b0.x, b0.y, b0.z, b0.w, b1.x, b1.y, b1.z, b1.w };
            short o[8];
            #pragma unroll
            for (int jj = 0; jj < 8; ++jj) {
                const float a = stq.y * ga[jj];
                o[jj] = f2bs(bf2f((ushort)qv[jj]) * a + (ba[jj] - stq.x * a));
            }
            qa[kk] = *(s16x8*)o;
        }
        f32x4 sacc[6];
        #pragma unroll
        for (int j = 0; j < 6; ++j) {
            f32x4 a = {};
            const int rb = j * 16 + l15;
            #pragma unroll
            for (int kk = 0; kk < 8; ++kk) {
                const s16x8 kf = *(const s16x8*)(Ks + rb * 512 + (((kk * 4 + l4) ^ (rb & 7)) << 4));
                a = mfma16(qa[kk], kf, a);
            }
            sacc[j] = a;
        }
        float px[6][4];
        #pragma unroll
        for (int q = 0; q < 4; ++q) {
            float m = -1e30f;
            #pragma unroll
            for (int j = 0; j < 6; ++j) {
                const int key = j * 16 + l15;
                const float v = (key < NE) ? sacc[j][q] : -1e30f;
                px[j][q] = v;
                m = fmaxf(m, v);
            }
            #pragma unroll
            for (int o = 1; o < 16; o <<= 1) m = fmaxf(m, __shfl_xor(m, o, 64));
            float s = 0.f;
            #pragma unroll
            for (int j = 0; j < 6; ++j) {
                const float e = __expf((px[j][q] - m) * 0.0625f);
                px[j][q] = e; s += e;
            }
            #pragma unroll
            for (int o = 1; o < 16; o <<= 1) s += __shfl_xor(s, o, 64);
            const float r = 1.f / s;
            #pragma unroll
            for (int j = 0; j < 6; ++j) px[j][q] *= r;
        }
        #pragma unroll
        for (int j = 0; j < 6; ++j)
            #pragma unroll
            for (int q = 0; q < 4; ++q)
                Pb[(w * 16 + l4 * 4 + q) * 104 + j * 16 + l15] =
                    __float2bfloat16(px[j][q]);
    }
    __syncthreads();

    // ---- O = P V ; V gathered directly from L3-resident qkv3 (read-once),
    // LN applied inline from stV (common-mistake #7: no LDS stage for 1-use data)
    s16x8 vf[2][3];
    #pragma unroll
    for (int dj = 0; dj < 2; ++dj) {
        const int d = (2 * w + dj) * 16 + l15;
        const float gc = g[hoff + d], bc = bprm[hoff + d];
        #pragma unroll
        for (int ks = 0; ks < 3; ++ks) {
            #pragma unroll
            for (int jj = 0; jj < 8; ++jj) {
                const int m = (ks * 4 + l4) * 8 + jj;
                if (m < NE) {
                    const float2 st = stV[m];
                    const float a = st.y * gc;
                    const float vval = bf2f(*(const ushort*)(qkv3 +
                        (size_t)(brow + m) * QS + 2048 + hoff + d));
                    vf[dj][ks][jj] = f2bs(vval * a + (bc - st.x * a));
                } else {
                    vf[dj][ks][jj] = (short)0;
                }
            }
        }
    }
    f32x4 oacc[6][2] = {};
    #pragma unroll
    for (int i = 0; i < 6; ++i) {
        s16x8 pa[3];
        #pragma unroll
        for (int ks = 0; ks < 3; ++ks)
            pa[ks] = *(const s16x8*)(Pb + (i * 16 + l15) * 104 + (ks * 4 + l4) * 8);
        #pragma unroll
        for (int dj = 0; dj < 2; ++dj)
            #pragma unroll
            for (int ks = 0; ks < 3; ++ks)
                oacc[i][dj] = mfma16(pa[ks], vf[dj][ks], oacc[i][dj]);
    }
    #pragma unroll
    for (int i = 0; i < 6; ++i) {
        #pragma unroll
        for (int q = 0; q < 4; ++q) {
            const int n = i * 16 + l4 * 4 + q;
            if (n < NE) {
                #pragma unroll
                for (int dj = 0; dj < 2; ++dj) {
                    const int d = (2 * w + dj) * 16 + l15;
                    nv[(size_t)(brow + n) * HID + hoff + d] =
                        __float2bfloat16(oacc[i][dj][q]);
                }
            }
        }
    }
}

// ---------------- fused: out-LN stats + maxpool(LN+relu) + final mapping ----
__global__ __launch_bounds__(512) void k_pool_final(const bf16* __restrict__ X,
        const float2* __restrict__ part2, const float* __restrict__ g,
        const float* __restrict__ bprm, const float* __restrict__ W,
        const float* __restrict__ bias, float* __restrict__ out) {
    __shared__ float pr[DM];
    __shared__ float2 st_sh[NE];
    const int bb = blockIdx.x;
    const int c = threadIdx.x;          // 512
    if (c < NE) {
        const float2* p = part2 + (size_t)(bb * NE + c) * 8;
        float s = 0.f, s2 = 0.f;
        #pragma unroll
        for (int h2 = 0; h2 < 8; ++h2) { s += p[h2].x; s2 += p[h2].y; }
        const float mean = s * (1.f / 512.f);
        const float var  = s2 * (1.f / 512.f) - mean * mean;
        st_sh[c] = make_float2(mean, rsqrtf(var + 1e-6f));
    }
    __syncthreads();
    const float gc = g[c], bc = bprm[c];
    const bf16* xp = X + (size_t)bb * NE * DM + c;
    float mx = -1e30f;
    for (int n = 0; n < NE; ++n) {
        const float2 s = st_sh[n];
        const float a = s.y * gc;
        const float v = bf2f(*(const ushort*)(xp + (size_t)n * DM)) * a + (bc - s.x * a);
        mx = fmaxf(mx, fmaxf(v, 0.f));
    }
    pr[c] = mx;
    __syncthreads();
    if (c < ODIM) {
        const float4* w4 = (const float4*)(W + (size_t)c * DM);
        float acc = 0.f;
        #pragma unroll 4
        for (int c4 = 0; c4 < DM / 4; ++c4) {
            const float4 wv = w4[c4];
            acc += wv.x * pr[c4 * 4] + wv.y * pr[c4 * 4 + 1]
                 + wv.z * pr[c4 * 4 + 2] + wv.w * pr[c4 * 4 + 3];
        }
        out[(size_t)bb * ODIM + c] = lrelu_f(acc + bias[c]);
    }
}

extern "C" void kernel_launch(void* const* d_in, const int* in_sizes, int n_in,
                              void* d_out, int out_size, void* d_ws, size_t ws_size,
                              hipStream_t stream) {
    const float* x   = (const float*)d_in[0];
    const float* w1  = (const float*)d_in[1];
    const float* b1  = (const float*)d_in[2];
    const float* w2  = (const float*)d_in[3];
    const float* b2  = (const float*)d_in[4];
    const float* wq  = (const float*)d_in[5];
    const float* wk  = (const float*)d_in[6];
    const float* wvv = (const float*)d_in[7];
    const float* lng = (const float*)d_in[8];
    const float* lnb = (const float*)d_in[9];
    const float* wo  = (const float*)d_in[10];
    const float* lg2 = (const float*)d_in[11];
    const float* lb2 = (const float*)d_in[12];
    const float* mw  = (const float*)d_in[13];
    const float* mb  = (const float*)d_in[14];

    char* ws = (char*)d_ws;
    size_t off = 0;
    auto alloc = [&](size_t bytes) {
        void* p = ws + off;
        off = (off + bytes + 255) & ~(size_t)255;
        return p;
    };
    bf16*   y1t   = (bf16*)  alloc((size_t)BB * P1 * 64 * 2);       // 13.1 MB
    bf16*   ebf   = (bf16*)  alloc((size_t)MR * DM * 2);            // 21.2 MB
    bf16*   qkv3  = (bf16*)  alloc((size_t)MR * QS * 2);            // 127.4 MB
    bf16*   nv    = (bf16*)  alloc((size_t)MR * HID * 2);           // 42.5 MB
    bf16*   ao    = (bf16*)  alloc((size_t)MR * DM * 2);            // 21.2 MB
    float2* part1 = (float2*)alloc((size_t)MR * 48 * 8);            // 8 MB
    float2* part2 = (float2*)alloc((size_t)MR * 8 * 8);             // 1.3 MB
    bf16*   w1b   = (bf16*)  alloc((size_t)C1 * CIN * 64 * 2);
    bf16*   w2b   = (bf16*)  alloc((size_t)512 * HID * 2);
    float*  b2p   = (float*) alloc(512 * 4);
    bf16*   wqkv  = (bf16*)  alloc((size_t)3072 * DM * 2);          // 3 MB
    bf16*   wob   = (bf16*)  alloc((size_t)DM * HID * 2);           // 1 MB
    float*  outp  = (float*)d_out;

    // fused weight prep
    k_prep<<<4166, 256, 0, stream>>>(w1, w2, b2, wq, wk, wvv, wo,
                                     w1b, w2b, b2p, wqkv, wob);

    // conv1 -> y1t bf16
    k_conv1_mfma<<<BB, 512, 0, stream>>>(x, w1b, b1, y1t);

    // conv2 (implicit im2col, +bias +lrelu, coord fused) -> ebf
    k_gemm_conv2<<<dim3(4, MR / 128), 256, 0, stream>>>(y1t, w2b, b2p, ebf);

    // QKV projection GEMM (256x256 8-phase, stripe-major XCD mapping) + partials
    k_gemm_qkv8<<<972, 512, 0, stream>>>(ebf, wqkv, qkv3, part1);

    // attention (in-kernel LN stats; V gathered direct from global)
    k_attn6<<<BB * NH, 512, 0, stream>>>(qkv3, part1, lng, lnb, nv);

    // out projection + residual + partials (BK=64 dbuf)
    k_gemm_stats<1><<<dim3(4, MR / 128), 256, 0, stream>>>(nv, wob, ebf,
                                                           ao, part2, HID, DM, 8);

    // fused: out-LN stats + maxpool(LN+relu) + final mapping
    k_pool_final<<<BB, 512, 0, stream>>>(ao, part2, lg2, lb2, mw, mb, outp);
}